// Round 2
// baseline (1499.464 us; speedup 1.0000x reference)
//
#include <hip/hip_runtime.h>
#include <hip/hip_bf16.h>
#include <math.h>

#define NIMG 64
#define NP   2601   // patches per image (51*51)
#define SEQ  2602   // NP + cls
#define EMB  128
#define IND  75     // 3*5*5
#define NHEAD 8
#define HD   16
#define CCH  256    // tokens per chunk; ws = (CCH*64*(128+384)+8192)*4 B ~= 33.6 MB

__device__ __forceinline__ float dot4(float4 a, float4 b) {
    return a.x*b.x + a.y*b.y + a.z*b.z + a.w*b.w;
}
__device__ __forceinline__ void fma4(float4& o, float p, float4 v) {
    o.x += p*v.x; o.y += p*v.y; o.z += p*v.z; o.w += p*v.w;
}

// ---------------------------------------------------------------------------
// Zero the pooled accumulator (64*128 floats). ws is poisoned 0xAA each call.
// ---------------------------------------------------------------------------
__global__ __launch_bounds__(1024) void zero_pooled(float* __restrict__ p) {
    p[blockIdx.x * 1024 + threadIdx.x] = 0.0f;
}

// ---------------------------------------------------------------------------
// Embed one chunk of tokens. Grid: (ceil(c_act/8), 64 images), 128 threads.
// Block handles image l = blockIdx.y, tokens sl = blockIdx.x*8 .. +7.
// xc[sl][l][e] = patch(l, s-1) . lm_w[e,:] + lm_b[e] + PE(s, e);  s = s0+sl
// s == 0 is the class-token row: cls[e] + PE(0,e)  (PE(0,odd)=1).
// ---------------------------------------------------------------------------
__global__ __launch_bounds__(128) void embed_chunk(
    const float* __restrict__ images, const float* __restrict__ lm_w,
    const float* __restrict__ lm_b, const float* __restrict__ cls_tok,
    float* __restrict__ xc, int s0, int c_act) {
    __shared__ float wls[IND * EMB];    // [e*75 + f]
    __shared__ float patches[8][IND];

    for (int idx = threadIdx.x; idx < IND * EMB; idx += 128)
        wls[idx] = lm_w[idx];

    const int l = blockIdx.y;
    const int sl0 = blockIdx.x * 8;

    for (int idx = threadIdx.x; idx < 8 * IND; idx += 128) {
        int pp = idx / IND, f = idx % IND;
        int sl = sl0 + pp;
        if (sl < c_act) {
            int s = s0 + sl;
            if (s > 0) {
                int p = s - 1;
                int i = p / 51, j = p % 51;
                int c = f / 25, rr = (f % 25) / 5, cc = f % 5;
                patches[pp][f] =
                    images[(((size_t)l * 3 + c) * 255 + (i * 5 + rr)) * 255 + (j * 5 + cc)];
            }
        }
    }
    __syncthreads();

    const int e = threadIdx.x;
    const float bias = lm_b[e];
    const float pfac = powf(10000.0f, -(float)(e & ~1) / 128.0f);
    const bool odd = (e & 1);

    for (int pp = 0; pp < 8; ++pp) {
        int sl = sl0 + pp;
        if (sl >= c_act) break;
        int s = s0 + sl;
        float val;
        if (s == 0) {
            val = cls_tok[e] + (odd ? 1.0f : 0.0f);
        } else {
            float acc = bias;
            const float* wrow = &wls[e * IND];
            #pragma unroll 15
            for (int f = 0; f < IND; ++f) acc += patches[pp][f] * wrow[f];
            float angle = (float)s * pfac;
            val = acc + (odd ? cosf(angle) : sinf(angle));
        }
        xc[((size_t)sl * 64 + l) * EMB + e] = val;
    }
}

// ---------------------------------------------------------------------------
// C[M,N] = A[M,128] @ B[N,128]^T + bias[N], with row strides lda/ldc.
// BM=BN=64, K=128 in two BK=64 phases. 256 threads, 4x4 micro-tile.
// LDS stride 65 (odd) -> conflict-free. grid = (N/64, M/64).
// ---------------------------------------------------------------------------
__global__ __launch_bounds__(256) void gemm_bt_bias(
    const float* __restrict__ A, int lda, const float* __restrict__ B,
    const float* __restrict__ bias, float* __restrict__ C, int ldc, int N) {
    __shared__ float As[64 * 65];
    __shared__ float Bs[64 * 65];
    const int bm = blockIdx.y * 64;
    const int bn = blockIdx.x * 64;
    const int tid = threadIdx.x;
    const int tx = tid & 15, ty = tid >> 4;

    float acc[4][4] = {};

    for (int kk = 0; kk < 128; kk += 64) {
        __syncthreads();
        #pragma unroll
        for (int t = 0; t < 4; ++t) {
            int q = tid + t * 256;              // chunk id 0..1023
            int row = q >> 4, c4 = (q & 15) << 2;
            float4 va = *(const float4*)(A + (size_t)(bm + row) * lda + kk + c4);
            As[row * 65 + c4 + 0] = va.x; As[row * 65 + c4 + 1] = va.y;
            As[row * 65 + c4 + 2] = va.z; As[row * 65 + c4 + 3] = va.w;
            float4 vb = *(const float4*)(B + (size_t)(bn + row) * 128 + kk + c4);
            Bs[row * 65 + c4 + 0] = vb.x; Bs[row * 65 + c4 + 1] = vb.y;
            Bs[row * 65 + c4 + 2] = vb.z; Bs[row * 65 + c4 + 3] = vb.w;
        }
        __syncthreads();
        #pragma unroll 8
        for (int k = 0; k < 64; ++k) {
            float a0 = As[(ty * 4 + 0) * 65 + k];
            float a1 = As[(ty * 4 + 1) * 65 + k];
            float a2 = As[(ty * 4 + 2) * 65 + k];
            float a3 = As[(ty * 4 + 3) * 65 + k];
            float b0 = Bs[(tx * 4 + 0) * 65 + k];
            float b1 = Bs[(tx * 4 + 1) * 65 + k];
            float b2 = Bs[(tx * 4 + 2) * 65 + k];
            float b3 = Bs[(tx * 4 + 3) * 65 + k];
            acc[0][0] += a0 * b0; acc[0][1] += a0 * b1; acc[0][2] += a0 * b2; acc[0][3] += a0 * b3;
            acc[1][0] += a1 * b0; acc[1][1] += a1 * b1; acc[1][2] += a1 * b2; acc[1][3] += a1 * b3;
            acc[2][0] += a2 * b0; acc[2][1] += a2 * b1; acc[2][2] += a2 * b2; acc[2][3] += a2 * b3;
            acc[3][0] += a3 * b0; acc[3][1] += a3 * b1; acc[3][2] += a3 * b2; acc[3][3] += a3 * b3;
        }
    }

    float4 bv = *(const float4*)(bias + bn + tx * 4);
    #pragma unroll
    for (int i = 0; i < 4; ++i) {
        float4 r;
        r.x = acc[i][0] + bv.x; r.y = acc[i][1] + bv.y;
        r.z = acc[i][2] + bv.z; r.w = acc[i][3] + bv.w;
        *(float4*)(C + (size_t)(bm + ty * 4 + i) * ldc + bn + tx * 4) = r;
    }
}

// ---------------------------------------------------------------------------
// Attention over the IMAGE axis (torch batch_first=False quirk).
// One 64-thread block per (sl, h); thread l = image index.
// qkv row (sl,l): [q 0..127 | k 128..255 | v 256..383]. o overwrites q-slot
// in place (each block touches only its own h-slice of its own rows).
// ---------------------------------------------------------------------------
__global__ __launch_bounds__(64) void attention(float* __restrict__ qkv) {
    const int sl = blockIdx.x >> 3;
    const int h = blockIdx.x & 7;
    const int l = threadIdx.x;

    __shared__ float4 Ks[64 * 4];
    __shared__ float4 Vs[64 * 4];

    float* base = qkv + ((size_t)sl * 64 + l) * 384 + h * HD;
    float4 q0 = ((const float4*)base)[0];
    float4 q1 = ((const float4*)base)[1];
    float4 q2 = ((const float4*)base)[2];
    float4 q3 = ((const float4*)base)[3];
    const float scl = 0.25f;   // 1/sqrt(16)
    q0.x *= scl; q0.y *= scl; q0.z *= scl; q0.w *= scl;
    q1.x *= scl; q1.y *= scl; q1.z *= scl; q1.w *= scl;
    q2.x *= scl; q2.y *= scl; q2.z *= scl; q2.w *= scl;
    q3.x *= scl; q3.y *= scl; q3.z *= scl; q3.w *= scl;

    #pragma unroll
    for (int t = 0; t < 4; ++t) {
        Ks[l * 4 + t] = ((const float4*)(base + 128))[t];
        Vs[l * 4 + t] = ((const float4*)(base + 256))[t];
    }
    __syncthreads();

    float sc[64];
    #pragma unroll
    for (int m = 0; m < 64; ++m) {
        sc[m] = dot4(q0, Ks[m * 4 + 0]) + dot4(q1, Ks[m * 4 + 1])
              + dot4(q2, Ks[m * 4 + 2]) + dot4(q3, Ks[m * 4 + 3]);
    }
    float mx = sc[0];
    #pragma unroll
    for (int m = 1; m < 64; ++m) mx = fmaxf(mx, sc[m]);
    float sum = 0.0f;
    #pragma unroll
    for (int m = 0; m < 64; ++m) { float e_ = __expf(sc[m] - mx); sc[m] = e_; sum += e_; }
    const float inv = 1.0f / sum;

    float4 o0 = {0,0,0,0}, o1 = {0,0,0,0}, o2 = {0,0,0,0}, o3 = {0,0,0,0};
    #pragma unroll
    for (int m = 0; m < 64; ++m) {
        float p = sc[m];
        fma4(o0, p, Vs[m * 4 + 0]); fma4(o1, p, Vs[m * 4 + 1]);
        fma4(o2, p, Vs[m * 4 + 2]); fma4(o3, p, Vs[m * 4 + 3]);
    }
    o0.x *= inv; o0.y *= inv; o0.z *= inv; o0.w *= inv;
    o1.x *= inv; o1.y *= inv; o1.z *= inv; o1.w *= inv;
    o2.x *= inv; o2.y *= inv; o2.z *= inv; o2.w *= inv;
    o3.x *= inv; o3.y *= inv; o3.z *= inv; o3.w *= inv;

    float4* op = (float4*)base;   // in-place into q-slot
    op[0] = o0; op[1] = o1; op[2] = o2; op[3] = o3;
}

// ---------------------------------------------------------------------------
// Fused LayerNorm + mean-pool accumulate. y chunk lives in the k-slot:
// y[(sl*64+l)*384 + e], e<128. Grid (64 images, 8 groups), 128 threads (e).
// LN output is never materialized — only accumulated into pooled[l][e].
// ---------------------------------------------------------------------------
__global__ __launch_bounds__(128) void ln_pool(
    const float* __restrict__ y, const float* __restrict__ g,
    const float* __restrict__ b, float* __restrict__ pooled, int c_act) {
    const int l = blockIdx.x, grp = blockIdx.y, e = threadIdx.x;
    __shared__ float sh[4];
    const float ge = g[e], be = b[e];
    float local = 0.0f;

    for (int sl = grp; sl < c_act; sl += 8) {
        float v = y[((size_t)sl * 64 + l) * 384 + e];
        float s1 = v, s2 = v * v;
        #pragma unroll
        for (int off = 32; off > 0; off >>= 1) {
            s1 += __shfl_down(s1, off);
            s2 += __shfl_down(s2, off);
        }
        if ((e & 63) == 0) { sh[(e >> 6) * 2] = s1; sh[(e >> 6) * 2 + 1] = s2; }
        __syncthreads();
        float sum = sh[0] + sh[2];
        float sq  = sh[1] + sh[3];
        __syncthreads();
        float mu  = sum * (1.0f / 128.0f);
        float var = sq * (1.0f / 128.0f) - mu * mu;
        float r = rsqrtf(var + 1e-5f);
        local += (v - mu) * r * ge + be;
    }
    atomicAdd(&pooled[l * EMB + e], local);
}

// ---------------------------------------------------------------------------
// Classifier head: out[l,c] = (pooled[l]/SEQ) . out_w[c] + out_b[c]
// ---------------------------------------------------------------------------
__global__ __launch_bounds__(128) void classify(
    const float* __restrict__ pooled, const float* __restrict__ out_w,
    const float* __restrict__ out_b, float* __restrict__ out) {
    const int l = blockIdx.x, e = threadIdx.x;
    __shared__ float sp[EMB];
    sp[e] = pooled[l * EMB + e] * (1.0f / (float)SEQ);
    __syncthreads();
    if (e < 3) {
        float acc = out_b[e];
        #pragma unroll 16
        for (int k = 0; k < EMB; ++k) acc += sp[k] * out_w[e * EMB + k];
        out[l * 3 + e] = acc;
    }
}

extern "C" void kernel_launch(void* const* d_in, const int* in_sizes, int n_in,
                              void* d_out, int out_size, void* d_ws, size_t ws_size,
                              hipStream_t stream) {
    const float* images = (const float*)d_in[0];
    const float* lm_w   = (const float*)d_in[1];
    const float* lm_b   = (const float*)d_in[2];
    const float* cls    = (const float*)d_in[3];
    const float* w_in   = (const float*)d_in[4];
    const float* b_in   = (const float*)d_in[5];
    const float* w_out  = (const float*)d_in[6];
    const float* b_out  = (const float*)d_in[7];
    const float* ln_g   = (const float*)d_in[8];
    const float* ln_b   = (const float*)d_in[9];
    const float* out_w  = (const float*)d_in[10];
    const float* out_b  = (const float*)d_in[11];
    float* out = (float*)d_out;

    // Workspace layout (33.6 MB total; chunk buffers reused across chunks):
    float* xc     = (float*)d_ws;                        // [CCH][64][128]
    float* qkvc   = xc + (size_t)CCH * 64 * EMB;         // [CCH][64][384]
    float* pooled = qkvc + (size_t)CCH * 64 * 384;       // [64][128]

    zero_pooled<<<dim3(8), 1024, 0, stream>>>(pooled);

    const int nchunks = (SEQ + CCH - 1) / CCH;           // 11
    for (int c = 0; c < nchunks; ++c) {
        int s0 = c * CCH;
        int ca = SEQ - s0; if (ca > CCH) ca = CCH;
        embed_chunk<<<dim3((ca + 7) / 8, 64), 128, 0, stream>>>(
            images, lm_w, lm_b, cls, xc, s0, ca);
        gemm_bt_bias<<<dim3(6, ca), 256, 0, stream>>>(
            xc, 128, w_in, b_in, qkvc, 384, 384);
        attention<<<dim3(ca * 8), 64, 0, stream>>>(qkvc);
        gemm_bt_bias<<<dim3(2, ca), 256, 0, stream>>>(
            qkvc, 384, w_out, b_out, qkvc + 128, 384, 128);
        ln_pool<<<dim3(64, 8), 128, 0, stream>>>(
            qkvc + 128, ln_g, ln_b, pooled, ca);
    }
    classify<<<dim3(NIMG), 128, 0, stream>>>(pooled, out_w, out_b, out);
}

// Round 3
// 1002.513 us; speedup vs baseline: 1.4957x; 1.4957x over previous
//
#include <hip/hip_runtime.h>
#include <math.h>

#define NIMG 64
#define SEQ  2602
#define EMB  128
#define HD   16
#define CCH  256     // tokens per chunk (even; last chunk = 42, also even)
#define SPAD 2624    // SEQ padded to multiple of 64

__device__ __forceinline__ float dot4(float4 a, float4 b) {
    return a.x*b.x + a.y*b.y + a.z*b.z + a.w*b.w;
}
__device__ __forceinline__ void fma4(float4& o, float p, float4 v) {
    o.x += p*v.x; o.y += p*v.y; o.z += p*v.z; o.w += p*v.w;
}

// ---------------------------------------------------------------------------
// A_pre[s][e]: s==0 -> cls + PE(0); 1<=s<SEQ -> lm_b + PE(s); else 0.
// ---------------------------------------------------------------------------
__global__ __launch_bounds__(128) void build_A(
    const float* __restrict__ lm_b, const float* __restrict__ cls,
    float* __restrict__ A) {
    const int s = blockIdx.x, e = threadIdx.x;
    const bool odd = e & 1;
    float v;
    if (s == 0) {
        v = cls[e] + (odd ? 1.0f : 0.0f);
    } else if (s < SEQ) {
        float pfac = powf(10000.0f, -(float)(e & ~1) / 128.0f);
        float ang = (float)s * pfac;
        v = lm_b[e] + (odd ? cosf(ang) : sinf(ang));
    } else {
        v = 0.0f;
    }
    A[(size_t)s * 128 + e] = v;
}

// ---------------------------------------------------------------------------
// W2[j][f] = sum_e w_in[j][e] * lm_w[e][f]; f in [0,80), zero-pad f>=75.
// ---------------------------------------------------------------------------
__global__ __launch_bounds__(128) void build_W2(
    const float* __restrict__ w_in, const float* __restrict__ lm_w,
    float* __restrict__ W2) {
    const int j = blockIdx.x, f = threadIdx.x;
    if (f >= 80) return;
    float acc = 0.0f;
    if (f < 75) {
        for (int e = 0; e < 128; ++e)
            acc += w_in[j * 128 + e] * lm_w[e * 75 + f];
    }
    W2[j * 80 + f] = acc;
}

__global__ __launch_bounds__(1024) void zero_pooled(float* __restrict__ p) {
    p[blockIdx.x * 1024 + threadIdx.x] = 0.0f;
}

// ---------------------------------------------------------------------------
// Patchify one chunk: Pb[sl][l][f] (f<80; pad + cls row = 0), coalesced write.
// Grid: (ceil(ca/4), 64 images), 320 threads (4 tokens x 80 f).
// ---------------------------------------------------------------------------
__global__ __launch_bounds__(320) void patchify(
    const float* __restrict__ images, float* __restrict__ Pb, int s0, int ca) {
    const int l = blockIdx.y;
    const int sl = blockIdx.x * 4 + threadIdx.x / 80;
    const int f = threadIdx.x % 80;
    if (sl >= ca) return;
    const int s = s0 + sl;
    float v = 0.0f;
    if (s > 0 && f < 75) {
        int p = s - 1;
        int i = p / 51, j = p % 51;
        int c = f / 25, rr = (f % 25) / 5, cc = f % 5;
        v = images[(((size_t)l * 3 + c) * 255 + (i * 5 + rr)) * 255 + (j * 5 + cc)];
    }
    Pb[((size_t)sl * 64 + l) * 80 + f] = v;
}

// ---------------------------------------------------------------------------
// QKV GEMM: C[M,384] = P[M,80] @ W2[384,80]^T + SB-row-bias.
// BM=128 (2 tokens), BN=64, K=80 in two BK=40 passes. 256 thr, 8x4 microtile.
// LDS transposed [k][m]: stride 132/68 -> conflict-free b128 frag reads.
// ---------------------------------------------------------------------------
__global__ __launch_bounds__(256) void gemm_qkv(
    const float* __restrict__ P, const float* __restrict__ W2,
    const float* __restrict__ SBc, float* __restrict__ C) {
    __shared__ float As[40 * 132];
    __shared__ float Bs[40 * 68];
    const int bm = blockIdx.y * 128;
    const int bn = blockIdx.x * 64;
    const int tid = threadIdx.x;
    const int tx = tid & 15, ty = tid >> 4;

    float acc[8][4] = {};

    for (int kk = 0; kk < 80; kk += 40) {
        __syncthreads();
        #pragma unroll
        for (int t = 0; t < 5; ++t) {
            int q = tid + t * 256;               // 0..1279: 128 rows x 10 f4
            int row = q & 127, c4 = (q >> 7) << 2;
            float4 va = *(const float4*)(P + (size_t)(bm + row) * 80 + kk + c4);
            As[(c4 + 0) * 132 + row] = va.x;
            As[(c4 + 1) * 132 + row] = va.y;
            As[(c4 + 2) * 132 + row] = va.z;
            As[(c4 + 3) * 132 + row] = va.w;
        }
        #pragma unroll
        for (int t = 0; t < 3; ++t) {
            int q = tid + t * 256;               // 0..639: 64 rows x 10 f4
            if (q < 640) {
                int row = q & 63, c4 = (q >> 6) << 2;
                float4 vb = *(const float4*)(W2 + (size_t)(bn + row) * 80 + kk + c4);
                Bs[(c4 + 0) * 68 + row] = vb.x;
                Bs[(c4 + 1) * 68 + row] = vb.y;
                Bs[(c4 + 2) * 68 + row] = vb.z;
                Bs[(c4 + 3) * 68 + row] = vb.w;
            }
        }
        __syncthreads();
        #pragma unroll 4
        for (int k = 0; k < 40; ++k) {
            float4 a0 = *(const float4*)&As[k * 132 + (ty << 2)];
            float4 a1 = *(const float4*)&As[k * 132 + 64 + (ty << 2)];
            float4 bv = *(const float4*)&Bs[k * 68 + (tx << 2)];
            acc[0][0] += a0.x*bv.x; acc[0][1] += a0.x*bv.y; acc[0][2] += a0.x*bv.z; acc[0][3] += a0.x*bv.w;
            acc[1][0] += a0.y*bv.x; acc[1][1] += a0.y*bv.y; acc[1][2] += a0.y*bv.z; acc[1][3] += a0.y*bv.w;
            acc[2][0] += a0.z*bv.x; acc[2][1] += a0.z*bv.y; acc[2][2] += a0.z*bv.z; acc[2][3] += a0.z*bv.w;
            acc[3][0] += a0.w*bv.x; acc[3][1] += a0.w*bv.y; acc[3][2] += a0.w*bv.z; acc[3][3] += a0.w*bv.w;
            acc[4][0] += a1.x*bv.x; acc[4][1] += a1.x*bv.y; acc[4][2] += a1.x*bv.z; acc[4][3] += a1.x*bv.w;
            acc[5][0] += a1.y*bv.x; acc[5][1] += a1.y*bv.y; acc[5][2] += a1.y*bv.z; acc[5][3] += a1.y*bv.w;
            acc[6][0] += a1.z*bv.x; acc[6][1] += a1.z*bv.y; acc[6][2] += a1.z*bv.z; acc[6][3] += a1.z*bv.w;
            acc[7][0] += a1.w*bv.x; acc[7][1] += a1.w*bv.y; acc[7][2] += a1.w*bv.z; acc[7][3] += a1.w*bv.w;
        }
    }

    const int sl0 = blockIdx.y * 2;
    float4 b0 = *(const float4*)(SBc + (size_t)sl0 * 384 + bn + (tx << 2));
    float4 b1 = *(const float4*)(SBc + (size_t)(sl0 + 1) * 384 + bn + (tx << 2));
    #pragma unroll
    for (int i = 0; i < 4; ++i) {
        float4 r0, r1;
        r0.x = acc[i][0] + b0.x; r0.y = acc[i][1] + b0.y;
        r0.z = acc[i][2] + b0.z; r0.w = acc[i][3] + b0.w;
        r1.x = acc[4 + i][0] + b1.x; r1.y = acc[4 + i][1] + b1.y;
        r1.z = acc[4 + i][2] + b1.z; r1.w = acc[4 + i][3] + b1.w;
        *(float4*)(C + (size_t)(bm + (ty << 2) + i) * 384 + bn + (tx << 2)) = r0;
        *(float4*)(C + (size_t)(bm + 64 + (ty << 2) + i) * 384 + bn + (tx << 2)) = r1;
    }
}

// ---------------------------------------------------------------------------
// Generic: C[M,N] = A[M,128] @ B[N,128]^T + bias[N]. BM=BN=64, BK=64 x2.
// 256 thr, 4x4 microtile, transposed LDS [k][m] stride 68 -> b128 frags.
// ---------------------------------------------------------------------------
__global__ __launch_bounds__(256) void gemm64(
    const float* __restrict__ A, int lda, const float* __restrict__ B,
    const float* __restrict__ bias, float* __restrict__ C, int ldc) {
    __shared__ float As[64 * 68];
    __shared__ float Bs[64 * 68];
    const int bm = blockIdx.y * 64;
    const int bn = blockIdx.x * 64;
    const int tid = threadIdx.x;
    const int tx = tid & 15, ty = tid >> 4;

    float acc[4][4] = {};

    for (int kk = 0; kk < 128; kk += 64) {
        __syncthreads();
        #pragma unroll
        for (int t = 0; t < 4; ++t) {
            int q = tid + t * 256;               // 0..1023: 64 rows x 16 f4
            int row = q & 63, c4 = (q >> 6) << 2;
            float4 va = *(const float4*)(A + (size_t)(bm + row) * lda + kk + c4);
            As[(c4 + 0) * 68 + row] = va.x;
            As[(c4 + 1) * 68 + row] = va.y;
            As[(c4 + 2) * 68 + row] = va.z;
            As[(c4 + 3) * 68 + row] = va.w;
            float4 vb = *(const float4*)(B + (size_t)(bn + row) * 128 + kk + c4);
            Bs[(c4 + 0) * 68 + row] = vb.x;
            Bs[(c4 + 1) * 68 + row] = vb.y;
            Bs[(c4 + 2) * 68 + row] = vb.z;
            Bs[(c4 + 3) * 68 + row] = vb.w;
        }
        __syncthreads();
        #pragma unroll 4
        for (int k = 0; k < 64; ++k) {
            float4 av = *(const float4*)&As[k * 68 + (ty << 2)];
            float4 bv = *(const float4*)&Bs[k * 68 + (tx << 2)];
            acc[0][0] += av.x*bv.x; acc[0][1] += av.x*bv.y; acc[0][2] += av.x*bv.z; acc[0][3] += av.x*bv.w;
            acc[1][0] += av.y*bv.x; acc[1][1] += av.y*bv.y; acc[1][2] += av.y*bv.z; acc[1][3] += av.y*bv.w;
            acc[2][0] += av.z*bv.x; acc[2][1] += av.z*bv.y; acc[2][2] += av.z*bv.z; acc[2][3] += av.z*bv.w;
            acc[3][0] += av.w*bv.x; acc[3][1] += av.w*bv.y; acc[3][2] += av.w*bv.z; acc[3][3] += av.w*bv.w;
        }
    }

    float4 bv = *(const float4*)(bias + bn + (tx << 2));
    #pragma unroll
    for (int i = 0; i < 4; ++i) {
        float4 r;
        r.x = acc[i][0] + bv.x; r.y = acc[i][1] + bv.y;
        r.z = acc[i][2] + bv.z; r.w = acc[i][3] + bv.w;
        *(float4*)(C + (size_t)(bm + (ty << 2) + i) * ldc + bn + (tx << 2)) = r;
    }
}

// ---------------------------------------------------------------------------
// Attention over the IMAGE axis. One 64-thread block per (sl, h).
// qkv row (sl,l): [q|k|v] x128. o overwrites the q-slot in place.
// ---------------------------------------------------------------------------
__global__ __launch_bounds__(64) void attention(float* __restrict__ qkv) {
    const int sl = blockIdx.x >> 3;
    const int h = blockIdx.x & 7;
    const int l = threadIdx.x;

    __shared__ float4 Ks[64 * 4];
    __shared__ float4 Vs[64 * 4];

    float* base = qkv + ((size_t)sl * 64 + l) * 384 + h * HD;
    float4 q0 = ((const float4*)base)[0];
    float4 q1 = ((const float4*)base)[1];
    float4 q2 = ((const float4*)base)[2];
    float4 q3 = ((const float4*)base)[3];
    const float scl = 0.25f;
    q0.x *= scl; q0.y *= scl; q0.z *= scl; q0.w *= scl;
    q1.x *= scl; q1.y *= scl; q1.z *= scl; q1.w *= scl;
    q2.x *= scl; q2.y *= scl; q2.z *= scl; q2.w *= scl;
    q3.x *= scl; q3.y *= scl; q3.z *= scl; q3.w *= scl;

    #pragma unroll
    for (int t = 0; t < 4; ++t) {
        Ks[l * 4 + t] = ((const float4*)(base + 128))[t];
        Vs[l * 4 + t] = ((const float4*)(base + 256))[t];
    }
    __syncthreads();

    float sc[64];
    #pragma unroll
    for (int m = 0; m < 64; ++m) {
        sc[m] = dot4(q0, Ks[m * 4 + 0]) + dot4(q1, Ks[m * 4 + 1])
              + dot4(q2, Ks[m * 4 + 2]) + dot4(q3, Ks[m * 4 + 3]);
    }
    float mx = sc[0];
    #pragma unroll
    for (int m = 1; m < 64; ++m) mx = fmaxf(mx, sc[m]);
    float sum = 0.0f;
    #pragma unroll
    for (int m = 0; m < 64; ++m) { float e_ = __expf(sc[m] - mx); sc[m] = e_; sum += e_; }
    const float inv = 1.0f / sum;

    float4 o0 = {0,0,0,0}, o1 = {0,0,0,0}, o2 = {0,0,0,0}, o3 = {0,0,0,0};
    #pragma unroll
    for (int m = 0; m < 64; ++m) {
        float p = sc[m];
        fma4(o0, p, Vs[m * 4 + 0]); fma4(o1, p, Vs[m * 4 + 1]);
        fma4(o2, p, Vs[m * 4 + 2]); fma4(o3, p, Vs[m * 4 + 3]);
    }
    o0.x *= inv; o0.y *= inv; o0.z *= inv; o0.w *= inv;
    o1.x *= inv; o1.y *= inv; o1.z *= inv; o1.w *= inv;
    o2.x *= inv; o2.y *= inv; o2.z *= inv; o2.w *= inv;
    o3.x *= inv; o3.y *= inv; o3.z *= inv; o3.w *= inv;

    float4* op = (float4*)base;
    op[0] = o0; op[1] = o1; op[2] = o2; op[3] = o3;
}

// ---------------------------------------------------------------------------
// Fused LayerNorm + mean-pool accumulate (y in the k-slot, stride 384).
// ---------------------------------------------------------------------------
__global__ __launch_bounds__(128) void ln_pool(
    const float* __restrict__ y, const float* __restrict__ g,
    const float* __restrict__ b, float* __restrict__ pooled, int c_act) {
    const int l = blockIdx.x, grp = blockIdx.y, e = threadIdx.x;
    __shared__ float sh[4];
    const float ge = g[e], be = b[e];
    float local = 0.0f;

    for (int sl = grp; sl < c_act; sl += 8) {
        float v = y[((size_t)sl * 64 + l) * 384 + e];
        float s1 = v, s2 = v * v;
        #pragma unroll
        for (int off = 32; off > 0; off >>= 1) {
            s1 += __shfl_down(s1, off);
            s2 += __shfl_down(s2, off);
        }
        if ((e & 63) == 0) { sh[(e >> 6) * 2] = s1; sh[(e >> 6) * 2 + 1] = s2; }
        __syncthreads();
        float sum = sh[0] + sh[2];
        float sq  = sh[1] + sh[3];
        __syncthreads();
        float mu  = sum * (1.0f / 128.0f);
        float var = sq * (1.0f / 128.0f) - mu * mu;
        float r = rsqrtf(var + 1e-5f);
        local += (v - mu) * r * ge + be;
    }
    atomicAdd(&pooled[l * EMB + e], local);
}

__global__ __launch_bounds__(128) void classify(
    const float* __restrict__ pooled, const float* __restrict__ out_w,
    const float* __restrict__ out_b, float* __restrict__ out) {
    const int l = blockIdx.x, e = threadIdx.x;
    __shared__ float sp[EMB];
    sp[e] = pooled[l * EMB + e] * (1.0f / (float)SEQ);
    __syncthreads();
    if (e < 3) {
        float acc = out_b[e];
        #pragma unroll 16
        for (int k = 0; k < EMB; ++k) acc += sp[k] * out_w[e * EMB + k];
        out[l * 3 + e] = acc;
    }
}

extern "C" void kernel_launch(void* const* d_in, const int* in_sizes, int n_in,
                              void* d_out, int out_size, void* d_ws, size_t ws_size,
                              hipStream_t stream) {
    const float* images = (const float*)d_in[0];
    const float* lm_w   = (const float*)d_in[1];
    const float* lm_b   = (const float*)d_in[2];
    const float* cls    = (const float*)d_in[3];
    const float* w_in   = (const float*)d_in[4];
    const float* b_in   = (const float*)d_in[5];
    const float* w_out  = (const float*)d_in[6];
    const float* b_out  = (const float*)d_in[7];
    const float* ln_g   = (const float*)d_in[8];
    const float* ln_b   = (const float*)d_in[9];
    const float* out_w  = (const float*)d_in[10];
    const float* out_b  = (const float*)d_in[11];
    float* out = (float*)d_out;

    // Workspace (~35.9 MB):
    float* Pb     = (float*)d_ws;                        // [CCH][64][80]
    float* qkvc   = Pb + (size_t)CCH * 64 * 80;          // [CCH][64][384]
    float* SB     = qkvc + (size_t)CCH * 64 * 384;       // [SPAD][384]
    float* W2     = SB + (size_t)SPAD * 384;             // [384][80]
    float* A_pre  = W2 + 384 * 80;                       // [SPAD][128]
    float* pooled = A_pre + (size_t)SPAD * 128;          // [64][128]

    // Precompute fused weights / per-token bias
    build_A<<<dim3(SPAD), 128, 0, stream>>>(lm_b, cls, A_pre);
    gemm64<<<dim3(6, SPAD / 64), 256, 0, stream>>>(A_pre, 128, w_in, b_in, SB, 384);
    build_W2<<<dim3(384), 128, 0, stream>>>(w_in, lm_w, W2);
    zero_pooled<<<dim3(8), 1024, 0, stream>>>(pooled);

    const int nchunks = (SEQ + CCH - 1) / CCH;           // 11
    for (int c = 0; c < nchunks; ++c) {
        int s0 = c * CCH;
        int ca = SEQ - s0; if (ca > CCH) ca = CCH;       // 256 ... 42 (always even)
        patchify<<<dim3((ca + 3) / 4, 64), 320, 0, stream>>>(images, Pb, s0, ca);
        gemm_qkv<<<dim3(6, ca / 2), 256, 0, stream>>>(Pb, W2, SB + (size_t)s0 * 384, qkvc);
        attention<<<dim3(ca * 8), 64, 0, stream>>>(qkvc);
        gemm64<<<dim3(2, ca), 256, 0, stream>>>(qkvc, 384, w_out, b_out, qkvc + 128, 384);
        ln_pool<<<dim3(64, 8), 128, 0, stream>>>(qkvc + 128, ln_g, ln_b, pooled, ca);
    }
    classify<<<dim3(NIMG), 128, 0, stream>>>(pooled, out_w, out_b, out);
}

// Round 4
// 673.331 us; speedup vs baseline: 2.2269x; 1.4889x over previous
//
#include <hip/hip_runtime.h>
#include <math.h>

#define NIMG 64
#define SEQ  2602
#define EMB  128
#define HD   16
#define CCH  652     // tokens per chunk -> 4 chunks (652,652,652,646)
#define SPAD 2624    // SEQ padded to multiple of 64
#define KQ   96      // patch K padded 75 -> 96 (multiple of 32)
#define LSQ  104     // LDS row stride (bf16) for KQ  (208 B, 16B-multiple)
#define LSO  136     // LDS row stride (bf16) for K=128 (272 B, 16B-multiple)

typedef float f32x4 __attribute__((ext_vector_type(4)));
typedef short short8 __attribute__((ext_vector_type(8)));

__device__ __forceinline__ unsigned short f2bf(float f) {
    union { float f; unsigned int u; } v; v.f = f;
    unsigned int r = (v.u + 0x7fffu + ((v.u >> 16) & 1u)) >> 16;   // RNE
    return (unsigned short)r;
}
__device__ __forceinline__ float dot4(float4 a, float4 b) {
    return a.x*b.x + a.y*b.y + a.z*b.z + a.w*b.w;
}
__device__ __forceinline__ void fma4(float4& o, float p, float4 v) {
    o.x += p*v.x; o.y += p*v.y; o.z += p*v.z; o.w += p*v.w;
}

// ---------------------------------------------------------------------------
// A_pre[s][e]: s==0 -> cls + PE(0); 1<=s<SEQ -> lm_b + PE(s); else 0.
// ---------------------------------------------------------------------------
__global__ __launch_bounds__(128) void build_A(
    const float* __restrict__ lm_b, const float* __restrict__ cls,
    float* __restrict__ A) {
    const int s = blockIdx.x, e = threadIdx.x;
    const bool odd = e & 1;
    float v;
    if (s == 0) {
        v = cls[e] + (odd ? 1.0f : 0.0f);
    } else if (s < SEQ) {
        float pfac = powf(10000.0f, -(float)(e & ~1) / 128.0f);
        float ang = (float)s * pfac;
        v = lm_b[e] + (odd ? cosf(ang) : sinf(ang));
    } else {
        v = 0.0f;
    }
    A[(size_t)s * 128 + e] = v;
}

// ---------------------------------------------------------------------------
// W2[j][f] = sum_e w_in[j][e]*lm_w[e][f], f<75; zero-pad to KQ. bf16 output.
// ---------------------------------------------------------------------------
__global__ __launch_bounds__(128) void build_W2(
    const float* __restrict__ w_in, const float* __restrict__ lm_w,
    unsigned short* __restrict__ W2) {
    const int j = blockIdx.x, f = threadIdx.x;
    if (f >= KQ) return;
    float acc = 0.0f;
    if (f < 75) {
        for (int e = 0; e < 128; ++e)
            acc += w_in[j * 128 + e] * lm_w[e * 75 + f];
    }
    W2[j * KQ + f] = f2bf(acc);
}

__global__ __launch_bounds__(1024) void zero_pooled(float* __restrict__ p) {
    p[blockIdx.x * 1024 + threadIdx.x] = 0.0f;
}

// ---------------------------------------------------------------------------
// Patchify one chunk to bf16: Pb[sl][l][f], f<KQ (pad + cls row = 0).
// Grid: (ceil(ca/4), 64 images), 384 threads = 4 tokens x 96 f.
// ---------------------------------------------------------------------------
__global__ __launch_bounds__(384) void patchify(
    const float* __restrict__ images, unsigned short* __restrict__ Pb,
    int s0, int ca) {
    const int l = blockIdx.y;
    const int sl = blockIdx.x * 4 + threadIdx.x / KQ;
    const int f = threadIdx.x % KQ;
    if (sl >= ca) return;
    const int s = s0 + sl;
    float v = 0.0f;
    if (s > 0 && f < 75) {
        int p = s - 1;
        int i = p / 51, j = p % 51;
        int c = f / 25, rr = (f % 25) / 5, cc = f % 5;
        v = images[(((size_t)l * 3 + c) * 255 + (i * 5 + rr)) * 255 + (j * 5 + cc)];
    }
    Pb[((size_t)sl * 64 + l) * KQ + f] = f2bf(v);
}

// ---------------------------------------------------------------------------
// MFMA QKV GEMM: C[M,384] = P[M,KQ](bf16) @ W2[384,KQ](bf16)^T + SB[token].
// BM=64 (= one token: rows are the 64 images), BN=64, 256 thr = 4 waves.
// Wave w: m-rows [w*16, w*16+16), 4 n-tiles, 3 k-steps of 32.
// Layouts (m89/m120-verified): A-frag m=lane&15,k=quad*8+j; B row-contig;
// C/D col=lane&15, row=quad*4+reg. fp32 accumulate + fp32 epilogue.
// ---------------------------------------------------------------------------
__global__ __launch_bounds__(256) void gemm_qkv_mfma(
    const unsigned short* __restrict__ P, const unsigned short* __restrict__ W2,
    const float* __restrict__ SBc, float* __restrict__ C) {
    __shared__ unsigned short As[64 * LSQ];
    __shared__ unsigned short Bs[64 * LSQ];
    const int tid = threadIdx.x;
    const int bm = blockIdx.y * 64;
    const int bn = blockIdx.x * 64;
    const int wv = tid >> 6, lane = tid & 63, quad = lane >> 4, col = lane & 15;

    #pragma unroll
    for (int t = 0; t < 3; ++t) {                 // 768 16B-chunks per matrix
        int q = tid + t * 256;
        int row = q & 63, c = q >> 6;             // c in 0..11
        *(float4*)&As[row * LSQ + c * 8] =
            *(const float4*)(P + (size_t)(bm + row) * KQ + c * 8);
        *(float4*)&Bs[row * LSQ + c * 8] =
            *(const float4*)(W2 + (size_t)(bn + row) * KQ + c * 8);
    }
    __syncthreads();

    f32x4 acc[4] = {};
    const int mrow = wv * 16 + col;
    #pragma unroll
    for (int ks = 0; ks < 3; ++ks) {
        const int k0 = ks * 32 + quad * 8;
        short8 a = *(const short8*)&As[mrow * LSQ + k0];
        #pragma unroll
        for (int nt = 0; nt < 4; ++nt) {
            short8 b = *(const short8*)&Bs[(nt * 16 + col) * LSQ + k0];
            acc[nt] = __builtin_amdgcn_mfma_f32_16x16x32_bf16(a, b, acc[nt], 0, 0, 0);
        }
    }

    const float* brow = SBc + (size_t)blockIdx.y * 384 + bn;   // one token/block
    #pragma unroll
    for (int nt = 0; nt < 4; ++nt) {
        float bv = brow[nt * 16 + col];
        #pragma unroll
        for (int r = 0; r < 4; ++r)
            C[(size_t)(bm + wv * 16 + quad * 4 + r) * 384 + bn + nt * 16 + col]
                = acc[nt][r] + bv;
    }
}

// ---------------------------------------------------------------------------
// MFMA out-proj: C[M,128] = A[M,128](fp32,stride 384) @ Bw[128,128]^T + bias.
// fp32 -> bf16 conversion happens in LDS staging. BM=BN=64, 4 k-steps.
// ---------------------------------------------------------------------------
__global__ __launch_bounds__(256) void gemm_out_mfma(
    const float* __restrict__ A, const float* __restrict__ Bw,
    const float* __restrict__ bias, float* __restrict__ C) {
    __shared__ unsigned short As[64 * LSO];
    __shared__ unsigned short Bs[64 * LSO];
    const int tid = threadIdx.x;
    const int bm = blockIdx.y * 64;
    const int bn = blockIdx.x * 64;
    const int wv = tid >> 6, lane = tid & 63, quad = lane >> 4, col = lane & 15;

    #pragma unroll
    for (int t = 0; t < 8; ++t) {                 // 2048 float4-chunks each
        int q = tid + t * 256;
        int row = q & 63, c4 = q >> 6;            // c4 in 0..31
        float4 va = *(const float4*)(A + (size_t)(bm + row) * 384 + c4 * 4);
        ushort4 pa; pa.x = f2bf(va.x); pa.y = f2bf(va.y);
        pa.z = f2bf(va.z); pa.w = f2bf(va.w);
        *(ushort4*)&As[row * LSO + c4 * 4] = pa;
        float4 vb = *(const float4*)(Bw + (size_t)(bn + row) * 128 + c4 * 4);
        ushort4 pb; pb.x = f2bf(vb.x); pb.y = f2bf(vb.y);
        pb.z = f2bf(vb.z); pb.w = f2bf(vb.w);
        *(ushort4*)&Bs[row * LSO + c4 * 4] = pb;
    }
    __syncthreads();

    f32x4 acc[4] = {};
    const int mrow = wv * 16 + col;
    #pragma unroll
    for (int ks = 0; ks < 4; ++ks) {
        const int k0 = ks * 32 + quad * 8;
        short8 a = *(const short8*)&As[mrow * LSO + k0];
        #pragma unroll
        for (int nt = 0; nt < 4; ++nt) {
            short8 b = *(const short8*)&Bs[(nt * 16 + col) * LSO + k0];
            acc[nt] = __builtin_amdgcn_mfma_f32_16x16x32_bf16(a, b, acc[nt], 0, 0, 0);
        }
    }

    #pragma unroll
    for (int nt = 0; nt < 4; ++nt) {
        float bv = bias[bn + nt * 16 + col];
        #pragma unroll
        for (int r = 0; r < 4; ++r)
            C[(size_t)(bm + wv * 16 + quad * 4 + r) * 384 + bn + nt * 16 + col]
                = acc[nt][r] + bv;
    }
}

// ---------------------------------------------------------------------------
// Attention over the IMAGE axis (fp32, unchanged). One wave per (sl, h).
// qkv row (sl,l): [q|k|v] x128; o overwrites the q-slot in place.
// ---------------------------------------------------------------------------
__global__ __launch_bounds__(64) void attention(float* __restrict__ qkv) {
    const int sl = blockIdx.x >> 3;
    const int h = blockIdx.x & 7;
    const int l = threadIdx.x;

    __shared__ float4 Ks[64 * 4];
    __shared__ float4 Vs[64 * 4];

    float* base = qkv + ((size_t)sl * 64 + l) * 384 + h * HD;
    float4 q0 = ((const float4*)base)[0];
    float4 q1 = ((const float4*)base)[1];
    float4 q2 = ((const float4*)base)[2];
    float4 q3 = ((const float4*)base)[3];
    const float scl = 0.25f;
    q0.x *= scl; q0.y *= scl; q0.z *= scl; q0.w *= scl;
    q1.x *= scl; q1.y *= scl; q1.z *= scl; q1.w *= scl;
    q2.x *= scl; q2.y *= scl; q2.z *= scl; q2.w *= scl;
    q3.x *= scl; q3.y *= scl; q3.z *= scl; q3.w *= scl;

    #pragma unroll
    for (int t = 0; t < 4; ++t) {
        Ks[l * 4 + t] = ((const float4*)(base + 128))[t];
        Vs[l * 4 + t] = ((const float4*)(base + 256))[t];
    }
    __syncthreads();

    float sc[64];
    #pragma unroll
    for (int m = 0; m < 64; ++m) {
        sc[m] = dot4(q0, Ks[m * 4 + 0]) + dot4(q1, Ks[m * 4 + 1])
              + dot4(q2, Ks[m * 4 + 2]) + dot4(q3, Ks[m * 4 + 3]);
    }
    float mx = sc[0];
    #pragma unroll
    for (int m = 1; m < 64; ++m) mx = fmaxf(mx, sc[m]);
    float sum = 0.0f;
    #pragma unroll
    for (int m = 0; m < 64; ++m) { float e_ = __expf(sc[m] - mx); sc[m] = e_; sum += e_; }
    const float inv = 1.0f / sum;

    float4 o0 = {0,0,0,0}, o1 = {0,0,0,0}, o2 = {0,0,0,0}, o3 = {0,0,0,0};
    #pragma unroll
    for (int m = 0; m < 64; ++m) {
        float p = sc[m];
        fma4(o0, p, Vs[m * 4 + 0]); fma4(o1, p, Vs[m * 4 + 1]);
        fma4(o2, p, Vs[m * 4 + 2]); fma4(o3, p, Vs[m * 4 + 3]);
    }
    o0.x *= inv; o0.y *= inv; o0.z *= inv; o0.w *= inv;
    o1.x *= inv; o1.y *= inv; o1.z *= inv; o1.w *= inv;
    o2.x *= inv; o2.y *= inv; o2.z *= inv; o2.w *= inv;
    o3.x *= inv; o3.y *= inv; o3.z *= inv; o3.w *= inv;

    float4* op = (float4*)base;
    op[0] = o0; op[1] = o1; op[2] = o2; op[3] = o3;
}

// ---------------------------------------------------------------------------
// Fused LayerNorm + mean-pool accumulate (y in the k-slot, stride 384).
// ---------------------------------------------------------------------------
__global__ __launch_bounds__(128) void ln_pool(
    const float* __restrict__ y, const float* __restrict__ g,
    const float* __restrict__ b, float* __restrict__ pooled, int c_act) {
    const int l = blockIdx.x, grp = blockIdx.y, e = threadIdx.x;
    __shared__ float sh[4];
    const float ge = g[e], be = b[e];
    float local = 0.0f;

    for (int sl = grp; sl < c_act; sl += 8) {
        float v = y[((size_t)sl * 64 + l) * 384 + e];
        float s1 = v, s2 = v * v;
        #pragma unroll
        for (int off = 32; off > 0; off >>= 1) {
            s1 += __shfl_down(s1, off);
            s2 += __shfl_down(s2, off);
        }
        if ((e & 63) == 0) { sh[(e >> 6) * 2] = s1; sh[(e >> 6) * 2 + 1] = s2; }
        __syncthreads();
        float sum = sh[0] + sh[2];
        float sq  = sh[1] + sh[3];
        __syncthreads();
        float mu  = sum * (1.0f / 128.0f);
        float var = sq * (1.0f / 128.0f) - mu * mu;
        float r = rsqrtf(var + 1e-5f);
        local += (v - mu) * r * ge + be;
    }
    atomicAdd(&pooled[l * EMB + e], local);
}

// ---------------------------------------------------------------------------
// fp32 GEMM (precompute only, SB = A_pre @ w_in^T + b_in). From R2 (verified).
// ---------------------------------------------------------------------------
__global__ __launch_bounds__(256) void gemm64(
    const float* __restrict__ A, int lda, const float* __restrict__ B,
    const float* __restrict__ bias, float* __restrict__ C, int ldc) {
    __shared__ float As[64 * 68];
    __shared__ float Bs[64 * 68];
    const int bm = blockIdx.y * 64;
    const int bn = blockIdx.x * 64;
    const int tid = threadIdx.x;
    const int tx = tid & 15, ty = tid >> 4;

    float acc[4][4] = {};

    for (int kk = 0; kk < 128; kk += 64) {
        __syncthreads();
        #pragma unroll
        for (int t = 0; t < 4; ++t) {
            int q = tid + t * 256;
            int row = q & 63, c4 = (q >> 6) << 2;
            float4 va = *(const float4*)(A + (size_t)(bm + row) * lda + kk + c4);
            As[(c4 + 0) * 68 + row] = va.x;
            As[(c4 + 1) * 68 + row] = va.y;
            As[(c4 + 2) * 68 + row] = va.z;
            As[(c4 + 3) * 68 + row] = va.w;
            float4 vb = *(const float4*)(B + (size_t)(bn + row) * 128 + kk + c4);
            Bs[(c4 + 0) * 68 + row] = vb.x;
            Bs[(c4 + 1) * 68 + row] = vb.y;
            Bs[(c4 + 2) * 68 + row] = vb.z;
            Bs[(c4 + 3) * 68 + row] = vb.w;
        }
        __syncthreads();
        #pragma unroll 4
        for (int k = 0; k < 64; ++k) {
            float4 av = *(const float4*)&As[k * 68 + (ty << 2)];
            float4 bv = *(const float4*)&Bs[k * 68 + (tx << 2)];
            acc[0][0] += av.x*bv.x; acc[0][1] += av.x*bv.y; acc[0][2] += av.x*bv.z; acc[0][3] += av.x*bv.w;
            acc[1][0] += av.y*bv.x; acc[1][1] += av.y*bv.y; acc[1][2] += av.y*bv.z; acc[1][3] += av.y*bv.w;
            acc[2][0] += av.z*bv.x; acc[2][1] += av.z*bv.y; acc[2][2] += av.z*bv.z; acc[2][3] += av.z*bv.w;
            acc[3][0] += av.w*bv.x; acc[3][1] += av.w*bv.y; acc[3][2] += av.w*bv.z; acc[3][3] += av.w*bv.w;
        }
    }

    float4 bv = *(const float4*)(bias + bn + (tx << 2));
    #pragma unroll
    for (int i = 0; i < 4; ++i) {
        float4 r;
        r.x = acc[i][0] + bv.x; r.y = acc[i][1] + bv.y;
        r.z = acc[i][2] + bv.z; r.w = acc[i][3] + bv.w;
        *(float4*)(C + (size_t)(bm + (ty << 2) + i) * ldc + bn + (tx << 2)) = r;
    }
}

__global__ __launch_bounds__(128) void classify(
    const float* __restrict__ pooled, const float* __restrict__ out_w,
    const float* __restrict__ out_b, float* __restrict__ out) {
    const int l = blockIdx.x, e = threadIdx.x;
    __shared__ float sp[EMB];
    sp[e] = pooled[l * EMB + e] * (1.0f / (float)SEQ);
    __syncthreads();
    if (e < 3) {
        float acc = out_b[e];
        #pragma unroll 16
        for (int k = 0; k < EMB; ++k) acc += sp[k] * out_w[e * EMB + k];
        out[l * 3 + e] = acc;
    }
}

extern "C" void kernel_launch(void* const* d_in, const int* in_sizes, int n_in,
                              void* d_out, int out_size, void* d_ws, size_t ws_size,
                              hipStream_t stream) {
    const float* images = (const float*)d_in[0];
    const float* lm_w   = (const float*)d_in[1];
    const float* lm_b   = (const float*)d_in[2];
    const float* cls    = (const float*)d_in[3];
    const float* w_in   = (const float*)d_in[4];
    const float* b_in   = (const float*)d_in[5];
    const float* w_out  = (const float*)d_in[6];
    const float* b_out  = (const float*)d_in[7];
    const float* ln_g   = (const float*)d_in[8];
    const float* ln_b   = (const float*)d_in[9];
    const float* out_w  = (const float*)d_in[10];
    const float* out_b  = (const float*)d_in[11];
    float* out = (float*)d_out;

    // Workspace (~78 MB of the 256 MiB available), all 16B-aligned:
    float* qkvc  = (float*)d_ws;                          // [CCH][64][384] f32
    float* SB    = qkvc + (size_t)CCH * 64 * 384;         // [SPAD][384] f32
    float* A_pre = SB + (size_t)SPAD * 384;               // [SPAD][128] f32
    float* pooled = A_pre + (size_t)SPAD * 128;           // [64][128] f32
    unsigned short* W2 = (unsigned short*)(pooled + 64 * 128); // [384][KQ] bf16
    unsigned short* Pb = W2 + (size_t)384 * KQ;           // [CCH][64][KQ] bf16

    build_A<<<dim3(SPAD), 128, 0, stream>>>(lm_b, cls, A_pre);
    gemm64<<<dim3(6, SPAD / 64), 256, 0, stream>>>(A_pre, 128, w_in, b_in, SB, 384);
    build_W2<<<dim3(384), 128, 0, stream>>>(w_in, lm_w, W2);
    zero_pooled<<<dim3(8), 1024, 0, stream>>>(pooled);

    const int nchunks = (SEQ + CCH - 1) / CCH;            // 4
    for (int c = 0; c < nchunks; ++c) {
        int s0 = c * CCH;
        int ca = SEQ - s0; if (ca > CCH) ca = CCH;
        patchify<<<dim3((ca + 3) / 4, 64), 384, 0, stream>>>(images, Pb, s0, ca);
        gemm_qkv_mfma<<<dim3(6, ca), 256, 0, stream>>>(Pb, W2, SB + (size_t)s0 * 384, qkvc);
        attention<<<dim3(ca * 8), 64, 0, stream>>>(qkvc);
        gemm_out_mfma<<<dim3(2, ca), 256, 0, stream>>>(qkvc, w_out, b_out, qkvc + 128);
        ln_pool<<<dim3(64, 8), 128, 0, stream>>>(qkvc + 128, ln_g, ln_b, pooled, ca);
    }
    classify<<<dim3(NIMG), 128, 0, stream>>>(pooled, out_w, out_b, out);
}

// Round 5
// 455.276 us; speedup vs baseline: 3.2935x; 1.4790x over previous
//
#include <hip/hip_runtime.h>
#include <math.h>

#define NIMG 64
#define SEQ  2602
#define EMB  128
#define HD   16
#define SPAD 2624    // SEQ padded to multiple of 64
#define KQ   96      // patch K padded 75 -> 96 (multiple of 32)
#define LSQ  104     // LDS row stride (bf16) for KQ  (208 B, 16B-multiple)
#define LSO  136     // LDS row stride (bf16) for K=128 (272 B, 16B-multiple)

typedef float f32x4 __attribute__((ext_vector_type(4)));
typedef short short8 __attribute__((ext_vector_type(8)));

__device__ __forceinline__ unsigned short f2bf(float f) {
    union { float f; unsigned int u; } v; v.f = f;
    unsigned int r = (v.u + 0x7fffu + ((v.u >> 16) & 1u)) >> 16;   // RNE
    return (unsigned short)r;
}
__device__ __forceinline__ float bflo(unsigned int w) {   // low bf16 of uint
    union { unsigned int u; float f; } v; v.u = w << 16; return v.f;
}
__device__ __forceinline__ float bfhi(unsigned int w) {   // high bf16 of uint
    union { unsigned int u; float f; } v; v.u = w & 0xffff0000u; return v.f;
}
__device__ __forceinline__ unsigned int packbf(float a, float b) {
    return (unsigned int)f2bf(a) | ((unsigned int)f2bf(b) << 16);
}
__device__ __forceinline__ float dot4(float4 a, float4 b) {
    return a.x*b.x + a.y*b.y + a.z*b.z + a.w*b.w;
}
__device__ __forceinline__ void fma4(float4& o, float p, float4 v) {
    o.x += p*v.x; o.y += p*v.y; o.z += p*v.z; o.w += p*v.w;
}

// ---------------------------------------------------------------------------
// A_pre[s][e]: s==0 -> cls + PE(0); 1<=s<SEQ -> lm_b + PE(s); else 0.
// ---------------------------------------------------------------------------
__global__ __launch_bounds__(128) void build_A(
    const float* __restrict__ lm_b, const float* __restrict__ cls,
    float* __restrict__ A) {
    const int s = blockIdx.x, e = threadIdx.x;
    const bool odd = e & 1;
    float v;
    if (s == 0) {
        v = cls[e] + (odd ? 1.0f : 0.0f);
    } else if (s < SEQ) {
        float pfac = powf(10000.0f, -(float)(e & ~1) / 128.0f);
        float ang = (float)s * pfac;
        v = lm_b[e] + (odd ? cosf(ang) : sinf(ang));
    } else {
        v = 0.0f;
    }
    A[(size_t)s * 128 + e] = v;
}

// ---------------------------------------------------------------------------
// W2[j][f] = sum_e w_in[j][e]*lm_w[e][f], f<75; zero-pad to KQ. bf16 out.
// ---------------------------------------------------------------------------
__global__ __launch_bounds__(128) void build_W2(
    const float* __restrict__ w_in, const float* __restrict__ lm_w,
    unsigned short* __restrict__ W2) {
    const int j = blockIdx.x, f = threadIdx.x;
    if (f >= KQ) return;
    float acc = 0.0f;
    if (f < 75) {
        for (int e = 0; e < 128; ++e)
            acc += w_in[j * 128 + e] * lm_w[e * 75 + f];
    }
    W2[j * KQ + f] = f2bf(acc);
}

// w_out fp32 -> bf16 once (so gemm_out stages raw 16B copies)
__global__ __launch_bounds__(128) void build_Wout(
    const float* __restrict__ w_out, unsigned short* __restrict__ Wo) {
    const int j = blockIdx.x, e = threadIdx.x;
    Wo[j * 128 + e] = f2bf(w_out[j * 128 + e]);
}

__global__ __launch_bounds__(1024) void zero_pooled(float* __restrict__ p) {
    p[blockIdx.x * 1024 + threadIdx.x] = 0.0f;
}

// ---------------------------------------------------------------------------
// Patchify full sequence to bf16: Pb[s][l][f], f<KQ (pad + cls row = 0).
// Grid: (ceil(SEQ/4), 64 images), 384 threads = 4 tokens x 96 f.
// ---------------------------------------------------------------------------
__global__ __launch_bounds__(384) void patchify(
    const float* __restrict__ images, unsigned short* __restrict__ Pb) {
    const int l = blockIdx.y;
    const int s = blockIdx.x * 4 + threadIdx.x / KQ;
    const int f = threadIdx.x % KQ;
    if (s >= SEQ) return;
    float v = 0.0f;
    if (s > 0 && f < 75) {
        int p = s - 1;
        int i = p / 51, j = p % 51;
        int c = f / 25, rr = (f % 25) / 5, cc = f % 5;
        v = images[(((size_t)l * 3 + c) * 255 + (i * 5 + rr)) * 255 + (j * 5 + cc)];
    }
    Pb[((size_t)s * 64 + l) * KQ + f] = f2bf(v);
}

// ---------------------------------------------------------------------------
// MFMA QKV GEMM: qkv[s][l][384](bf16) = P[s*64+l][KQ] @ W2[384][KQ]^T + SB[s].
// One block per (n-tile of 64, token s). 256 thr = 4 waves.
// A-frag m=lane&15,k=quad*8+j; B row-contig; C/D col=lane&15,row=quad*4+reg.
// ---------------------------------------------------------------------------
__global__ __launch_bounds__(256) void gemm_qkv_mfma(
    const unsigned short* __restrict__ P, const unsigned short* __restrict__ W2,
    const float* __restrict__ SB, unsigned short* __restrict__ qkv) {
    __shared__ unsigned short As[64 * LSQ];
    __shared__ unsigned short Bs[64 * LSQ];
    const int tid = threadIdx.x;
    const int s = blockIdx.y;
    const int bm = s * 64;
    const int bn = blockIdx.x * 64;
    const int wv = tid >> 6, lane = tid & 63, quad = lane >> 4, col = lane & 15;

    #pragma unroll
    for (int t = 0; t < 3; ++t) {                 // 768 16B-chunks per matrix
        int q = tid + t * 256;
        int row = q & 63, c = q >> 6;             // c in 0..11
        *(float4*)&As[row * LSQ + c * 8] =
            *(const float4*)(P + (size_t)(bm + row) * KQ + c * 8);
        *(float4*)&Bs[row * LSQ + c * 8] =
            *(const float4*)(W2 + (size_t)(bn + row) * KQ + c * 8);
    }
    __syncthreads();

    f32x4 acc[4] = {};
    const int mrow = wv * 16 + col;
    #pragma unroll
    for (int ks = 0; ks < 3; ++ks) {
        const int k0 = ks * 32 + quad * 8;
        short8 a = *(const short8*)&As[mrow * LSQ + k0];
        #pragma unroll
        for (int nt = 0; nt < 4; ++nt) {
            short8 b = *(const short8*)&Bs[(nt * 16 + col) * LSQ + k0];
            acc[nt] = __builtin_amdgcn_mfma_f32_16x16x32_bf16(a, b, acc[nt], 0, 0, 0);
        }
    }

    const float* brow = SB + (size_t)s * 384 + bn;
    #pragma unroll
    for (int nt = 0; nt < 4; ++nt) {
        float bv = brow[nt * 16 + col];
        #pragma unroll
        for (int r = 0; r < 4; ++r)
            qkv[(size_t)(bm + wv * 16 + quad * 4 + r) * 384 + bn + nt * 16 + col]
                = f2bf(acc[nt][r] + bv);
    }
}

// ---------------------------------------------------------------------------
// Attention over the IMAGE axis (fp32 math, bf16 I/O). One wave per (s, h).
// qkv row (s,l): [q|k|v] x128 bf16; o overwrites the q-slot in place.
// ---------------------------------------------------------------------------
__global__ __launch_bounds__(64) void attention(unsigned short* __restrict__ qkv) {
    const int s = blockIdx.x >> 3;
    const int h = blockIdx.x & 7;
    const int l = threadIdx.x;

    __shared__ float4 Ks[64 * 4];
    __shared__ float4 Vs[64 * 4];

    unsigned short* base = qkv + ((size_t)s * 64 + l) * 384 + h * HD;

    uint4 qa = *(const uint4*)(base);
    uint4 qb = *(const uint4*)(base + 8);
    const float scl = 0.25f;
    float4 q0 = make_float4(bflo(qa.x)*scl, bfhi(qa.x)*scl, bflo(qa.y)*scl, bfhi(qa.y)*scl);
    float4 q1 = make_float4(bflo(qa.z)*scl, bfhi(qa.z)*scl, bflo(qa.w)*scl, bfhi(qa.w)*scl);
    float4 q2 = make_float4(bflo(qb.x)*scl, bfhi(qb.x)*scl, bflo(qb.y)*scl, bfhi(qb.y)*scl);
    float4 q3 = make_float4(bflo(qb.z)*scl, bfhi(qb.z)*scl, bflo(qb.w)*scl, bfhi(qb.w)*scl);

    uint4 ka = *(const uint4*)(base + 128);
    uint4 kb = *(const uint4*)(base + 136);
    Ks[l * 4 + 0] = make_float4(bflo(ka.x), bfhi(ka.x), bflo(ka.y), bfhi(ka.y));
    Ks[l * 4 + 1] = make_float4(bflo(ka.z), bfhi(ka.z), bflo(ka.w), bfhi(ka.w));
    Ks[l * 4 + 2] = make_float4(bflo(kb.x), bfhi(kb.x), bflo(kb.y), bfhi(kb.y));
    Ks[l * 4 + 3] = make_float4(bflo(kb.z), bfhi(kb.z), bflo(kb.w), bfhi(kb.w));
    uint4 va = *(const uint4*)(base + 256);
    uint4 vb = *(const uint4*)(base + 264);
    Vs[l * 4 + 0] = make_float4(bflo(va.x), bfhi(va.x), bflo(va.y), bfhi(va.y));
    Vs[l * 4 + 1] = make_float4(bflo(va.z), bfhi(va.z), bflo(va.w), bfhi(va.w));
    Vs[l * 4 + 2] = make_float4(bflo(vb.x), bfhi(vb.x), bflo(vb.y), bfhi(vb.y));
    Vs[l * 4 + 3] = make_float4(bflo(vb.z), bfhi(vb.z), bflo(vb.w), bfhi(vb.w));
    __syncthreads();

    float sc[64];
    #pragma unroll
    for (int m = 0; m < 64; ++m) {
        sc[m] = dot4(q0, Ks[m * 4 + 0]) + dot4(q1, Ks[m * 4 + 1])
              + dot4(q2, Ks[m * 4 + 2]) + dot4(q3, Ks[m * 4 + 3]);
    }
    float mx = sc[0];
    #pragma unroll
    for (int m = 1; m < 64; ++m) mx = fmaxf(mx, sc[m]);
    float sum = 0.0f;
    #pragma unroll
    for (int m = 0; m < 64; ++m) { float e_ = __expf(sc[m] - mx); sc[m] = e_; sum += e_; }
    const float inv = 1.0f / sum;

    float4 o0 = {0,0,0,0}, o1 = {0,0,0,0}, o2 = {0,0,0,0}, o3 = {0,0,0,0};
    #pragma unroll
    for (int m = 0; m < 64; ++m) {
        float p = sc[m];
        fma4(o0, p, Vs[m * 4 + 0]); fma4(o1, p, Vs[m * 4 + 1]);
        fma4(o2, p, Vs[m * 4 + 2]); fma4(o3, p, Vs[m * 4 + 3]);
    }
    uint4 w0, w1;
    w0.x = packbf(o0.x * inv, o0.y * inv); w0.y = packbf(o0.z * inv, o0.w * inv);
    w0.z = packbf(o1.x * inv, o1.y * inv); w0.w = packbf(o1.z * inv, o1.w * inv);
    w1.x = packbf(o2.x * inv, o2.y * inv); w1.y = packbf(o2.z * inv, o2.w * inv);
    w1.z = packbf(o3.x * inv, o3.y * inv); w1.w = packbf(o3.z * inv, o3.w * inv);
    *(uint4*)(base) = w0;
    *(uint4*)(base + 8) = w1;
}

// ---------------------------------------------------------------------------
// Fused out-proj + LayerNorm + mean-pool. One block per token s, 256 thr.
// y[64 imgs][128 ch] = o @ Wo^T + b_out computed in registers (BN=128:
// 8 n-tiles per wave). LN per row via in-register nt-sum + shfl_xor(1,2,4,8)
// inside each 16-lane group. Result atomicAdd'ed into pooled; y never stored.
// ---------------------------------------------------------------------------
__global__ __launch_bounds__(256) void gemm_out_ln_pool(
    const unsigned short* __restrict__ qkv, const unsigned short* __restrict__ Wo,
    const float* __restrict__ b_out, const float* __restrict__ ln_g,
    const float* __restrict__ ln_b, float* __restrict__ pooled) {
    __shared__ unsigned short As[64 * LSO];
    __shared__ unsigned short Bs[128 * LSO];
    const int tid = threadIdx.x;
    const int s = blockIdx.x;
    const int wv = tid >> 6, lane = tid & 63, quad = lane >> 4, col = lane & 15;

    #pragma unroll
    for (int t = 0; t < 4; ++t) {                 // o rows: 64 x 16 chunks
        int q = tid + t * 256;
        int row = q >> 4, c = q & 15;
        *(float4*)&As[row * LSO + c * 8] =
            *(const float4*)(qkv + ((size_t)s * 64 + row) * 384 + c * 8);
    }
    #pragma unroll
    for (int t = 0; t < 8; ++t) {                 // Wo rows: 128 x 16 chunks
        int q = tid + t * 256;
        int row = q >> 4, c = q & 15;
        *(float4*)&Bs[row * LSO + c * 8] =
            *(const float4*)(Wo + (size_t)row * 128 + c * 8);
    }
    __syncthreads();

    f32x4 acc[8] = {};
    const int mrow = wv * 16 + col;
    #pragma unroll
    for (int ks = 0; ks < 4; ++ks) {
        const int k0 = ks * 32 + quad * 8;
        short8 a = *(const short8*)&As[mrow * LSO + k0];
        #pragma unroll
        for (int nt = 0; nt < 8; ++nt) {
            short8 b = *(const short8*)&Bs[(nt * 16 + col) * LSO + k0];
            acc[nt] = __builtin_amdgcn_mfma_f32_16x16x32_bf16(a, b, acc[nt], 0, 0, 0);
        }
    }

    float gch[8], bch[8], boch[8];
    #pragma unroll
    for (int nt = 0; nt < 8; ++nt) {
        int ch = nt * 16 + col;
        gch[nt] = ln_g[ch]; bch[nt] = ln_b[ch]; boch[nt] = b_out[ch];
    }
    const int l0 = wv * 16 + quad * 4;            // image row base for this lane
    #pragma unroll
    for (int r = 0; r < 4; ++r) {
        float yv[8];
        float s1 = 0.0f, s2 = 0.0f;
        #pragma unroll
        for (int nt = 0; nt < 8; ++nt) {
            yv[nt] = acc[nt][r] + boch[nt];
            s1 += yv[nt]; s2 += yv[nt] * yv[nt];
        }
        #pragma unroll
        for (int off = 1; off < 16; off <<= 1) {
            s1 += __shfl_xor(s1, off);
            s2 += __shfl_xor(s2, off);
        }
        float mu = s1 * (1.0f / 128.0f);
        float var = s2 * (1.0f / 128.0f) - mu * mu;
        float rinv = rsqrtf(var + 1e-5f);
        #pragma unroll
        for (int nt = 0; nt < 8; ++nt) {
            float v = (yv[nt] - mu) * rinv * gch[nt] + bch[nt];
            atomicAdd(&pooled[(l0 + r) * 128 + nt * 16 + col], v);
        }
    }
}

// ---------------------------------------------------------------------------
// fp32 GEMM (precompute only, SB = A_pre @ w_in^T + b_in).
// ---------------------------------------------------------------------------
__global__ __launch_bounds__(256) void gemm64(
    const float* __restrict__ A, int lda, const float* __restrict__ B,
    const float* __restrict__ bias, float* __restrict__ C, int ldc) {
    __shared__ float As[64 * 68];
    __shared__ float Bs[64 * 68];
    const int bm = blockIdx.y * 64;
    const int bn = blockIdx.x * 64;
    const int tid = threadIdx.x;
    const int tx = tid & 15, ty = tid >> 4;

    float acc[4][4] = {};

    for (int kk = 0; kk < 128; kk += 64) {
        __syncthreads();
        #pragma unroll
        for (int t = 0; t < 4; ++t) {
            int q = tid + t * 256;
            int row = q & 63, c4 = (q >> 6) << 2;
            float4 va = *(const float4*)(A + (size_t)(bm + row) * lda + kk + c4);
            As[(c4 + 0) * 68 + row] = va.x;
            As[(c4 + 1) * 68 + row] = va.y;
            As[(c4 + 2) * 68 + row] = va.z;
            As[(c4 + 3) * 68 + row] = va.w;
            float4 vb = *(const float4*)(B + (size_t)(bn + row) * 128 + kk + c4);
            Bs[(c4 + 0) * 68 + row] = vb.x;
            Bs[(c4 + 1) * 68 + row] = vb.y;
            Bs[(c4 + 2) * 68 + row] = vb.z;
            Bs[(c4 + 3) * 68 + row] = vb.w;
        }
        __syncthreads();
        #pragma unroll 4
        for (int k = 0; k < 64; ++k) {
            float4 av = *(const float4*)&As[k * 68 + (ty << 2)];
            float4 bv = *(const float4*)&Bs[k * 68 + (tx << 2)];
            acc[0][0] += av.x*bv.x; acc[0][1] += av.x*bv.y; acc[0][2] += av.x*bv.z; acc[0][3] += av.x*bv.w;
            acc[1][0] += av.y*bv.x; acc[1][1] += av.y*bv.y; acc[1][2] += av.y*bv.z; acc[1][3] += av.y*bv.w;
            acc[2][0] += av.z*bv.x; acc[2][1] += av.z*bv.y; acc[2][2] += av.z*bv.z; acc[2][3] += av.z*bv.w;
            acc[3][0] += av.w*bv.x; acc[3][1] += av.w*bv.y; acc[3][2] += av.w*bv.z; acc[3][3] += av.w*bv.w;
        }
    }

    float4 bv = *(const float4*)(bias + bn + (tx << 2));
    #pragma unroll
    for (int i = 0; i < 4; ++i) {
        float4 r;
        r.x = acc[i][0] + bv.x; r.y = acc[i][1] + bv.y;
        r.z = acc[i][2] + bv.z; r.w = acc[i][3] + bv.w;
        *(float4*)(C + (size_t)(bm + (ty << 2) + i) * ldc + bn + (tx << 2)) = r;
    }
}

__global__ __launch_bounds__(128) void classify(
    const float* __restrict__ pooled, const float* __restrict__ out_w,
    const float* __restrict__ out_b, float* __restrict__ out) {
    const int l = blockIdx.x, e = threadIdx.x;
    __shared__ float sp[EMB];
    sp[e] = pooled[l * EMB + e] * (1.0f / (float)SEQ);
    __syncthreads();
    if (e < 3) {
        float acc = out_b[e];
        #pragma unroll 16
        for (int k = 0; k < EMB; ++k) acc += sp[k] * out_w[e * EMB + k];
        out[l * 3 + e] = acc;
    }
}

extern "C" void kernel_launch(void* const* d_in, const int* in_sizes, int n_in,
                              void* d_out, int out_size, void* d_ws, size_t ws_size,
                              hipStream_t stream) {
    const float* images = (const float*)d_in[0];
    const float* lm_w   = (const float*)d_in[1];
    const float* lm_b   = (const float*)d_in[2];
    const float* cls    = (const float*)d_in[3];
    const float* w_in   = (const float*)d_in[4];
    const float* b_in   = (const float*)d_in[5];
    const float* w_out  = (const float*)d_in[6];
    const float* b_out  = (const float*)d_in[7];
    const float* ln_g   = (const float*)d_in[8];
    const float* ln_b   = (const float*)d_in[9];
    const float* out_w  = (const float*)d_in[10];
    const float* out_b  = (const float*)d_in[11];
    float* out = (float*)d_out;

    // Workspace (~165 MB of 256 MiB), all regions 16B-aligned:
    float* SB     = (float*)d_ws;                         // [SPAD][384] f32
    float* A_pre  = SB + (size_t)SPAD * 384;              // [SPAD][128] f32
    float* pooled = A_pre + (size_t)SPAD * 128;           // [64][128] f32
    unsigned short* W2   = (unsigned short*)(pooled + 64 * 128); // [384][KQ] bf16
    unsigned short* Wout = W2 + (size_t)384 * KQ;         // [128][128] bf16
    unsigned short* Pb   = Wout + 128 * 128;              // [SEQ][64][KQ] bf16
    unsigned short* qkv  = Pb + (size_t)SEQ * 64 * KQ;    // [SEQ][64][384] bf16

    build_A<<<dim3(SPAD), 128, 0, stream>>>(lm_b, cls, A_pre);
    gemm64<<<dim3(6, SPAD / 64), 256, 0, stream>>>(A_pre, 128, w_in, b_in, SB, 384);
    build_W2<<<dim3(384), 128, 0, stream>>>(w_in, lm_w, W2);
    build_Wout<<<dim3(128), 128, 0, stream>>>(w_out, Wout);
    zero_pooled<<<dim3(8), 1024, 0, stream>>>(pooled);

    patchify<<<dim3((SEQ + 3) / 4, 64), 384, 0, stream>>>(images, Pb);
    gemm_qkv_mfma<<<dim3(6, SEQ), 256, 0, stream>>>(Pb, W2, SB, qkv);
    attention<<<dim3(SEQ * 8), 64, 0, stream>>>(qkv);
    gemm_out_ln_pool<<<dim3(SEQ), 256, 0, stream>>>(qkv, Wout, b_out, ln_g, ln_b, pooled);
    classify<<<dim3(NIMG), 128, 0, stream>>>(pooled, out_w, out_b, out);
}

// Round 6
// 393.086 us; speedup vs baseline: 3.8146x; 1.1582x over previous
//
#include <hip/hip_runtime.h>
#include <math.h>

#define NIMG 64
#define SEQ  2602
#define EMB  128
#define HD   16
#define SPAD 2624    // SEQ padded to multiple of 64
#define KQ   96      // patch K padded 75 -> 96 (multiple of 32)
#define LSQ  104     // LDS row stride (bf16) for KQ  (208 B, 16B-multiple)
#define LSO  136     // LDS row stride (bf16) for K=128 (272 B, 16B-multiple)
#define PST  80      // LDS row stride (bf16) for P transpose (40 words: balanced b128)

typedef float f32x4 __attribute__((ext_vector_type(4)));
typedef short short8 __attribute__((ext_vector_type(8)));

__device__ __forceinline__ unsigned short f2bf(float f) {
    union { float f; unsigned int u; } v; v.f = f;
    unsigned int r = (v.u + 0x7fffu + ((v.u >> 16) & 1u)) >> 16;   // RNE
    return (unsigned short)r;
}

// ---------------------------------------------------------------------------
// A_pre[s][e]: s==0 -> cls + PE(0); 1<=s<SEQ -> lm_b + PE(s); else 0.
// ---------------------------------------------------------------------------
__global__ __launch_bounds__(128) void build_A(
    const float* __restrict__ lm_b, const float* __restrict__ cls,
    float* __restrict__ A) {
    const int s = blockIdx.x, e = threadIdx.x;
    const bool odd = e & 1;
    float v;
    if (s == 0) {
        v = cls[e] + (odd ? 1.0f : 0.0f);
    } else if (s < SEQ) {
        float pfac = powf(10000.0f, -(float)(e & ~1) / 128.0f);
        float ang = (float)s * pfac;
        v = lm_b[e] + (odd ? cosf(ang) : sinf(ang));
    } else {
        v = 0.0f;
    }
    A[(size_t)s * 128 + e] = v;
}

// ---------------------------------------------------------------------------
// W2[j][f] = sum_e w_in[j][e]*lm_w[e][f], f<75; zero-pad to KQ. bf16 out.
// ---------------------------------------------------------------------------
__global__ __launch_bounds__(128) void build_W2(
    const float* __restrict__ w_in, const float* __restrict__ lm_w,
    unsigned short* __restrict__ W2) {
    const int j = blockIdx.x, f = threadIdx.x;
    if (f >= KQ) return;
    float acc = 0.0f;
    if (f < 75) {
        for (int e = 0; e < 128; ++e)
            acc += w_in[j * 128 + e] * lm_w[e * 75 + f];
    }
    W2[j * KQ + f] = f2bf(acc);
}

__global__ __launch_bounds__(128) void build_Wout(
    const float* __restrict__ w_out, unsigned short* __restrict__ Wo) {
    const int j = blockIdx.x, e = threadIdx.x;
    Wo[j * 128 + e] = f2bf(w_out[j * 128 + e]);
}

__global__ __launch_bounds__(1024) void zero_pooled(float* __restrict__ p) {
    p[blockIdx.x * 1024 + threadIdx.x] = 0.0f;
}

// ---------------------------------------------------------------------------
// Patchify full sequence to bf16: Pb[s][l][f], f<KQ (pad + cls row = 0).
// ---------------------------------------------------------------------------
__global__ __launch_bounds__(384) void patchify(
    const float* __restrict__ images, unsigned short* __restrict__ Pb) {
    const int l = blockIdx.y;
    const int s = blockIdx.x * 4 + threadIdx.x / KQ;
    const int f = threadIdx.x % KQ;
    if (s >= SEQ) return;
    float v = 0.0f;
    if (s > 0 && f < 75) {
        int p = s - 1;
        int i = p / 51, j = p % 51;
        int c = f / 25, rr = (f % 25) / 5, cc = f % 5;
        v = images[(((size_t)l * 3 + c) * 255 + (i * 5 + rr)) * 255 + (j * 5 + cc)];
    }
    Pb[((size_t)s * 64 + l) * KQ + f] = f2bf(v);
}

// ---------------------------------------------------------------------------
// MFMA QKV GEMM. One block per (n-tile of 64, token s). 256 thr = 4 waves.
// Epilogue scatters to head-major: Qh[sh][l][16] (pre-scaled 0.25),
// Kh[sh][l][16], Vt[sh][d][l] (transposed).  sh = s*8 + h.
// ---------------------------------------------------------------------------
__global__ __launch_bounds__(256) void gemm_qkv_mfma(
    const unsigned short* __restrict__ P, const unsigned short* __restrict__ W2,
    const float* __restrict__ SB, unsigned short* __restrict__ Qh,
    unsigned short* __restrict__ Kh, unsigned short* __restrict__ Vt) {
    __shared__ unsigned short As[64 * LSQ];
    __shared__ unsigned short Bs[64 * LSQ];
    const int tid = threadIdx.x;
    const int s = blockIdx.y;
    const int bm = s * 64;
    const int bn = blockIdx.x * 64;
    const int wv = tid >> 6, lane = tid & 63, quad = lane >> 4, col = lane & 15;

    #pragma unroll
    for (int t = 0; t < 3; ++t) {
        int q = tid + t * 256;
        int row = q & 63, c = q >> 6;
        *(float4*)&As[row * LSQ + c * 8] =
            *(const float4*)(P + (size_t)(bm + row) * KQ + c * 8);
        *(float4*)&Bs[row * LSQ + c * 8] =
            *(const float4*)(W2 + (size_t)(bn + row) * KQ + c * 8);
    }
    __syncthreads();

    f32x4 acc[4] = {};
    const int mrow = wv * 16 + col;
    #pragma unroll
    for (int ks = 0; ks < 3; ++ks) {
        const int k0 = ks * 32 + quad * 8;
        short8 a = *(const short8*)&As[mrow * LSQ + k0];
        #pragma unroll
        for (int nt = 0; nt < 4; ++nt) {
            short8 b = *(const short8*)&Bs[(nt * 16 + col) * LSQ + k0];
            acc[nt] = __builtin_amdgcn_mfma_f32_16x16x32_bf16(a, b, acc[nt], 0, 0, 0);
        }
    }

    const float* brow = SB + (size_t)s * 384 + bn;
    #pragma unroll
    for (int nt = 0; nt < 4; ++nt) {
        int ch = bn + nt * 16 + col;
        float bv = brow[nt * 16 + col];
        #pragma unroll
        for (int r = 0; r < 4; ++r) {
            int l = wv * 16 + quad * 4 + r;        // image index within token
            float val = acc[nt][r] + bv;
            if (ch < 128) {
                int h = ch >> 4, d = ch & 15;
                Qh[((size_t)(s * 8 + h) * 64 + l) * 16 + d] = f2bf(val * 0.25f);
            } else if (ch < 256) {
                int c2 = ch - 128, h = c2 >> 4, d = c2 & 15;
                Kh[((size_t)(s * 8 + h) * 64 + l) * 16 + d] = f2bf(val);
            } else {
                int c2 = ch - 256, h = c2 >> 4, d = c2 & 15;
                Vt[((size_t)(s * 8 + h) * 16 + d) * 64 + l] = f2bf(val);
            }
        }
    }
}

// ---------------------------------------------------------------------------
// MFMA attention over the IMAGE axis. One 64-thread wave per (s,h).
// S = Q@K^T (K-dim 16 zero-padded to 32), softmax rows via shfl_xor in the
// 16-lane col groups of the C-layout, P -> LDS (stride PST) -> A-frags,
// O = P@Vt^T, scaled by 1/sum (same lane holds matching rows). bf16 I/O.
// ---------------------------------------------------------------------------
__global__ __launch_bounds__(64) void attention_mfma(
    const unsigned short* __restrict__ Qh, const unsigned short* __restrict__ Kh,
    const unsigned short* __restrict__ Vt, unsigned short* __restrict__ O) {
    __shared__ unsigned short Plds[64 * PST];
    const size_t sh = blockIdx.x;
    const int s = blockIdx.x >> 3, h = blockIdx.x & 7;
    const int lane = threadIdx.x, quad = lane >> 4, col = lane & 15;
    const unsigned short* qb = Qh + sh * 64 * 16;
    const unsigned short* kb = Kh + sh * 64 * 16;
    const unsigned short* vb = Vt + sh * 16 * 64;

    const int koff = (quad & 1) * 8;
    const short8 z8 = {};

    short8 bfr[4];
    #pragma unroll
    for (int nt = 0; nt < 4; ++nt) {
        short8 t = *(const short8*)(kb + (size_t)(nt * 16 + col) * 16 + koff);
        bfr[nt] = (quad < 2) ? t : z8;
    }

    f32x4 sc[4][4] = {};
    #pragma unroll
    for (int mt = 0; mt < 4; ++mt) {
        short8 t = *(const short8*)(qb + (size_t)(mt * 16 + col) * 16 + koff);
        short8 afr = (quad < 2) ? t : z8;
        #pragma unroll
        for (int nt = 0; nt < 4; ++nt)
            sc[mt][nt] = __builtin_amdgcn_mfma_f32_16x16x32_bf16(afr, bfr[nt], sc[mt][nt], 0, 0, 0);
    }

    // softmax per row M = mt*16 + quad*4 + r (16 col-lanes x 4 in-lane nt vals)
    float inv[4][4];
    #pragma unroll
    for (int mt = 0; mt < 4; ++mt) {
        #pragma unroll
        for (int r = 0; r < 4; ++r) {
            float mx = sc[mt][0][r];
            #pragma unroll
            for (int nt = 1; nt < 4; ++nt) mx = fmaxf(mx, sc[mt][nt][r]);
            #pragma unroll
            for (int off = 1; off < 16; off <<= 1) mx = fmaxf(mx, __shfl_xor(mx, off));
            float sum = 0.0f;
            float p[4];
            #pragma unroll
            for (int nt = 0; nt < 4; ++nt) { p[nt] = __expf(sc[mt][nt][r] - mx); sum += p[nt]; }
            #pragma unroll
            for (int off = 1; off < 16; off <<= 1) sum += __shfl_xor(sum, off);
            inv[mt][r] = 1.0f / sum;
            const int M = mt * 16 + quad * 4 + r;
            #pragma unroll
            for (int nt = 0; nt < 4; ++nt)
                Plds[M * PST + nt * 16 + col] = f2bf(p[nt]);
        }
    }
    __syncthreads();

    short8 vfr[2];
    #pragma unroll
    for (int ks = 0; ks < 2; ++ks)
        vfr[ks] = *(const short8*)(vb + (size_t)col * 64 + ks * 32 + quad * 8);

    const size_t orow0 = (size_t)s * 64;
    #pragma unroll
    for (int mt = 0; mt < 4; ++mt) {
        f32x4 o = {};
        #pragma unroll
        for (int ks = 0; ks < 2; ++ks) {
            short8 pa = *(const short8*)&Plds[(mt * 16 + col) * PST + ks * 32 + quad * 8];
            o = __builtin_amdgcn_mfma_f32_16x16x32_bf16(pa, vfr[ks], o, 0, 0, 0);
        }
        #pragma unroll
        for (int r = 0; r < 4; ++r)
            O[(orow0 + mt * 16 + quad * 4 + r) * 128 + h * 16 + col]
                = f2bf(o[r] * inv[mt][r]);
    }
}

// ---------------------------------------------------------------------------
// Fused out-proj + LayerNorm + mean-pool. One block per token s, 256 thr.
// ---------------------------------------------------------------------------
__global__ __launch_bounds__(256) void gemm_out_ln_pool(
    const unsigned short* __restrict__ O, const unsigned short* __restrict__ Wo,
    const float* __restrict__ b_out, const float* __restrict__ ln_g,
    const float* __restrict__ ln_b, float* __restrict__ pooled) {
    __shared__ unsigned short As[64 * LSO];
    __shared__ unsigned short Bs[128 * LSO];
    const int tid = threadIdx.x;
    const int s = blockIdx.x;
    const int wv = tid >> 6, lane = tid & 63, quad = lane >> 4, col = lane & 15;

    #pragma unroll
    for (int t = 0; t < 4; ++t) {                 // O rows: 64 x 16 chunks
        int q = tid + t * 256;
        int row = q >> 4, c = q & 15;
        *(float4*)&As[row * LSO + c * 8] =
            *(const float4*)(O + ((size_t)s * 64 + row) * 128 + c * 8);
    }
    #pragma unroll
    for (int t = 0; t < 8; ++t) {                 // Wo rows: 128 x 16 chunks
        int q = tid + t * 256;
        int row = q >> 4, c = q & 15;
        *(float4*)&Bs[row * LSO + c * 8] =
            *(const float4*)(Wo + (size_t)row * 128 + c * 8);
    }
    __syncthreads();

    f32x4 acc[8] = {};
    const int mrow = wv * 16 + col;
    #pragma unroll
    for (int ks = 0; ks < 4; ++ks) {
        const int k0 = ks * 32 + quad * 8;
        short8 a = *(const short8*)&As[mrow * LSO + k0];
        #pragma unroll
        for (int nt = 0; nt < 8; ++nt) {
            short8 b = *(const short8*)&Bs[(nt * 16 + col) * LSO + k0];
            acc[nt] = __builtin_amdgcn_mfma_f32_16x16x32_bf16(a, b, acc[nt], 0, 0, 0);
        }
    }

    float gch[8], bch[8], boch[8];
    #pragma unroll
    for (int nt = 0; nt < 8; ++nt) {
        int ch = nt * 16 + col;
        gch[nt] = ln_g[ch]; bch[nt] = ln_b[ch]; boch[nt] = b_out[ch];
    }
    const int l0 = wv * 16 + quad * 4;
    #pragma unroll
    for (int r = 0; r < 4; ++r) {
        float yv[8];
        float s1 = 0.0f, s2 = 0.0f;
        #pragma unroll
        for (int nt = 0; nt < 8; ++nt) {
            yv[nt] = acc[nt][r] + boch[nt];
            s1 += yv[nt]; s2 += yv[nt] * yv[nt];
        }
        #pragma unroll
        for (int off = 1; off < 16; off <<= 1) {
            s1 += __shfl_xor(s1, off);
            s2 += __shfl_xor(s2, off);
        }
        float mu = s1 * (1.0f / 128.0f);
        float var = s2 * (1.0f / 128.0f) - mu * mu;
        float rinv = rsqrtf(var + 1e-5f);
        #pragma unroll
        for (int nt = 0; nt < 8; ++nt) {
            float v = (yv[nt] - mu) * rinv * gch[nt] + bch[nt];
            atomicAdd(&pooled[(l0 + r) * 128 + nt * 16 + col], v);
        }
    }
}

// ---------------------------------------------------------------------------
// fp32 GEMM (precompute only, SB = A_pre @ w_in^T + b_in).
// ---------------------------------------------------------------------------
__global__ __launch_bounds__(256) void gemm64(
    const float* __restrict__ A, int lda, const float* __restrict__ B,
    const float* __restrict__ bias, float* __restrict__ C, int ldc) {
    __shared__ float As[64 * 68];
    __shared__ float Bs[64 * 68];
    const int bm = blockIdx.y * 64;
    const int bn = blockIdx.x * 64;
    const int tid = threadIdx.x;
    const int tx = tid & 15, ty = tid >> 4;

    float acc[4][4] = {};

    for (int kk = 0; kk < 128; kk += 64) {
        __syncthreads();
        #pragma unroll
        for (int t = 0; t < 4; ++t) {
            int q = tid + t * 256;
            int row = q & 63, c4 = (q >> 6) << 2;
            float4 va = *(const float4*)(A + (size_t)(bm + row) * lda + kk + c4);
            As[(c4 + 0) * 68 + row] = va.x;
            As[(c4 + 1) * 68 + row] = va.y;
            As[(c4 + 2) * 68 + row] = va.z;
            As[(c4 + 3) * 68 + row] = va.w;
            float4 vb = *(const float4*)(B + (size_t)(bn + row) * 128 + kk + c4);
            Bs[(c4 + 0) * 68 + row] = vb.x;
            Bs[(c4 + 1) * 68 + row] = vb.y;
            Bs[(c4 + 2) * 68 + row] = vb.z;
            Bs[(c4 + 3) * 68 + row] = vb.w;
        }
        __syncthreads();
        #pragma unroll 4
        for (int k = 0; k < 64; ++k) {
            float4 av = *(const float4*)&As[k * 68 + (ty << 2)];
            float4 bv = *(const float4*)&Bs[k * 68 + (tx << 2)];
            acc[0][0] += av.x*bv.x; acc[0][1] += av.x*bv.y; acc[0][2] += av.x*bv.z; acc[0][3] += av.x*bv.w;
            acc[1][0] += av.y*bv.x; acc[1][1] += av.y*bv.y; acc[1][2] += av.y*bv.z; acc[1][3] += av.y*bv.w;
            acc[2][0] += av.z*bv.x; acc[2][1] += av.z*bv.y; acc[2][2] += av.z*bv.z; acc[2][3] += av.z*bv.w;
            acc[3][0] += av.w*bv.x; acc[3][1] += av.w*bv.y; acc[3][2] += av.w*bv.z; acc[3][3] += av.w*bv.w;
        }
    }

    float4 bv = *(const float4*)(bias + bn + (tx << 2));
    #pragma unroll
    for (int i = 0; i < 4; ++i) {
        float4 r;
        r.x = acc[i][0] + bv.x; r.y = acc[i][1] + bv.y;
        r.z = acc[i][2] + bv.z; r.w = acc[i][3] + bv.w;
        *(float4*)(C + (size_t)(bm + (ty << 2) + i) * ldc + bn + (tx << 2)) = r;
    }
}

__global__ __launch_bounds__(128) void classify(
    const float* __restrict__ pooled, const float* __restrict__ out_w,
    const float* __restrict__ out_b, float* __restrict__ out) {
    const int l = blockIdx.x, e = threadIdx.x;
    __shared__ float sp[EMB];
    sp[e] = pooled[l * EMB + e] * (1.0f / (float)SEQ);
    __syncthreads();
    if (e < 3) {
        float acc = out_b[e];
        #pragma unroll 16
        for (int k = 0; k < EMB; ++k) acc += sp[k] * out_w[e * EMB + k];
        out[l * 3 + e] = acc;
    }
}

extern "C" void kernel_launch(void* const* d_in, const int* in_sizes, int n_in,
                              void* d_out, int out_size, void* d_ws, size_t ws_size,
                              hipStream_t stream) {
    const float* images = (const float*)d_in[0];
    const float* lm_w   = (const float*)d_in[1];
    const float* lm_b   = (const float*)d_in[2];
    const float* cls    = (const float*)d_in[3];
    const float* w_in   = (const float*)d_in[4];
    const float* b_in   = (const float*)d_in[5];
    const float* w_out  = (const float*)d_in[6];
    const float* b_out  = (const float*)d_in[7];
    const float* ln_g   = (const float*)d_in[8];
    const float* ln_b   = (const float*)d_in[9];
    const float* out_w  = (const float*)d_in[10];
    const float* out_b  = (const float*)d_in[11];
    float* out = (float*)d_out;

    // Workspace (~208 MB of 256 MiB), all regions 16B-aligned:
    float* SB     = (float*)d_ws;                         // [SPAD][384] f32
    float* A_pre  = SB + (size_t)SPAD * 384;              // [SPAD][128] f32
    float* pooled = A_pre + (size_t)SPAD * 128;           // [64][128] f32
    unsigned short* W2   = (unsigned short*)(pooled + 64 * 128); // [384][KQ]
    unsigned short* Wout = W2 + (size_t)384 * KQ;         // [128][128]
    unsigned short* Pb   = Wout + 128 * 128;              // [SEQ][64][KQ]
    unsigned short* Qh   = Pb + (size_t)SEQ * 64 * KQ;    // [SEQ*8][64][16]
    unsigned short* Kh   = Qh + (size_t)SEQ * 8 * 64 * 16;
    unsigned short* Vt   = Kh + (size_t)SEQ * 8 * 64 * 16; // [SEQ*8][16][64]
    unsigned short* Obuf = Vt + (size_t)SEQ * 8 * 16 * 64; // [SEQ*64][128]

    build_A<<<dim3(SPAD), 128, 0, stream>>>(lm_b, cls, A_pre);
    gemm64<<<dim3(6, SPAD / 64), 256, 0, stream>>>(A_pre, 128, w_in, b_in, SB, 384);
    build_W2<<<dim3(384), 128, 0, stream>>>(w_in, lm_w, W2);
    build_Wout<<<dim3(128), 128, 0, stream>>>(w_out, Wout);
    zero_pooled<<<dim3(8), 1024, 0, stream>>>(pooled);

    patchify<<<dim3((SEQ + 3) / 4, 64), 384, 0, stream>>>(images, Pb);
    gemm_qkv_mfma<<<dim3(6, SEQ), 256, 0, stream>>>(Pb, W2, SB, Qh, Kh, Vt);
    attention_mfma<<<dim3(SEQ * 8), 64, 0, stream>>>(Qh, Kh, Vt, Obuf);
    gemm_out_ln_pool<<<dim3(SEQ), 256, 0, stream>>>(Obuf, Wout, b_out, ln_g, ln_b, pooled);
    classify<<<dim3(NIMG), 128, 0, stream>>>(pooled, out_w, out_b, out);
}

// Round 7
// 353.456 us; speedup vs baseline: 4.2423x; 1.1121x over previous
//
#include <hip/hip_runtime.h>
#include <math.h>

#define NIMG 64
#define SEQ  2602
#define EMB  128
#define HD   16
#define SPAD 2624    // SEQ padded to multiple of 64
#define KQ   96      // patch K padded 75 -> 96 (multiple of 32)
#define LSQ  104     // LDS row stride (bf16) for KQ  (208 B, 16B-multiple)
#define LSO  136     // LDS row stride (bf16) for K=128 (272 B, 16B-multiple)
#define PST  80      // LDS row stride (bf16) for P (40 words)

typedef float f32x4 __attribute__((ext_vector_type(4)));
typedef short short8 __attribute__((ext_vector_type(8)));

__device__ __forceinline__ unsigned short f2bf(float f) {
    union { float f; unsigned int u; } v; v.f = f;
    unsigned int r = (v.u + 0x7fffu + ((v.u >> 16) & 1u)) >> 16;   // RNE
    return (unsigned short)r;
}

// ---------------------------------------------------------------------------
// A_pre[s][e]: s==0 -> cls + PE(0); 1<=s<SEQ -> lm_b + PE(s); else 0.
// ---------------------------------------------------------------------------
__global__ __launch_bounds__(128) void build_A(
    const float* __restrict__ lm_b, const float* __restrict__ cls,
    float* __restrict__ A) {
    const int s = blockIdx.x, e = threadIdx.x;
    const bool odd = e & 1;
    float v;
    if (s == 0) {
        v = cls[e] + (odd ? 1.0f : 0.0f);
    } else if (s < SEQ) {
        float pfac = powf(10000.0f, -(float)(e & ~1) / 128.0f);
        float ang = (float)s * pfac;
        v = lm_b[e] + (odd ? cosf(ang) : sinf(ang));
    } else {
        v = 0.0f;
    }
    A[(size_t)s * 128 + e] = v;
}

// ---------------------------------------------------------------------------
// W2[j][f] = sum_e w_in[j][e]*lm_w[e][f], f<75; zero-pad to KQ. bf16 out.
// ---------------------------------------------------------------------------
__global__ __launch_bounds__(128) void build_W2(
    const float* __restrict__ w_in, const float* __restrict__ lm_w,
    unsigned short* __restrict__ W2) {
    const int j = blockIdx.x, f = threadIdx.x;
    if (f >= KQ) return;
    float acc = 0.0f;
    if (f < 75) {
        for (int e = 0; e < 128; ++e)
            acc += w_in[j * 128 + e] * lm_w[e * 75 + f];
    }
    W2[j * KQ + f] = f2bf(acc);
}

__global__ __launch_bounds__(128) void build_Wout(
    const float* __restrict__ w_out, unsigned short* __restrict__ Wo) {
    const int j = blockIdx.x, e = threadIdx.x;
    Wo[j * 128 + e] = f2bf(w_out[j * 128 + e]);
}

__global__ __launch_bounds__(1024) void zero_pooled(float* __restrict__ p) {
    p[blockIdx.x * 1024 + threadIdx.x] = 0.0f;
}

// ---------------------------------------------------------------------------
// Patchify full sequence to bf16: Pb[s][l][f], f<KQ (pad + cls row = 0).
// ---------------------------------------------------------------------------
__global__ __launch_bounds__(384) void patchify(
    const float* __restrict__ images, unsigned short* __restrict__ Pb) {
    const int l = blockIdx.y;
    const int s = blockIdx.x * 4 + threadIdx.x / KQ;
    const int f = threadIdx.x % KQ;
    if (s >= SEQ) return;
    float v = 0.0f;
    if (s > 0 && f < 75) {
        int p = s - 1;
        int i = p / 51, j = p % 51;
        int c = f / 25, rr = (f % 25) / 5, cc = f % 5;
        v = images[(((size_t)l * 3 + c) * 255 + (i * 5 + rr)) * 255 + (j * 5 + cc)];
    }
    Pb[((size_t)s * 64 + l) * KQ + f] = f2bf(v);
}

// ---------------------------------------------------------------------------
// MFMA QKV GEMM. 1-D grid, XCD-swizzled so all 6 n-blocks of a token share an
// XCD (L2 reuse of the A-tile). Epilogue assembles the 64x64 tile in LDS in
// destination order (XOR-swizzled 16B chunks; quad-conflict-free) then does
// 2 coalesced dwordx4 stores/thread. All of Q/K/V land in [s][8][64][16]
// (Q pre-scaled by 0.25).
// ---------------------------------------------------------------------------
__global__ __launch_bounds__(256) void gemm_qkv_mfma(
    const unsigned short* __restrict__ P, const unsigned short* __restrict__ W2,
    const float* __restrict__ SB, unsigned short* __restrict__ Qh,
    unsigned short* __restrict__ Kh, unsigned short* __restrict__ Vh) {
    __shared__ __align__(16) unsigned short As[64 * LSQ];
    __shared__ __align__(16) unsigned short Bs[64 * LSQ];
    const int tid = threadIdx.x;
    const int xcd = blockIdx.x & 7;
    const int q_ = blockIdx.x >> 3;            // 0..1955
    const int s = xcd + (q_ / 6) * 8;
    const int j = q_ % 6;
    if (s >= SEQ) return;
    const int bm = s * 64;
    const int bn = j * 64;
    const int wv = tid >> 6, lane = tid & 63, quad = lane >> 4, col = lane & 15;

    #pragma unroll
    for (int t = 0; t < 3; ++t) {
        int q = tid + t * 256;
        int row = q & 63, c = q >> 6;
        *(float4*)&As[row * LSQ + c * 8] =
            *(const float4*)(P + (size_t)(bm + row) * KQ + c * 8);
        *(float4*)&Bs[row * LSQ + c * 8] =
            *(const float4*)(W2 + (size_t)(bn + row) * KQ + c * 8);
    }
    __syncthreads();

    f32x4 acc[4] = {};
    const int mrow = wv * 16 + col;
    #pragma unroll
    for (int ks = 0; ks < 3; ++ks) {
        const int k0 = ks * 32 + quad * 8;
        short8 a = *(const short8*)&As[mrow * LSQ + k0];
        #pragma unroll
        for (int nt = 0; nt < 4; ++nt) {
            short8 b = *(const short8*)&Bs[(nt * 16 + col) * LSQ + k0];
            acc[nt] = __builtin_amdgcn_mfma_f32_16x16x32_bf16(a, b, acc[nt], 0, 0, 0);
        }
    }

    const float scale = (j < 2) ? 0.25f : 1.0f;
    unsigned short* dst = (j < 2) ? (Qh + (size_t)s * 8192 + j * 4096)
                        : (j < 4) ? (Kh + (size_t)s * 8192 + (j - 2) * 4096)
                                  : (Vh + (size_t)s * 8192 + (j - 4) * 4096);
    const float* brow = SB + (size_t)s * 384 + bn;

    __syncthreads();                 // all waves done reading As
    unsigned short* tile = As;       // reuse 8 KB of As for assembly
    #pragma unroll
    for (int nt = 0; nt < 4; ++nt) {
        float bv = brow[nt * 16 + col];
        #pragma unroll
        for (int r = 0; r < 4; ++r) {
            int l = wv * 16 + quad * 4 + r;
            int cc = (l * 2 + (col >> 3)) ^ ((l >> 2) & 3);
            tile[nt * 1024 + cc * 8 + (col & 7)] = f2bf((acc[nt][r] + bv) * scale);
        }
    }
    __syncthreads();
    #pragma unroll
    for (int t = 0; t < 2; ++t) {
        int c = tid + t * 256;                 // dest chunk 0..511
        int nt = c >> 7, cc = c & 127, l = cc >> 1;
        int cs = cc ^ ((l >> 2) & 3);
        *(short8*)(dst + (size_t)c * 8) = *(const short8*)&tile[nt * 1024 + cs * 8];
    }
}

// ---------------------------------------------------------------------------
// MFMA attention over the IMAGE axis. One wave per (s,h). V arrives row-major
// [64][16] and is LDS-transposed (conflict-free). P and O go through LDS with
// XOR-swizzled 16B chunks. O stored head-major [s][8][64][16], coalesced.
// ---------------------------------------------------------------------------
__global__ __launch_bounds__(64) void attention_mfma(
    const unsigned short* __restrict__ Qh, const unsigned short* __restrict__ Kh,
    const unsigned short* __restrict__ Vh, unsigned short* __restrict__ O) {
    __shared__ __align__(16) unsigned short Plds[64 * PST];
    __shared__ __align__(16) unsigned short Vlds[16 * 72];
    __shared__ __align__(16) unsigned short Olds[64 * 16];
    const size_t sh = blockIdx.x;
    const int lane = threadIdx.x, quad = lane >> 4, col = lane & 15;
    const unsigned short* qb = Qh + sh * 1024;
    const unsigned short* kb = Kh + sh * 1024;
    const unsigned short* vb = Vh + sh * 1024;

    // stage V transposed: lane loads row l=lane (32 B), scatters to Vlds[d][l]
    short8 v0 = *(const short8*)(vb + lane * 16);
    short8 v1 = *(const short8*)(vb + lane * 16 + 8);
    #pragma unroll
    for (int d = 0; d < 8; ++d) {
        Vlds[d * 72 + lane]       = (unsigned short)v0[d];
        Vlds[(d + 8) * 72 + lane] = (unsigned short)v1[d];
    }

    const int koff = (quad & 1) * 8;
    const short8 z8 = {};
    short8 bfr[4];
    #pragma unroll
    for (int nt = 0; nt < 4; ++nt) {
        short8 t = *(const short8*)(kb + (size_t)(nt * 16 + col) * 16 + koff);
        bfr[nt] = (quad < 2) ? t : z8;
    }

    f32x4 sc[4][4] = {};
    #pragma unroll
    for (int mt = 0; mt < 4; ++mt) {
        short8 t = *(const short8*)(qb + (size_t)(mt * 16 + col) * 16 + koff);
        short8 afr = (quad < 2) ? t : z8;
        #pragma unroll
        for (int nt = 0; nt < 4; ++nt)
            sc[mt][nt] = __builtin_amdgcn_mfma_f32_16x16x32_bf16(afr, bfr[nt], sc[mt][nt], 0, 0, 0);
    }

    // softmax per row M = mt*16 + quad*4 + r; P -> LDS (chunk-swizzled)
    float inv[4][4];
    #pragma unroll
    for (int mt = 0; mt < 4; ++mt) {
        #pragma unroll
        for (int r = 0; r < 4; ++r) {
            float mx = sc[mt][0][r];
            #pragma unroll
            for (int nt = 1; nt < 4; ++nt) mx = fmaxf(mx, sc[mt][nt][r]);
            #pragma unroll
            for (int off = 1; off < 16; off <<= 1) mx = fmaxf(mx, __shfl_xor(mx, off));
            float sum = 0.0f;
            float p[4];
            #pragma unroll
            for (int nt = 0; nt < 4; ++nt) { p[nt] = __expf(sc[mt][nt][r] - mx); sum += p[nt]; }
            #pragma unroll
            for (int off = 1; off < 16; off <<= 1) sum += __shfl_xor(sum, off);
            inv[mt][r] = 1.0f / sum;
            const int M = mt * 16 + quad * 4 + r;
            const int swz = (M >> 2) & 7;
            #pragma unroll
            for (int nt = 0; nt < 4; ++nt) {
                int jc = (nt * 2 + (col >> 3)) ^ swz;
                Plds[M * PST + jc * 8 + (col & 7)] = f2bf(p[nt]);
            }
        }
    }
    __syncthreads();

    short8 vfr[2];
    #pragma unroll
    for (int ks = 0; ks < 2; ++ks)
        vfr[ks] = *(const short8*)&Vlds[col * 72 + ks * 32 + quad * 8];

    #pragma unroll
    for (int mt = 0; mt < 4; ++mt) {
        f32x4 o = {};
        const int m = mt * 16 + col;
        const int swz = (m >> 2) & 7;
        #pragma unroll
        for (int ks = 0; ks < 2; ++ks) {
            int kcs = (ks * 4 + quad) ^ swz;
            short8 pa = *(const short8*)&Plds[m * PST + kcs * 8];
            o = __builtin_amdgcn_mfma_f32_16x16x32_bf16(pa, vfr[ks], o, 0, 0, 0);
        }
        #pragma unroll
        for (int r = 0; r < 4; ++r) {
            int l = mt * 16 + quad * 4 + r;
            int cc = (l * 2 + (col >> 3)) ^ ((l >> 2) & 3);
            Olds[cc * 8 + (col & 7)] = f2bf(o[r] * inv[mt][r]);
        }
    }
    __syncthreads();

    unsigned short* od = O + sh * 1024;       // [s][8][64][16], 2 KB contiguous
    #pragma unroll
    for (int jj = 0; jj < 2; ++jj) {
        int cc = lane * 2 + jj;
        int cs = cc ^ ((lane >> 2) & 3);
        *(short8*)(od + cc * 8) = *(const short8*)&Olds[cs * 8];
    }
}

// ---------------------------------------------------------------------------
// Fused out-proj + LayerNorm + mean-pool. One block per token s, 256 thr.
// A-tile staged from head-major O [s][8][64][16] (coalesced linear reads).
// ---------------------------------------------------------------------------
__global__ __launch_bounds__(256) void gemm_out_ln_pool(
    const unsigned short* __restrict__ O, const unsigned short* __restrict__ Wo,
    const float* __restrict__ b_out, const float* __restrict__ ln_g,
    const float* __restrict__ ln_b, float* __restrict__ pooled) {
    __shared__ __align__(16) unsigned short As[64 * LSO];
    __shared__ __align__(16) unsigned short Bs[128 * LSO];
    const int tid = threadIdx.x;
    const int s = blockIdx.x;
    const int wv = tid >> 6, lane = tid & 63, quad = lane >> 4, col = lane & 15;

    #pragma unroll
    for (int t = 0; t < 4; ++t) {                 // O: 1024 chunks, source-linear
        int q = tid + t * 256;
        int h = q >> 7, rem = q & 127, l = rem >> 1, jj = rem & 1;
        *(short8*)&As[l * LSO + h * 16 + jj * 8] =
            *(const short8*)(O + (size_t)s * 8192 + (size_t)q * 8);
    }
    #pragma unroll
    for (int t = 0; t < 8; ++t) {                 // Wo rows: 128 x 16 chunks
        int q = tid + t * 256;
        int row = q >> 4, c = q & 15;
        *(float4*)&Bs[row * LSO + c * 8] =
            *(const float4*)(Wo + (size_t)row * 128 + c * 8);
    }
    __syncthreads();

    f32x4 acc[8] = {};
    const int mrow = wv * 16 + col;
    #pragma unroll
    for (int ks = 0; ks < 4; ++ks) {
        const int k0 = ks * 32 + quad * 8;
        short8 a = *(const short8*)&As[mrow * LSO + k0];
        #pragma unroll
        for (int nt = 0; nt < 8; ++nt) {
            short8 b = *(const short8*)&Bs[(nt * 16 + col) * LSO + k0];
            acc[nt] = __builtin_amdgcn_mfma_f32_16x16x32_bf16(a, b, acc[nt], 0, 0, 0);
        }
    }

    float gch[8], bch[8], boch[8];
    #pragma unroll
    for (int nt = 0; nt < 8; ++nt) {
        int ch = nt * 16 + col;
        gch[nt] = ln_g[ch]; bch[nt] = ln_b[ch]; boch[nt] = b_out[ch];
    }
    const int l0 = wv * 16 + quad * 4;
    #pragma unroll
    for (int r = 0; r < 4; ++r) {
        float yv[8];
        float s1 = 0.0f, s2 = 0.0f;
        #pragma unroll
        for (int nt = 0; nt < 8; ++nt) {
            yv[nt] = acc[nt][r] + boch[nt];
            s1 += yv[nt]; s2 += yv[nt] * yv[nt];
        }
        #pragma unroll
        for (int off = 1; off < 16; off <<= 1) {
            s1 += __shfl_xor(s1, off);
            s2 += __shfl_xor(s2, off);
        }
        float mu = s1 * (1.0f / 128.0f);
        float var = s2 * (1.0f / 128.0f) - mu * mu;
        float rinv = rsqrtf(var + 1e-5f);
        #pragma unroll
        for (int nt = 0; nt < 8; ++nt) {
            float v = (yv[nt] - mu) * rinv * gch[nt] + bch[nt];
            atomicAdd(&pooled[(l0 + r) * 128 + nt * 16 + col], v);
        }
    }
}

// ---------------------------------------------------------------------------
// fp32 GEMM (precompute only, SB = A_pre @ w_in^T + b_in).
// ---------------------------------------------------------------------------
__global__ __launch_bounds__(256) void gemm64(
    const float* __restrict__ A, int lda, const float* __restrict__ B,
    const float* __restrict__ bias, float* __restrict__ C, int ldc) {
    __shared__ float As[64 * 68];
    __shared__ float Bs[64 * 68];
    const int bm = blockIdx.y * 64;
    const int bn = blockIdx.x * 64;
    const int tid = threadIdx.x;
    const int tx = tid & 15, ty = tid >> 4;

    float acc[4][4] = {};

    for (int kk = 0; kk < 128; kk += 64) {
        __syncthreads();
        #pragma unroll
        for (int t = 0; t < 4; ++t) {
            int q = tid + t * 256;
            int row = q & 63, c4 = (q >> 6) << 2;
            float4 va = *(const float4*)(A + (size_t)(bm + row) * lda + kk + c4);
            As[(c4 + 0) * 68 + row] = va.x;
            As[(c4 + 1) * 68 + row] = va.y;
            As[(c4 + 2) * 68 + row] = va.z;
            As[(c4 + 3) * 68 + row] = va.w;
            float4 vb = *(const float4*)(B + (size_t)(bn + row) * 128 + kk + c4);
            Bs[(c4 + 0) * 68 + row] = vb.x;
            Bs[(c4 + 1) * 68 + row] = vb.y;
            Bs[(c4 + 2) * 68 + row] = vb.z;
            Bs[(c4 + 3) * 68 + row] = vb.w;
        }
        __syncthreads();
        #pragma unroll 4
        for (int k = 0; k < 64; ++k) {
            float4 av = *(const float4*)&As[k * 68 + (ty << 2)];
            float4 bv = *(const float4*)&Bs[k * 68 + (tx << 2)];
            acc[0][0] += av.x*bv.x; acc[0][1] += av.x*bv.y; acc[0][2] += av.x*bv.z; acc[0][3] += av.x*bv.w;
            acc[1][0] += av.y*bv.x; acc[1][1] += av.y*bv.y; acc[1][2] += av.y*bv.z; acc[1][3] += av.y*bv.w;
            acc[2][0] += av.z*bv.x; acc[2][1] += av.z*bv.y; acc[2][2] += av.z*bv.z; acc[2][3] += av.z*bv.w;
            acc[3][0] += av.w*bv.x; acc[3][1] += av.w*bv.y; acc[3][2] += av.w*bv.z; acc[3][3] += av.w*bv.w;
        }
    }

    float4 bv = *(const float4*)(bias + bn + (tx << 2));
    #pragma unroll
    for (int i = 0; i < 4; ++i) {
        float4 r;
        r.x = acc[i][0] + bv.x; r.y = acc[i][1] + bv.y;
        r.z = acc[i][2] + bv.z; r.w = acc[i][3] + bv.w;
        *(float4*)(C + (size_t)(bm + (ty << 2) + i) * ldc + bn + (tx << 2)) = r;
    }
}

__global__ __launch_bounds__(128) void classify(
    const float* __restrict__ pooled, const float* __restrict__ out_w,
    const float* __restrict__ out_b, float* __restrict__ out) {
    const int l = blockIdx.x, e = threadIdx.x;
    __shared__ float sp[EMB];
    sp[e] = pooled[l * EMB + e] * (1.0f / (float)SEQ);
    __syncthreads();
    if (e < 3) {
        float acc = out_b[e];
        #pragma unroll 16
        for (int k = 0; k < EMB; ++k) acc += sp[k] * out_w[e * EMB + k];
        out[l * 3 + e] = acc;
    }
}

extern "C" void kernel_launch(void* const* d_in, const int* in_sizes, int n_in,
                              void* d_out, int out_size, void* d_ws, size_t ws_size,
                              hipStream_t stream) {
    const float* images = (const float*)d_in[0];
    const float* lm_w   = (const float*)d_in[1];
    const float* lm_b   = (const float*)d_in[2];
    const float* cls    = (const float*)d_in[3];
    const float* w_in   = (const float*)d_in[4];
    const float* b_in   = (const float*)d_in[5];
    const float* w_out  = (const float*)d_in[6];
    const float* b_out  = (const float*)d_in[7];
    const float* ln_g   = (const float*)d_in[8];
    const float* ln_b   = (const float*)d_in[9];
    const float* out_w  = (const float*)d_in[10];
    const float* out_b  = (const float*)d_in[11];
    float* out = (float*)d_out;

    // Workspace (~208 MB of 256 MiB), all regions 16B-aligned:
    float* SB     = (float*)d_ws;                         // [SPAD][384] f32
    float* A_pre  = SB + (size_t)SPAD * 384;              // [SPAD][128] f32
    float* pooled = A_pre + (size_t)SPAD * 128;           // [64][128] f32
    unsigned short* W2   = (unsigned short*)(pooled + 64 * 128); // [384][KQ]
    unsigned short* Wout = W2 + (size_t)384 * KQ;         // [128][128]
    unsigned short* Pb   = Wout + 128 * 128;              // [SEQ][64][KQ]
    unsigned short* Qh   = Pb + (size_t)SEQ * 64 * KQ;    // [SEQ][8][64][16]
    unsigned short* Kh   = Qh + (size_t)SEQ * 8192;       // [SEQ][8][64][16]
    unsigned short* Vh   = Kh + (size_t)SEQ * 8192;       // [SEQ][8][64][16]
    unsigned short* Obuf = Vh + (size_t)SEQ * 8192;       // [SEQ][8][64][16]

    build_A<<<dim3(SPAD), 128, 0, stream>>>(lm_b, cls, A_pre);
    gemm64<<<dim3(6, SPAD / 64), 256, 0, stream>>>(A_pre, 128, w_in, b_in, SB, 384);
    build_W2<<<dim3(384), 128, 0, stream>>>(w_in, lm_w, W2);
    build_Wout<<<dim3(128), 128, 0, stream>>>(w_out, Wout);
    zero_pooled<<<dim3(8), 1024, 0, stream>>>(pooled);

    patchify<<<dim3((SEQ + 3) / 4, 64), 384, 0, stream>>>(images, Pb);
    gemm_qkv_mfma<<<dim3(8 * 326 * 6), 256, 0, stream>>>(Pb, W2, SB, Qh, Kh, Vh);
    attention_mfma<<<dim3(SEQ * 8), 64, 0, stream>>>(Qh, Kh, Vh, Obuf);
    gemm_out_ln_pool<<<dim3(SEQ), 256, 0, stream>>>(Obuf, Wout, b_out, ln_g, ln_b, pooled);
    classify<<<dim3(NIMG), 128, 0, stream>>>(pooled, out_w, out_b, out);
}

// Round 8
// 303.791 us; speedup vs baseline: 4.9358x; 1.1635x over previous
//
#include <hip/hip_runtime.h>
#include <math.h>

#define NIMG 64
#define SEQ  2602
#define EMB  128
#define HD   16
#define SPAD 2624    // SEQ padded to multiple of 64
#define KQ   96      // patch K padded 75 -> 96 (multiple of 32)
#define LSQ  104     // LDS row stride (bf16) for KQ  (208 B, 16B-multiple)
#define LSO  136     // LDS row stride (bf16) for K=128 (272 B, 16B-multiple)
#define PST  80      // LDS row stride (bf16) for P (40 words)
#define TOK  8       // tokens per gemm_out_ln_pool block

typedef float f32x4 __attribute__((ext_vector_type(4)));
typedef short short8 __attribute__((ext_vector_type(8)));

__device__ __forceinline__ unsigned short f2bf(float f) {
    union { float f; unsigned int u; } v; v.f = f;
    unsigned int r = (v.u + 0x7fffu + ((v.u >> 16) & 1u)) >> 16;   // RNE
    return (unsigned short)r;
}

// ---------------------------------------------------------------------------
// A_pre[s][e]: s==0 -> cls + PE(0); 1<=s<SEQ -> lm_b + PE(s); else 0.
// ---------------------------------------------------------------------------
__global__ __launch_bounds__(128) void build_A(
    const float* __restrict__ lm_b, const float* __restrict__ cls,
    float* __restrict__ A) {
    const int s = blockIdx.x, e = threadIdx.x;
    const bool odd = e & 1;
    float v;
    if (s == 0) {
        v = cls[e] + (odd ? 1.0f : 0.0f);
    } else if (s < SEQ) {
        float pfac = powf(10000.0f, -(float)(e & ~1) / 128.0f);
        float ang = (float)s * pfac;
        v = lm_b[e] + (odd ? cosf(ang) : sinf(ang));
    } else {
        v = 0.0f;
    }
    A[(size_t)s * 128 + e] = v;
}

// ---------------------------------------------------------------------------
// W2[j][f] = sum_e w_in[j][e]*lm_w[e][f], f<75; zero-pad to KQ. bf16 out.
// ---------------------------------------------------------------------------
__global__ __launch_bounds__(128) void build_W2(
    const float* __restrict__ w_in, const float* __restrict__ lm_w,
    unsigned short* __restrict__ W2) {
    const int j = blockIdx.x, f = threadIdx.x;
    if (f >= KQ) return;
    float acc = 0.0f;
    if (f < 75) {
        for (int e = 0; e < 128; ++e)
            acc += w_in[j * 128 + e] * lm_w[e * 75 + f];
    }
    W2[j * KQ + f] = f2bf(acc);
}

__global__ __launch_bounds__(128) void build_Wout(
    const float* __restrict__ w_out, unsigned short* __restrict__ Wo) {
    const int j = blockIdx.x, e = threadIdx.x;
    Wo[j * 128 + e] = f2bf(w_out[j * 128 + e]);
}

__global__ __launch_bounds__(1024) void zero_pooled(float* __restrict__ p) {
    p[blockIdx.x * 1024 + threadIdx.x] = 0.0f;
}

// ---------------------------------------------------------------------------
// Patchify full sequence to bf16: Pb[s][l][f], f<KQ (pad + cls row = 0).
// ---------------------------------------------------------------------------
__global__ __launch_bounds__(384) void patchify(
    const float* __restrict__ images, unsigned short* __restrict__ Pb) {
    const int l = blockIdx.y;
    const int s = blockIdx.x * 4 + threadIdx.x / KQ;
    const int f = threadIdx.x % KQ;
    if (s >= SEQ) return;
    float v = 0.0f;
    if (s > 0 && f < 75) {
        int p = s - 1;
        int i = p / 51, j = p % 51;
        int c = f / 25, rr = (f % 25) / 5, cc = f % 5;
        v = images[(((size_t)l * 3 + c) * 255 + (i * 5 + rr)) * 255 + (j * 5 + cc)];
    }
    Pb[((size_t)s * 64 + l) * KQ + f] = f2bf(v);
}

// ---------------------------------------------------------------------------
// MFMA QKV GEMM. 1-D grid, XCD-swizzled so all 6 n-blocks of a token share an
// XCD (L2 reuse of the A-tile). Epilogue assembles the 64x64 tile in LDS in
// destination order (XOR-swizzled 16B chunks; quad-conflict-free) then does
// 2 coalesced dwordx4 stores/thread. All of Q/K/V land in [s][8][64][16]
// (Q pre-scaled by 0.25).
// ---------------------------------------------------------------------------
__global__ __launch_bounds__(256) void gemm_qkv_mfma(
    const unsigned short* __restrict__ P, const unsigned short* __restrict__ W2,
    const float* __restrict__ SB, unsigned short* __restrict__ Qh,
    unsigned short* __restrict__ Kh, unsigned short* __restrict__ Vh) {
    __shared__ __align__(16) unsigned short As[64 * LSQ];
    __shared__ __align__(16) unsigned short Bs[64 * LSQ];
    const int tid = threadIdx.x;
    const int xcd = blockIdx.x & 7;
    const int q_ = blockIdx.x >> 3;            // 0..1955
    const int s = xcd + (q_ / 6) * 8;
    const int j = q_ % 6;
    if (s >= SEQ) return;
    const int bm = s * 64;
    const int bn = j * 64;
    const int wv = tid >> 6, lane = tid & 63, quad = lane >> 4, col = lane & 15;

    #pragma unroll
    for (int t = 0; t < 3; ++t) {
        int q = tid + t * 256;
        int row = q & 63, c = q >> 6;
        *(float4*)&As[row * LSQ + c * 8] =
            *(const float4*)(P + (size_t)(bm + row) * KQ + c * 8);
        *(float4*)&Bs[row * LSQ + c * 8] =
            *(const float4*)(W2 + (size_t)(bn + row) * KQ + c * 8);
    }
    __syncthreads();

    f32x4 acc[4] = {};
    const int mrow = wv * 16 + col;
    #pragma unroll
    for (int ks = 0; ks < 3; ++ks) {
        const int k0 = ks * 32 + quad * 8;
        short8 a = *(const short8*)&As[mrow * LSQ + k0];
        #pragma unroll
        for (int nt = 0; nt < 4; ++nt) {
            short8 b = *(const short8*)&Bs[(nt * 16 + col) * LSQ + k0];
            acc[nt] = __builtin_amdgcn_mfma_f32_16x16x32_bf16(a, b, acc[nt], 0, 0, 0);
        }
    }

    const float scale = (j < 2) ? 0.25f : 1.0f;
    unsigned short* dst = (j < 2) ? (Qh + (size_t)s * 8192 + j * 4096)
                        : (j < 4) ? (Kh + (size_t)s * 8192 + (j - 2) * 4096)
                                  : (Vh + (size_t)s * 8192 + (j - 4) * 4096);
    const float* brow = SB + (size_t)s * 384 + bn;

    __syncthreads();                 // all waves done reading As
    unsigned short* tile = As;       // reuse 8 KB of As for assembly
    #pragma unroll
    for (int nt = 0; nt < 4; ++nt) {
        float bv = brow[nt * 16 + col];
        #pragma unroll
        for (int r = 0; r < 4; ++r) {
            int l = wv * 16 + quad * 4 + r;
            int cc = (l * 2 + (col >> 3)) ^ ((l >> 2) & 3);
            tile[nt * 1024 + cc * 8 + (col & 7)] = f2bf((acc[nt][r] + bv) * scale);
        }
    }
    __syncthreads();
    #pragma unroll
    for (int t = 0; t < 2; ++t) {
        int c = tid + t * 256;                 // dest chunk 0..511
        int nt = c >> 7, cc = c & 127, l = cc >> 1;
        int cs = cc ^ ((l >> 2) & 3);
        *(short8*)(dst + (size_t)c * 8) = *(const short8*)&tile[nt * 1024 + cs * 8];
    }
}

// ---------------------------------------------------------------------------
// MFMA attention over the IMAGE axis. One wave per (s,h). V arrives row-major
// [64][16] and is LDS-transposed (conflict-free). P and O go through LDS with
// XOR-swizzled 16B chunks. O stored head-major [s][8][64][16], coalesced.
// ---------------------------------------------------------------------------
__global__ __launch_bounds__(64) void attention_mfma(
    const unsigned short* __restrict__ Qh, const unsigned short* __restrict__ Kh,
    const unsigned short* __restrict__ Vh, unsigned short* __restrict__ O) {
    __shared__ __align__(16) unsigned short Plds[64 * PST];
    __shared__ __align__(16) unsigned short Vlds[16 * 72];
    __shared__ __align__(16) unsigned short Olds[64 * 16];
    const size_t sh = blockIdx.x;
    const int lane = threadIdx.x, quad = lane >> 4, col = lane & 15;
    const unsigned short* qb = Qh + sh * 1024;
    const unsigned short* kb = Kh + sh * 1024;
    const unsigned short* vb = Vh + sh * 1024;

    // stage V transposed: lane loads row l=lane (32 B), scatters to Vlds[d][l]
    short8 v0 = *(const short8*)(vb + lane * 16);
    short8 v1 = *(const short8*)(vb + lane * 16 + 8);
    #pragma unroll
    for (int d = 0; d < 8; ++d) {
        Vlds[d * 72 + lane]       = (unsigned short)v0[d];
        Vlds[(d + 8) * 72 + lane] = (unsigned short)v1[d];
    }

    const int koff = (quad & 1) * 8;
    const short8 z8 = {};
    short8 bfr[4];
    #pragma unroll
    for (int nt = 0; nt < 4; ++nt) {
        short8 t = *(const short8*)(kb + (size_t)(nt * 16 + col) * 16 + koff);
        bfr[nt] = (quad < 2) ? t : z8;
    }

    f32x4 sc[4][4] = {};
    #pragma unroll
    for (int mt = 0; mt < 4; ++mt) {
        short8 t = *(const short8*)(qb + (size_t)(mt * 16 + col) * 16 + koff);
        short8 afr = (quad < 2) ? t : z8;
        #pragma unroll
        for (int nt = 0; nt < 4; ++nt)
            sc[mt][nt] = __builtin_amdgcn_mfma_f32_16x16x32_bf16(afr, bfr[nt], sc[mt][nt], 0, 0, 0);
    }

    // softmax per row M = mt*16 + quad*4 + r; P -> LDS (chunk-swizzled)
    float inv[4][4];
    #pragma unroll
    for (int mt = 0; mt < 4; ++mt) {
        #pragma unroll
        for (int r = 0; r < 4; ++r) {
            float mx = sc[mt][0][r];
            #pragma unroll
            for (int nt = 1; nt < 4; ++nt) mx = fmaxf(mx, sc[mt][nt][r]);
            #pragma unroll
            for (int off = 1; off < 16; off <<= 1) mx = fmaxf(mx, __shfl_xor(mx, off));
            float sum = 0.0f;
            float p[4];
            #pragma unroll
            for (int nt = 0; nt < 4; ++nt) { p[nt] = __expf(sc[mt][nt][r] - mx); sum += p[nt]; }
            #pragma unroll
            for (int off = 1; off < 16; off <<= 1) sum += __shfl_xor(sum, off);
            inv[mt][r] = 1.0f / sum;
            const int M = mt * 16 + quad * 4 + r;
            const int swz = (M >> 2) & 7;
            #pragma unroll
            for (int nt = 0; nt < 4; ++nt) {
                int jc = (nt * 2 + (col >> 3)) ^ swz;
                Plds[M * PST + jc * 8 + (col & 7)] = f2bf(p[nt]);
            }
        }
    }
    __syncthreads();

    short8 vfr[2];
    #pragma unroll
    for (int ks = 0; ks < 2; ++ks)
        vfr[ks] = *(const short8*)&Vlds[col * 72 + ks * 32 + quad * 8];

    #pragma unroll
    for (int mt = 0; mt < 4; ++mt) {
        f32x4 o = {};
        const int m = mt * 16 + col;
        const int swz = (m >> 2) & 7;
        #pragma unroll
        for (int ks = 0; ks < 2; ++ks) {
            int kcs = (ks * 4 + quad) ^ swz;
            short8 pa = *(const short8*)&Plds[m * PST + kcs * 8];
            o = __builtin_amdgcn_mfma_f32_16x16x32_bf16(pa, vfr[ks], o, 0, 0, 0);
        }
        #pragma unroll
        for (int r = 0; r < 4; ++r) {
            int l = mt * 16 + quad * 4 + r;
            int cc = (l * 2 + (col >> 3)) ^ ((l >> 2) & 3);
            Olds[cc * 8 + (col & 7)] = f2bf(o[r] * inv[mt][r]);
        }
    }
    __syncthreads();

    unsigned short* od = O + sh * 1024;       // [s][8][64][16], 2 KB contiguous
    #pragma unroll
    for (int jj = 0; jj < 2; ++jj) {
        int cc = lane * 2 + jj;
        int cs = cc ^ ((lane >> 2) & 3);
        *(short8*)(od + cc * 8) = *(const short8*)&Olds[cs * 8];
    }
}

// ---------------------------------------------------------------------------
// Fused out-proj + LayerNorm + mean-pool, TOK tokens per block (G12: atomics
// amortized across tokens; register accumulator, one atomic set per block).
// O-tiles double-buffered in LDS; one __syncthreads per token.
// ---------------------------------------------------------------------------
__global__ __launch_bounds__(256) void gemm_out_ln_pool(
    const unsigned short* __restrict__ O, const unsigned short* __restrict__ Wo,
    const float* __restrict__ b_out, const float* __restrict__ ln_g,
    const float* __restrict__ ln_b, float* __restrict__ pooled) {
    __shared__ __align__(16) unsigned short As[2][64 * LSO];
    __shared__ __align__(16) unsigned short Bs[128 * LSO];
    const int tid = threadIdx.x;
    const int s0 = blockIdx.x * TOK;
    const int wv = tid >> 6, lane = tid & 63, quad = lane >> 4, col = lane & 15;

    #pragma unroll
    for (int t = 0; t < 8; ++t) {                 // Wo rows: 128 x 16 chunks
        int q = tid + t * 256;
        int row = q >> 4, c = q & 15;
        *(float4*)&Bs[row * LSO + c * 8] =
            *(const float4*)(Wo + (size_t)row * 128 + c * 8);
    }
    #pragma unroll
    for (int t = 0; t < 4; ++t) {                 // token s0 -> As[0]
        int q = tid + t * 256;
        int h = q >> 7, rem = q & 127, l = rem >> 1, jj = rem & 1;
        *(short8*)&As[0][l * LSO + h * 16 + jj * 8] =
            *(const short8*)(O + (size_t)s0 * 8192 + (size_t)q * 8);
    }
    __syncthreads();

    float gch[8], bch[8], boch[8];
    #pragma unroll
    for (int nt = 0; nt < 8; ++nt) {
        int ch = nt * 16 + col;
        gch[nt] = ln_g[ch]; bch[nt] = ln_b[ch]; boch[nt] = b_out[ch];
    }
    const int mrow = wv * 16 + col;
    const int l0 = wv * 16 + quad * 4;
    const int nT = (SEQ - s0 < TOK) ? (SEQ - s0) : TOK;
    float accum[8][4] = {};

    for (int tt = 0; tt < nT; ++tt) {
        if (tt + 1 < nT) {                        // prefetch next token
            const size_t sn = s0 + tt + 1;
            #pragma unroll
            for (int t = 0; t < 4; ++t) {
                int q = tid + t * 256;
                int h = q >> 7, rem = q & 127, l = rem >> 1, jj = rem & 1;
                *(short8*)&As[(tt + 1) & 1][l * LSO + h * 16 + jj * 8] =
                    *(const short8*)(O + sn * 8192 + (size_t)q * 8);
            }
        }
        const unsigned short* Ac = As[tt & 1];
        f32x4 acc[8] = {};
        #pragma unroll
        for (int ks = 0; ks < 4; ++ks) {
            const int k0 = ks * 32 + quad * 8;
            short8 a = *(const short8*)&Ac[mrow * LSO + k0];
            #pragma unroll
            for (int nt = 0; nt < 8; ++nt) {
                short8 b = *(const short8*)&Bs[(nt * 16 + col) * LSO + k0];
                acc[nt] = __builtin_amdgcn_mfma_f32_16x16x32_bf16(a, b, acc[nt], 0, 0, 0);
            }
        }
        #pragma unroll
        for (int r = 0; r < 4; ++r) {
            float yv[8];
            float s1 = 0.0f, s2 = 0.0f;
            #pragma unroll
            for (int nt = 0; nt < 8; ++nt) {
                yv[nt] = acc[nt][r] + boch[nt];
                s1 += yv[nt]; s2 += yv[nt] * yv[nt];
            }
            #pragma unroll
            for (int off = 1; off < 16; off <<= 1) {
                s1 += __shfl_xor(s1, off);
                s2 += __shfl_xor(s2, off);
            }
            float mu = s1 * (1.0f / 128.0f);
            float var = s2 * (1.0f / 128.0f) - mu * mu;
            float rinv = rsqrtf(var + 1e-5f);
            #pragma unroll
            for (int nt = 0; nt < 8; ++nt)
                accum[nt][r] += (yv[nt] - mu) * rinv * gch[nt] + bch[nt];
        }
        __syncthreads();
    }

    #pragma unroll
    for (int nt = 0; nt < 8; ++nt)
        #pragma unroll
        for (int r = 0; r < 4; ++r)
            atomicAdd(&pooled[(l0 + r) * 128 + nt * 16 + col], accum[nt][r]);
}

// ---------------------------------------------------------------------------
// fp32 GEMM (precompute only, SB = A_pre @ w_in^T + b_in).
// ---------------------------------------------------------------------------
__global__ __launch_bounds__(256) void gemm64(
    const float* __restrict__ A, int lda, const float* __restrict__ B,
    const float* __restrict__ bias, float* __restrict__ C, int ldc) {
    __shared__ float As[64 * 68];
    __shared__ float Bs[64 * 68];
    const int bm = blockIdx.y * 64;
    const int bn = blockIdx.x * 64;
    const int tid = threadIdx.x;
    const int tx = tid & 15, ty = tid >> 4;

    float acc[4][4] = {};

    for (int kk = 0; kk < 128; kk += 64) {
        __syncthreads();
        #pragma unroll
        for (int t = 0; t < 4; ++t) {
            int q = tid + t * 256;
            int row = q & 63, c4 = (q >> 6) << 2;
            float4 va = *(const float4*)(A + (size_t)(bm + row) * lda + kk + c4);
            As[(c4 + 0) * 68 + row] = va.x;
            As[(c4 + 1) * 68 + row] = va.y;
            As[(c4 + 2) * 68 + row] = va.z;
            As[(c4 + 3) * 68 + row] = va.w;
            float4 vb = *(const float4*)(B + (size_t)(bn + row) * 128 + kk + c4);
            Bs[(c4 + 0) * 68 + row] = vb.x;
            Bs[(c4 + 1) * 68 + row] = vb.y;
            Bs[(c4 + 2) * 68 + row] = vb.z;
            Bs[(c4 + 3) * 68 + row] = vb.w;
        }
        __syncthreads();
        #pragma unroll 4
        for (int k = 0; k < 64; ++k) {
            float4 av = *(const float4*)&As[k * 68 + (ty << 2)];
            float4 bv = *(const float4*)&Bs[k * 68 + (tx << 2)];
            acc[0][0] += av.x*bv.x; acc[0][1] += av.x*bv.y; acc[0][2] += av.x*bv.z; acc[0][3] += av.x*bv.w;
            acc[1][0] += av.y*bv.x; acc[1][1] += av.y*bv.y; acc[1][2] += av.y*bv.z; acc[1][3] += av.y*bv.w;
            acc[2][0] += av.z*bv.x; acc[2][1] += av.z*bv.y; acc[2][2] += av.z*bv.z; acc[2][3] += av.z*bv.w;
            acc[3][0] += av.w*bv.x; acc[3][1] += av.w*bv.y; acc[3][2] += av.w*bv.z; acc[3][3] += av.w*bv.w;
        }
    }

    float4 bv = *(const float4*)(bias + bn + (tx << 2));
    #pragma unroll
    for (int i = 0; i < 4; ++i) {
        float4 r;
        r.x = acc[i][0] + bv.x; r.y = acc[i][1] + bv.y;
        r.z = acc[i][2] + bv.z; r.w = acc[i][3] + bv.w;
        *(float4*)(C + (size_t)(bm + (ty << 2) + i) * ldc + bn + (tx << 2)) = r;
    }
}

__global__ __launch_bounds__(128) void classify(
    const float* __restrict__ pooled, const float* __restrict__ out_w,
    const float* __restrict__ out_b, float* __restrict__ out) {
    const int l = blockIdx.x, e = threadIdx.x;
    __shared__ float sp[EMB];
    sp[e] = pooled[l * EMB + e] * (1.0f / (float)SEQ);
    __syncthreads();
    if (e < 3) {
        float acc = out_b[e];
        #pragma unroll 16
        for (int k = 0; k < EMB; ++k) acc += sp[k] * out_w[e * EMB + k];
        out[l * 3 + e] = acc;
    }
}

extern "C" void kernel_launch(void* const* d_in, const int* in_sizes, int n_in,
                              void* d_out, int out_size, void* d_ws, size_t ws_size,
                              hipStream_t stream) {
    const float* images = (const float*)d_in[0];
    const float* lm_w   = (const float*)d_in[1];
    const float* lm_b   = (const float*)d_in[2];
    const float* cls    = (const float*)d_in[3];
    const float* w_in   = (const float*)d_in[4];
    const float* b_in   = (const float*)d_in[5];
    const float* w_out  = (const float*)d_in[6];
    const float* b_out  = (const float*)d_in[7];
    const float* ln_g   = (const float*)d_in[8];
    const float* ln_b   = (const float*)d_in[9];
    const float* out_w  = (const float*)d_in[10];
    const float* out_b  = (const float*)d_in[11];
    float* out = (float*)d_out;

    // Workspace (~208 MB of 256 MiB), all regions 16B-aligned:
    float* SB     = (float*)d_ws;                         // [SPAD][384] f32
    float* A_pre  = SB + (size_t)SPAD * 384;              // [SPAD][128] f32
    float* pooled = A_pre + (size_t)SPAD * 128;           // [64][128] f32
    unsigned short* W2   = (unsigned short*)(pooled + 64 * 128); // [384][KQ]
    unsigned short* Wout = W2 + (size_t)384 * KQ;         // [128][128]
    unsigned short* Pb   = Wout + 128 * 128;              // [SEQ][64][KQ]
    unsigned short* Qh   = Pb + (size_t)SEQ * 64 * KQ;    // [SEQ][8][64][16]
    unsigned short* Kh   = Qh + (size_t)SEQ * 8192;       // [SEQ][8][64][16]
    unsigned short* Vh   = Kh + (size_t)SEQ * 8192;       // [SEQ][8][64][16]
    unsigned short* Obuf = Vh + (size_t)SEQ * 8192;       // [SEQ][8][64][16]

    build_A<<<dim3(SPAD), 128, 0, stream>>>(lm_b, cls, A_pre);
    gemm64<<<dim3(6, SPAD / 64), 256, 0, stream>>>(A_pre, 128, w_in, b_in, SB, 384);
    build_W2<<<dim3(384), 128, 0, stream>>>(w_in, lm_w, W2);
    build_Wout<<<dim3(128), 128, 0, stream>>>(w_out, Wout);
    zero_pooled<<<dim3(8), 1024, 0, stream>>>(pooled);

    patchify<<<dim3((SEQ + 3) / 4, 64), 384, 0, stream>>>(images, Pb);
    gemm_qkv_mfma<<<dim3(8 * 326 * 6), 256, 0, stream>>>(Pb, W2, SB, Qh, Kh, Vh);
    attention_mfma<<<dim3(SEQ * 8), 64, 0, stream>>>(Qh, Kh, Vh, Obuf);
    gemm_out_ln_pool<<<dim3((SEQ + TOK - 1) / TOK), 256, 0, stream>>>(
        Obuf, Wout, b_out, ln_g, ln_b, pooled);
    classify<<<dim3(NIMG), 128, 0, stream>>>(pooled, out_w, out_b, out);
}

// Round 9
// 270.813 us; speedup vs baseline: 5.5369x; 1.1218x over previous
//
#include <hip/hip_runtime.h>
#include <math.h>

#define NIMG 64
#define SEQ  2602
#define EMB  128
#define HD   16
#define SPAD 2624    // SEQ padded to multiple of 64
#define KQ   96      // patch K padded 75 -> 96 (multiple of 32)
#define LSQ  104     // LDS row stride (bf16) for KQ  (208 B, 16B-multiple)
#define LSO  136     // LDS row stride (bf16) for K=128 (272 B, 16B-multiple)
#define PST  80      // LDS row stride (bf16) for P (40 words)
#define TOK  8       // tokens per gemm_out_ln_pool block

typedef float f32x4 __attribute__((ext_vector_type(4)));
typedef short short8 __attribute__((ext_vector_type(8)));

// round-half-up bf16 (2 VALU ops; bias 2^-17 relative — negligible)
__device__ __forceinline__ unsigned short f2bf(float f) {
    union { float f; unsigned int u; } v; v.f = f;
    return (unsigned short)((v.u + 0x8000u) >> 16);
}

// ---------------------------------------------------------------------------
// A_pre[s][e]: s==0 -> cls + PE(0); 1<=s<SEQ -> lm_b + PE(s); else 0.
// ---------------------------------------------------------------------------
__global__ __launch_bounds__(128) void build_A(
    const float* __restrict__ lm_b, const float* __restrict__ cls,
    float* __restrict__ A) {
    const int s = blockIdx.x, e = threadIdx.x;
    const bool odd = e & 1;
    float v;
    if (s == 0) {
        v = cls[e] + (odd ? 1.0f : 0.0f);
    } else if (s < SEQ) {
        float pfac = powf(10000.0f, -(float)(e & ~1) / 128.0f);
        float ang = (float)s * pfac;
        v = lm_b[e] + (odd ? cosf(ang) : sinf(ang));
    } else {
        v = 0.0f;
    }
    A[(size_t)s * 128 + e] = v;
}

// ---------------------------------------------------------------------------
// W2[j][f] = sum_e w_in[j][e]*lm_w[e][f], f<75; zero-pad to KQ. bf16 out.
// ---------------------------------------------------------------------------
__global__ __launch_bounds__(128) void build_W2(
    const float* __restrict__ w_in, const float* __restrict__ lm_w,
    unsigned short* __restrict__ W2) {
    const int j = blockIdx.x, f = threadIdx.x;
    if (f >= KQ) return;
    float acc = 0.0f;
    if (f < 75) {
        for (int e = 0; e < 128; ++e)
            acc += w_in[j * 128 + e] * lm_w[e * 75 + f];
    }
    W2[j * KQ + f] = f2bf(acc);
}

__global__ __launch_bounds__(128) void build_Wout(
    const float* __restrict__ w_out, unsigned short* __restrict__ Wo) {
    const int j = blockIdx.x, e = threadIdx.x;
    Wo[j * 128 + e] = f2bf(w_out[j * 128 + e]);
}

__global__ __launch_bounds__(1024) void zero_pooled(float* __restrict__ p) {
    p[blockIdx.x * 1024 + threadIdx.x] = 0.0f;
}

// ---------------------------------------------------------------------------
// Patchify full sequence to bf16: Pb[s][l][f], f<KQ (pad + cls row = 0).
// ---------------------------------------------------------------------------
__global__ __launch_bounds__(384) void patchify(
    const float* __restrict__ images, unsigned short* __restrict__ Pb) {
    const int l = blockIdx.y;
    const int s = blockIdx.x * 4 + threadIdx.x / KQ;
    const int f = threadIdx.x % KQ;
    if (s >= SEQ) return;
    float v = 0.0f;
    if (s > 0 && f < 75) {
        int p = s - 1;
        int i = p / 51, j = p % 51;
        int c = f / 25, rr = (f % 25) / 5, cc = f % 5;
        v = images[(((size_t)l * 3 + c) * 255 + (i * 5 + rr)) * 255 + (j * 5 + cc)];
    }
    Pb[((size_t)s * 64 + l) * KQ + f] = f2bf(v);
}

// ---------------------------------------------------------------------------
// MFMA QKV GEMM. XCD-swizzled grid; LDS-assembled coalesced epilogue.
// Q pre-scaled by 0.125 (= 1/sqrt(16) * 1/2 for the K-duplication in attn).
// ---------------------------------------------------------------------------
__global__ __launch_bounds__(256) void gemm_qkv_mfma(
    const unsigned short* __restrict__ P, const unsigned short* __restrict__ W2,
    const float* __restrict__ SB, unsigned short* __restrict__ Qh,
    unsigned short* __restrict__ Kh, unsigned short* __restrict__ Vh) {
    __shared__ __align__(16) unsigned short As[64 * LSQ];
    __shared__ __align__(16) unsigned short Bs[64 * LSQ];
    const int tid = threadIdx.x;
    const int xcd = blockIdx.x & 7;
    const int q_ = blockIdx.x >> 3;            // 0..1955
    const int s = xcd + (q_ / 6) * 8;
    const int j = q_ % 6;
    if (s >= SEQ) return;
    const int bm = s * 64;
    const int bn = j * 64;
    const int wv = tid >> 6, lane = tid & 63, quad = lane >> 4, col = lane & 15;

    #pragma unroll
    for (int t = 0; t < 3; ++t) {
        int q = tid + t * 256;
        int row = q & 63, c = q >> 6;
        *(float4*)&As[row * LSQ + c * 8] =
            *(const float4*)(P + (size_t)(bm + row) * KQ + c * 8);
        *(float4*)&Bs[row * LSQ + c * 8] =
            *(const float4*)(W2 + (size_t)(bn + row) * KQ + c * 8);
    }
    __syncthreads();

    f32x4 acc[4] = {};
    const int mrow = wv * 16 + col;
    #pragma unroll
    for (int ks = 0; ks < 3; ++ks) {
        const int k0 = ks * 32 + quad * 8;
        short8 a = *(const short8*)&As[mrow * LSQ + k0];
        #pragma unroll
        for (int nt = 0; nt < 4; ++nt) {
            short8 b = *(const short8*)&Bs[(nt * 16 + col) * LSQ + k0];
            acc[nt] = __builtin_amdgcn_mfma_f32_16x16x32_bf16(a, b, acc[nt], 0, 0, 0);
        }
    }

    const float scale = (j < 2) ? 0.125f : 1.0f;
    unsigned short* dst = (j < 2) ? (Qh + (size_t)s * 8192 + j * 4096)
                        : (j < 4) ? (Kh + (size_t)s * 8192 + (j - 2) * 4096)
                                  : (Vh + (size_t)s * 8192 + (j - 4) * 4096);
    const float* brow = SB + (size_t)s * 384 + bn;

    __syncthreads();                 // all waves done reading As
    unsigned short* tile = As;       // reuse 8 KB of As for assembly
    #pragma unroll
    for (int nt = 0; nt < 4; ++nt) {
        float bv = brow[nt * 16 + col];
        #pragma unroll
        for (int r = 0; r < 4; ++r) {
            int l = wv * 16 + quad * 4 + r;
            int cc = (l * 2 + (col >> 3)) ^ ((l >> 2) & 3);
            tile[nt * 1024 + cc * 8 + (col & 7)] = f2bf((acc[nt][r] + bv) * scale);
        }
    }
    __syncthreads();
    #pragma unroll
    for (int t = 0; t < 2; ++t) {
        int c = tid + t * 256;                 // dest chunk 0..511
        int nt = c >> 7, cc = c & 127, l = cc >> 1;
        int cs = cc ^ ((l >> 2) & 3);
        *(short8*)(dst + (size_t)c * 8) = *(const short8*)&tile[nt * 1024 + cs * 8];
    }
}

// ---------------------------------------------------------------------------
// MFMA attention over the IMAGE axis. One wave per (s,h).
// No max pass (scores bounded by construction); K-dim 16 duplicated into the
// 32-slot MFMA (factor 2 folded into Q scale). Row sums via MFMA with a
// B=ones fragment — lands in the same C-layout rows as O, so 1/sum needs no
// lane exchange. P rounded half-up to bf16; normalization uses sums of the
// SAME rounded P (self-consistent softmax).
// ---------------------------------------------------------------------------
__global__ __launch_bounds__(64) void attention_mfma(
    const unsigned short* __restrict__ Qh, const unsigned short* __restrict__ Kh,
    const unsigned short* __restrict__ Vh, unsigned short* __restrict__ O) {
    __shared__ __align__(16) unsigned short Plds[64 * PST];
    __shared__ __align__(16) unsigned short Vlds[16 * 72];
    __shared__ __align__(16) unsigned short Olds[64 * 16];
    const size_t sh = blockIdx.x;
    const int lane = threadIdx.x, quad = lane >> 4, col = lane & 15;
    const unsigned short* qb = Qh + sh * 1024;
    const unsigned short* kb = Kh + sh * 1024;
    const unsigned short* vb = Vh + sh * 1024;

    // stage V transposed: lane loads row l=lane (32 B), scatters to Vlds[d][l]
    short8 v0 = *(const short8*)(vb + lane * 16);
    short8 v1 = *(const short8*)(vb + lane * 16 + 8);
    #pragma unroll
    for (int d = 0; d < 8; ++d) {
        Vlds[d * 72 + lane]       = (unsigned short)v0[d];
        Vlds[(d + 8) * 72 + lane] = (unsigned short)v1[d];
    }

    const int koff = (quad & 1) * 8;   // quads 2,3 duplicate k0..15 -> 2x dot
    short8 bfr[4];
    #pragma unroll
    for (int nt = 0; nt < 4; ++nt)
        bfr[nt] = *(const short8*)(kb + (size_t)(nt * 16 + col) * 16 + koff);

    f32x4 sc[4][4] = {};
    #pragma unroll
    for (int mt = 0; mt < 4; ++mt) {
        short8 afr = *(const short8*)(qb + (size_t)(mt * 16 + col) * 16 + koff);
        #pragma unroll
        for (int nt = 0; nt < 4; ++nt)
            sc[mt][nt] = __builtin_amdgcn_mfma_f32_16x16x32_bf16(afr, bfr[nt], sc[mt][nt], 0, 0, 0);
    }

    // exp (no max) -> P in LDS (chunk-swizzled), half-up bf16
    #pragma unroll
    for (int mt = 0; mt < 4; ++mt) {
        #pragma unroll
        for (int r = 0; r < 4; ++r) {
            const int M = mt * 16 + quad * 4 + r;
            const int swz = (M >> 2) & 7;
            #pragma unroll
            for (int nt = 0; nt < 4; ++nt) {
                int jc = (nt * 2 + (col >> 3)) ^ swz;
                Plds[M * PST + jc * 8 + (col & 7)] = f2bf(__expf(sc[mt][nt][r]));
            }
        }
    }
    __syncthreads();

    short8 vfr[2];
    #pragma unroll
    for (int ks = 0; ks < 2; ++ks)
        vfr[ks] = *(const short8*)&Vlds[col * 72 + ks * 32 + quad * 8];
    short8 ones8;
    #pragma unroll
    for (int i = 0; i < 8; ++i) ones8[i] = (short)0x3F80;   // bf16 1.0

    #pragma unroll
    for (int mt = 0; mt < 4; ++mt) {
        f32x4 o = {}, sm = {};
        const int m = mt * 16 + col;
        const int swz = (m >> 2) & 7;
        #pragma unroll
        for (int ks = 0; ks < 2; ++ks) {
            int kcs = (ks * 4 + quad) ^ swz;
            short8 pa = *(const short8*)&Plds[m * PST + kcs * 8];
            o  = __builtin_amdgcn_mfma_f32_16x16x32_bf16(pa, vfr[ks], o, 0, 0, 0);
            sm = __builtin_amdgcn_mfma_f32_16x16x32_bf16(pa, ones8, sm, 0, 0, 0);
        }
        #pragma unroll
        for (int r = 0; r < 4; ++r) {
            float iv = __builtin_amdgcn_rcpf(sm[r]);
            int l = mt * 16 + quad * 4 + r;
            int cc = (l * 2 + (col >> 3)) ^ ((l >> 2) & 3);
            Olds[cc * 8 + (col & 7)] = f2bf(o[r] * iv);
        }
    }
    __syncthreads();

    unsigned short* od = O + sh * 1024;       // [s][8][64][16], 2 KB contiguous
    #pragma unroll
    for (int jj = 0; jj < 2; ++jj) {
        int cc = lane * 2 + jj;
        int cs = cc ^ ((lane >> 2) & 3);
        *(short8*)(od + cc * 8) = *(const short8*)&Olds[cs * 8];
    }
}

// ---------------------------------------------------------------------------
// Fused out-proj + LayerNorm + mean-pool, TOK tokens per block (atomics
// amortized across tokens; register accumulator, one atomic set per block).
// ---------------------------------------------------------------------------
__global__ __launch_bounds__(256) void gemm_out_ln_pool(
    const unsigned short* __restrict__ O, const unsigned short* __restrict__ Wo,
    const float* __restrict__ b_out, const float* __restrict__ ln_g,
    const float* __restrict__ ln_b, float* __restrict__ pooled) {
    __shared__ __align__(16) unsigned short As[2][64 * LSO];
    __shared__ __align__(16) unsigned short Bs[128 * LSO];
    const int tid = threadIdx.x;
    const int s0 = blockIdx.x * TOK;
    const int wv = tid >> 6, lane = tid & 63, quad = lane >> 4, col = lane & 15;

    #pragma unroll
    for (int t = 0; t < 8; ++t) {                 // Wo rows: 128 x 16 chunks
        int q = tid + t * 256;
        int row = q >> 4, c = q & 15;
        *(float4*)&Bs[row * LSO + c * 8] =
            *(const float4*)(Wo + (size_t)row * 128 + c * 8);
    }
    #pragma unroll
    for (int t = 0; t < 4; ++t) {                 // token s0 -> As[0]
        int q = tid + t * 256;
        int h = q >> 7, rem = q & 127, l = rem >> 1, jj = rem & 1;
        *(short8*)&As[0][l * LSO + h * 16 + jj * 8] =
            *(const short8*)(O + (size_t)s0 * 8192 + (size_t)q * 8);
    }
    __syncthreads();

    float gch[8], bch[8], boch[8];
    #pragma unroll
    for (int nt = 0; nt < 8; ++nt) {
        int ch = nt * 16 + col;
        gch[nt] = ln_g[ch]; bch[nt] = ln_b[ch]; boch[nt] = b_out[ch];
    }
    const int mrow = wv * 16 + col;
    const int l0 = wv * 16 + quad * 4;
    const int nT = (SEQ - s0 < TOK) ? (SEQ - s0) : TOK;
    float accum[8][4] = {};

    for (int tt = 0; tt < nT; ++tt) {
        if (tt + 1 < nT) {                        // prefetch next token
            const size_t sn = s0 + tt + 1;
            #pragma unroll
            for (int t = 0; t < 4; ++t) {
                int q = tid + t * 256;
                int h = q >> 7, rem = q & 127, l = rem >> 1, jj = rem & 1;
                *(short8*)&As[(tt + 1) & 1][l * LSO + h * 16 + jj * 8] =
                    *(const short8*)(O + sn * 8192 + (size_t)q * 8);
            }
        }
        const unsigned short* Ac = As[tt & 1];
        f32x4 acc[8] = {};
        #pragma unroll
        for (int ks = 0; ks < 4; ++ks) {
            const int k0 = ks * 32 + quad * 8;
            short8 a = *(const short8*)&Ac[mrow * LSO + k0];
            #pragma unroll
            for (int nt = 0; nt < 8; ++nt) {
                short8 b = *(const short8*)&Bs[(nt * 16 + col) * LSO + k0];
                acc[nt] = __builtin_amdgcn_mfma_f32_16x16x32_bf16(a, b, acc[nt], 0, 0, 0);
            }
        }
        #pragma unroll
        for (int r = 0; r < 4; ++r) {
            float yv[8];
            float s1 = 0.0f, s2 = 0.0f;
            #pragma unroll
            for (int nt = 0; nt < 8; ++nt) {
                yv[nt] = acc[nt][r] + boch[nt];
                s1 += yv[nt]; s2 += yv[nt] * yv[nt];
            }
            #pragma unroll
            for (int off = 1; off < 16; off <<= 1) {
                s1 += __shfl_xor(s1, off);
                s2 += __shfl_xor(s2, off);
            }
            float mu = s1 * (1.0f / 128.0f);
            float var = s2 * (1.0f / 128.0f) - mu * mu;
            float rinv = rsqrtf(var + 1e-5f);
            #pragma unroll
            for (int nt = 0; nt < 8; ++nt)
                accum[nt][r] += (yv[nt] - mu) * rinv * gch[nt] + bch[nt];
        }
        __syncthreads();
    }

    #pragma unroll
    for (int nt = 0; nt < 8; ++nt)
        #pragma unroll
        for (int r = 0; r < 4; ++r)
            atomicAdd(&pooled[(l0 + r) * 128 + nt * 16 + col], accum[nt][r]);
}

// ---------------------------------------------------------------------------
// fp32 GEMM (precompute only, SB = A_pre @ w_in^T + b_in).
// ---------------------------------------------------------------------------
__global__ __launch_bounds__(256) void gemm64(
    const float* __restrict__ A, int lda, const float* __restrict__ B,
    const float* __restrict__ bias, float* __restrict__ C, int ldc) {
    __shared__ float As[64 * 68];
    __shared__ float Bs[64 * 68];
    const int bm = blockIdx.y * 64;
    const int bn = blockIdx.x * 64;
    const int tid = threadIdx.x;
    const int tx = tid & 15, ty = tid >> 4;

    float acc[4][4] = {};

    for (int kk = 0; kk < 128; kk += 64) {
        __syncthreads();
        #pragma unroll
        for (int t = 0; t < 4; ++t) {
            int q = tid + t * 256;
            int row = q & 63, c4 = (q >> 6) << 2;
            float4 va = *(const float4*)(A + (size_t)(bm + row) * lda + kk + c4);
            As[(c4 + 0) * 68 + row] = va.x;
            As[(c4 + 1) * 68 + row] = va.y;
            As[(c4 + 2) * 68 + row] = va.z;
            As[(c4 + 3) * 68 + row] = va.w;
            float4 vb = *(const float4*)(B + (size_t)(bn + row) * 128 + kk + c4);
            Bs[(c4 + 0) * 68 + row] = vb.x;
            Bs[(c4 + 1) * 68 + row] = vb.y;
            Bs[(c4 + 2) * 68 + row] = vb.z;
            Bs[(c4 + 3) * 68 + row] = vb.w;
        }
        __syncthreads();
        #pragma unroll 4
        for (int k = 0; k < 64; ++k) {
            float4 av = *(const float4*)&As[k * 68 + (ty << 2)];
            float4 bv = *(const float4*)&Bs[k * 68 + (tx << 2)];
            acc[0][0] += av.x*bv.x; acc[0][1] += av.x*bv.y; acc[0][2] += av.x*bv.z; acc[0][3] += av.x*bv.w;
            acc[1][0] += av.y*bv.x; acc[1][1] += av.y*bv.y; acc[1][2] += av.y*bv.z; acc[1][3] += av.y*bv.w;
            acc[2][0] += av.z*bv.x; acc[2][1] += av.z*bv.y; acc[2][2] += av.z*bv.z; acc[2][3] += av.z*bv.w;
            acc[3][0] += av.w*bv.x; acc[3][1] += av.w*bv.y; acc[3][2] += av.w*bv.z; acc[3][3] += av.w*bv.w;
        }
    }

    float4 bv = *(const float4*)(bias + bn + (tx << 2));
    #pragma unroll
    for (int i = 0; i < 4; ++i) {
        float4 r;
        r.x = acc[i][0] + bv.x; r.y = acc[i][1] + bv.y;
        r.z = acc[i][2] + bv.z; r.w = acc[i][3] + bv.w;
        *(float4*)(C + (size_t)(bm + (ty << 2) + i) * ldc + bn + (tx << 2)) = r;
    }
}

__global__ __launch_bounds__(128) void classify(
    const float* __restrict__ pooled, const float* __restrict__ out_w,
    const float* __restrict__ out_b, float* __restrict__ out) {
    const int l = blockIdx.x, e = threadIdx.x;
    __shared__ float sp[EMB];
    sp[e] = pooled[l * EMB + e] * (1.0f / (float)SEQ);
    __syncthreads();
    if (e < 3) {
        float acc = out_b[e];
        #pragma unroll 16
        for (int k = 0; k < EMB; ++k) acc += sp[k] * out_w[e * EMB + k];
        out[l * 3 + e] = acc;
    }
}

extern "C" void kernel_launch(void* const* d_in, const int* in_sizes, int n_in,
                              void* d_out, int out_size, void* d_ws, size_t ws_size,
                              hipStream_t stream) {
    const float* images = (const float*)d_in[0];
    const float* lm_w   = (const float*)d_in[1];
    const float* lm_b   = (const float*)d_in[2];
    const float* cls    = (const float*)d_in[3];
    const float* w_in   = (const float*)d_in[4];
    const float* b_in   = (const float*)d_in[5];
    const float* w_out  = (const float*)d_in[6];
    const float* b_out  = (const float*)d_in[7];
    const float* ln_g   = (const float*)d_in[8];
    const float* ln_b   = (const float*)d_in[9];
    const float* out_w  = (const float*)d_in[10];
    const float* out_b  = (const float*)d_in[11];
    float* out = (float*)d_out;

    // Workspace (~208 MB of 256 MiB), all regions 16B-aligned:
    float* SB     = (float*)d_ws;                         // [SPAD][384] f32
    float* A_pre  = SB + (size_t)SPAD * 384;              // [SPAD][128] f32
    float* pooled = A_pre + (size_t)SPAD * 128;           // [64][128] f32
    unsigned short* W2   = (unsigned short*)(pooled + 64 * 128); // [384][KQ]
    unsigned short* Wout = W2 + (size_t)384 * KQ;         // [128][128]
    unsigned short* Pb   = Wout + 128 * 128;              // [SEQ][64][KQ]
    unsigned short* Qh   = Pb + (size_t)SEQ * 64 * KQ;    // [SEQ][8][64][16]
    unsigned short* Kh   = Qh + (size_t)SEQ * 8192;       // [SEQ][8][64][16]
    unsigned short* Vh   = Kh + (size_t)SEQ * 8192;       // [SEQ][8][64][16]
    unsigned short* Obuf = Vh + (size_t)SEQ * 8192;       // [SEQ][8][64][16]

    build_A<<<dim3(SPAD), 128, 0, stream>>>(lm_b, cls, A_pre);
    gemm64<<<dim3(6, SPAD / 64), 256, 0, stream>>>(A_pre, 128, w_in, b_in, SB, 384);
    build_W2<<<dim3(384), 128, 0, stream>>>(w_in, lm_w, W2);
    build_Wout<<<dim3(128), 128, 0, stream>>>(w_out, Wout);
    zero_pooled<<<dim3(8), 1024, 0, stream>>>(pooled);

    patchify<<<dim3((SEQ + 3) / 4, 64), 384, 0, stream>>>(images, Pb);
    gemm_qkv_mfma<<<dim3(8 * 326 * 6), 256, 0, stream>>>(Pb, W2, SB, Qh, Kh, Vh);
    attention_mfma<<<dim3(SEQ * 8), 64, 0, stream>>>(Qh, Kh, Vh, Obuf);
    gemm_out_ln_pool<<<dim3((SEQ + TOK - 1) / TOK), 256, 0, stream>>>(
        Obuf, Wout, b_out, ln_g, ln_b, pooled);
    classify<<<dim3(NIMG), 128, 0, stream>>>(pooled, out_w, out_b, out);
}

// Round 10
// 249.199 us; speedup vs baseline: 6.0171x; 1.0867x over previous
//
#include <hip/hip_runtime.h>
#include <math.h>

#define NIMG 64
#define SEQ  2602
#define EMB  128
#define HD   16
#define SPAD 2624    // SEQ padded to multiple of 64
#define KQ   96      // patch K padded 75 -> 96 (multiple of 32)
#define LSQ  104     // LDS row stride (bf16) for KQ  (208 B, 16B-multiple)
#define LSO  136     // LDS row stride (bf16) for K=128 (272 B, 16B-multiple)
#define PST  80      // LDS row stride (bf16) for P (40 words)
#define TOK  8       // tokens per gemm_out_ln_pool block

typedef float f32x4 __attribute__((ext_vector_type(4)));
typedef short short8 __attribute__((ext_vector_type(8)));

// round-half-up bf16 (2 VALU ops; bias 2^-17 relative — negligible)
__device__ __forceinline__ unsigned short f2bf(float f) {
    union { float f; unsigned int u; } v; v.f = f;
    return (unsigned short)((v.u + 0x8000u) >> 16);
}

// ---------------------------------------------------------------------------
// A_pre[s][e]: s==0 -> cls + PE(0); 1<=s<SEQ -> lm_b + PE(s); else 0.
// ---------------------------------------------------------------------------
__global__ __launch_bounds__(128) void build_A(
    const float* __restrict__ lm_b, const float* __restrict__ cls,
    float* __restrict__ A) {
    const int s = blockIdx.x, e = threadIdx.x;
    const bool odd = e & 1;
    float v;
    if (s == 0) {
        v = cls[e] + (odd ? 1.0f : 0.0f);
    } else if (s < SEQ) {
        float pfac = powf(10000.0f, -(float)(e & ~1) / 128.0f);
        float ang = (float)s * pfac;
        v = lm_b[e] + (odd ? cosf(ang) : sinf(ang));
    } else {
        v = 0.0f;
    }
    A[(size_t)s * 128 + e] = v;
}

// ---------------------------------------------------------------------------
// W2[j][f] = sum_e w_in[j][e]*lm_w[e][f], f<75; zero-pad to KQ. bf16 out.
// ---------------------------------------------------------------------------
__global__ __launch_bounds__(128) void build_W2(
    const float* __restrict__ w_in, const float* __restrict__ lm_w,
    unsigned short* __restrict__ W2) {
    const int j = blockIdx.x, f = threadIdx.x;
    if (f >= KQ) return;
    float acc = 0.0f;
    if (f < 75) {
        for (int e = 0; e < 128; ++e)
            acc += w_in[j * 128 + e] * lm_w[e * 75 + f];
    }
    W2[j * KQ + f] = f2bf(acc);
}

__global__ __launch_bounds__(128) void build_Wout(
    const float* __restrict__ w_out, unsigned short* __restrict__ Wo) {
    const int j = blockIdx.x, e = threadIdx.x;
    Wo[j * 128 + e] = f2bf(w_out[j * 128 + e]);
}

__global__ __launch_bounds__(1024) void zero_pooled(float* __restrict__ p) {
    p[blockIdx.x * 1024 + threadIdx.x] = 0.0f;
}

// Pb token s=0 (cls row): 64 images x 96 halves = 3072 uints of zero.
__global__ __launch_bounds__(1024) void zero_cls(unsigned int* __restrict__ p) {
    p[blockIdx.x * 1024 + threadIdx.x] = 0u;
}

// ---------------------------------------------------------------------------
// Patchify, coalesced both ends. Grid (51 patch-rows, 64 images), 256 thr.
// Phase 1: stage 15 image rows (3ch x 5rows x 255px) lane-consecutive ->
// LDS bf16 [seg][x] (each pixel fetched exactly once device-wide).
// Phase 2: 4 threads/token gather 24 halves each from LDS, emit 3 x 16B
// stores -> Pb[s][l][0..96) contiguous (192 B per token, 16B-aligned).
// ---------------------------------------------------------------------------
__global__ __launch_bounds__(256) void patchify(
    const float* __restrict__ images, unsigned short* __restrict__ Pb) {
    __shared__ unsigned short rows[15][256];
    const int i = blockIdx.x, l = blockIdx.y;
    const int tid = threadIdx.x;

    if (tid < 255) {
        #pragma unroll
        for (int seg = 0; seg < 15; ++seg) {
            int c = seg / 5, rr = seg % 5;
            float v = images[(((size_t)l * 3 + c) * 255 + (i * 5 + rr)) * 255 + tid];
            rows[seg][tid] = f2bf(v);
        }
    }
    __syncthreads();

    const int j = tid >> 2;          // token within this patch-row
    const int part = tid & 3;        // quarter of the 96-wide feature row
    if (j < 51) {
        const int f0 = part * 24;
        __align__(16) unsigned short buf[24];
        #pragma unroll
        for (int u = 0; u < 24; ++u) {
            int f = f0 + u;
            unsigned short v = 0;
            if (f < 75) {
                int c = f / 25, rem = f % 25, rr = rem / 5, cc = rem % 5;
                v = rows[c * 5 + rr][j * 5 + cc];
            }
            buf[u] = v;
        }
        const int s = i * 51 + j + 1;
        unsigned short* dst = Pb + ((size_t)s * 64 + l) * KQ + f0;
        #pragma unroll
        for (int t = 0; t < 3; ++t)
            *(short8*)(dst + t * 8) = *(const short8*)&buf[t * 8];
    }
}

// ---------------------------------------------------------------------------
// MFMA QKV GEMM. XCD-swizzled grid; LDS-assembled coalesced epilogue.
// Q pre-scaled by 0.125 (= 1/sqrt(16) * 1/2 for the K-duplication in attn).
// ---------------------------------------------------------------------------
__global__ __launch_bounds__(256) void gemm_qkv_mfma(
    const unsigned short* __restrict__ P, const unsigned short* __restrict__ W2,
    const float* __restrict__ SB, unsigned short* __restrict__ Qh,
    unsigned short* __restrict__ Kh, unsigned short* __restrict__ Vh) {
    __shared__ __align__(16) unsigned short As[64 * LSQ];
    __shared__ __align__(16) unsigned short Bs[64 * LSQ];
    const int tid = threadIdx.x;
    const int xcd = blockIdx.x & 7;
    const int q_ = blockIdx.x >> 3;            // 0..1955
    const int s = xcd + (q_ / 6) * 8;
    const int j = q_ % 6;
    if (s >= SEQ) return;
    const int bm = s * 64;
    const int bn = j * 64;
    const int wv = tid >> 6, lane = tid & 63, quad = lane >> 4, col = lane & 15;

    #pragma unroll
    for (int t = 0; t < 3; ++t) {
        int q = tid + t * 256;
        int row = q & 63, c = q >> 6;
        *(float4*)&As[row * LSQ + c * 8] =
            *(const float4*)(P + (size_t)(bm + row) * KQ + c * 8);
        *(float4*)&Bs[row * LSQ + c * 8] =
            *(const float4*)(W2 + (size_t)(bn + row) * KQ + c * 8);
    }
    __syncthreads();

    f32x4 acc[4] = {};
    const int mrow = wv * 16 + col;
    #pragma unroll
    for (int ks = 0; ks < 3; ++ks) {
        const int k0 = ks * 32 + quad * 8;
        short8 a = *(const short8*)&As[mrow * LSQ + k0];
        #pragma unroll
        for (int nt = 0; nt < 4; ++nt) {
            short8 b = *(const short8*)&Bs[(nt * 16 + col) * LSQ + k0];
            acc[nt] = __builtin_amdgcn_mfma_f32_16x16x32_bf16(a, b, acc[nt], 0, 0, 0);
        }
    }

    const float scale = (j < 2) ? 0.125f : 1.0f;
    unsigned short* dst = (j < 2) ? (Qh + (size_t)s * 8192 + j * 4096)
                        : (j < 4) ? (Kh + (size_t)s * 8192 + (j - 2) * 4096)
                                  : (Vh + (size_t)s * 8192 + (j - 4) * 4096);
    const float* brow = SB + (size_t)s * 384 + bn;

    __syncthreads();                 // all waves done reading As
    unsigned short* tile = As;       // reuse 8 KB of As for assembly
    #pragma unroll
    for (int nt = 0; nt < 4; ++nt) {
        float bv = brow[nt * 16 + col];
        #pragma unroll
        for (int r = 0; r < 4; ++r) {
            int l = wv * 16 + quad * 4 + r;
            int cc = (l * 2 + (col >> 3)) ^ ((l >> 2) & 3);
            tile[nt * 1024 + cc * 8 + (col & 7)] = f2bf((acc[nt][r] + bv) * scale);
        }
    }
    __syncthreads();
    #pragma unroll
    for (int t = 0; t < 2; ++t) {
        int c = tid + t * 256;                 // dest chunk 0..511
        int nt = c >> 7, cc = c & 127, l = cc >> 1;
        int cs = cc ^ ((l >> 2) & 3);
        *(short8*)(dst + (size_t)c * 8) = *(const short8*)&tile[nt * 1024 + cs * 8];
    }
}

// ---------------------------------------------------------------------------
// MFMA attention over the IMAGE axis. One wave per (s,h).
// No max pass (scores bounded by construction); K-dim 16 duplicated into the
// 32-slot MFMA (factor 2 folded into Q scale). Row sums via MFMA with a
// B=ones fragment. P rounded half-up to bf16; normalization uses sums of the
// SAME rounded P (self-consistent softmax).
// ---------------------------------------------------------------------------
__global__ __launch_bounds__(64) void attention_mfma(
    const unsigned short* __restrict__ Qh, const unsigned short* __restrict__ Kh,
    const unsigned short* __restrict__ Vh, unsigned short* __restrict__ O) {
    __shared__ __align__(16) unsigned short Plds[64 * PST];
    __shared__ __align__(16) unsigned short Vlds[16 * 72];
    __shared__ __align__(16) unsigned short Olds[64 * 16];
    const size_t sh = blockIdx.x;
    const int lane = threadIdx.x, quad = lane >> 4, col = lane & 15;
    const unsigned short* qb = Qh + sh * 1024;
    const unsigned short* kb = Kh + sh * 1024;
    const unsigned short* vb = Vh + sh * 1024;

    // stage V transposed: lane loads row l=lane (32 B), scatters to Vlds[d][l]
    short8 v0 = *(const short8*)(vb + lane * 16);
    short8 v1 = *(const short8*)(vb + lane * 16 + 8);
    #pragma unroll
    for (int d = 0; d < 8; ++d) {
        Vlds[d * 72 + lane]       = (unsigned short)v0[d];
        Vlds[(d + 8) * 72 + lane] = (unsigned short)v1[d];
    }

    const int koff = (quad & 1) * 8;   // quads 2,3 duplicate k0..15 -> 2x dot
    short8 bfr[4];
    #pragma unroll
    for (int nt = 0; nt < 4; ++nt)
        bfr[nt] = *(const short8*)(kb + (size_t)(nt * 16 + col) * 16 + koff);

    f32x4 sc[4][4] = {};
    #pragma unroll
    for (int mt = 0; mt < 4; ++mt) {
        short8 afr = *(const short8*)(qb + (size_t)(mt * 16 + col) * 16 + koff);
        #pragma unroll
        for (int nt = 0; nt < 4; ++nt)
            sc[mt][nt] = __builtin_amdgcn_mfma_f32_16x16x32_bf16(afr, bfr[nt], sc[mt][nt], 0, 0, 0);
    }

    // exp (no max) -> P in LDS (chunk-swizzled), half-up bf16
    #pragma unroll
    for (int mt = 0; mt < 4; ++mt) {
        #pragma unroll
        for (int r = 0; r < 4; ++r) {
            const int M = mt * 16 + quad * 4 + r;
            const int swz = (M >> 2) & 7;
            #pragma unroll
            for (int nt = 0; nt < 4; ++nt) {
                int jc = (nt * 2 + (col >> 3)) ^ swz;
                Plds[M * PST + jc * 8 + (col & 7)] = f2bf(__expf(sc[mt][nt][r]));
            }
        }
    }
    __syncthreads();

    short8 vfr[2];
    #pragma unroll
    for (int ks = 0; ks < 2; ++ks)
        vfr[ks] = *(const short8*)&Vlds[col * 72 + ks * 32 + quad * 8];
    short8 ones8;
    #pragma unroll
    for (int i = 0; i < 8; ++i) ones8[i] = (short)0x3F80;   // bf16 1.0

    #pragma unroll
    for (int mt = 0; mt < 4; ++mt) {
        f32x4 o = {}, sm = {};
        const int m = mt * 16 + col;
        const int swz = (m >> 2) & 7;
        #pragma unroll
        for (int ks = 0; ks < 2; ++ks) {
            int kcs = (ks * 4 + quad) ^ swz;
            short8 pa = *(const short8*)&Plds[m * PST + kcs * 8];
            o  = __builtin_amdgcn_mfma_f32_16x16x32_bf16(pa, vfr[ks], o, 0, 0, 0);
            sm = __builtin_amdgcn_mfma_f32_16x16x32_bf16(pa, ones8, sm, 0, 0, 0);
        }
        #pragma unroll
        for (int r = 0; r < 4; ++r) {
            float iv = __builtin_amdgcn_rcpf(sm[r]);
            int l = mt * 16 + quad * 4 + r;
            int cc = (l * 2 + (col >> 3)) ^ ((l >> 2) & 3);
            Olds[cc * 8 + (col & 7)] = f2bf(o[r] * iv);
        }
    }
    __syncthreads();

    unsigned short* od = O + sh * 1024;       // [s][8][64][16], 2 KB contiguous
    #pragma unroll
    for (int jj = 0; jj < 2; ++jj) {
        int cc = lane * 2 + jj;
        int cs = cc ^ ((lane >> 2) & 3);
        *(short8*)(od + cc * 8) = *(const short8*)&Olds[cs * 8];
    }
}

// ---------------------------------------------------------------------------
// Fused out-proj + LayerNorm + mean-pool, TOK tokens per block (atomics
// amortized across tokens; register accumulator, one atomic set per block).
// ---------------------------------------------------------------------------
__global__ __launch_bounds__(256) void gemm_out_ln_pool(
    const unsigned short* __restrict__ O, const unsigned short* __restrict__ Wo,
    const float* __restrict__ b_out, const float* __restrict__ ln_g,
    const float* __restrict__ ln_b, float* __restrict__ pooled) {
    __shared__ __align__(16) unsigned short As[2][64 * LSO];
    __shared__ __align__(16) unsigned short Bs[128 * LSO];
    const int tid = threadIdx.x;
    const int s0 = blockIdx.x * TOK;
    const int wv = tid >> 6, lane = tid & 63, quad = lane >> 4, col = lane & 15;

    #pragma unroll
    for (int t = 0; t < 8; ++t) {                 // Wo rows: 128 x 16 chunks
        int q = tid + t * 256;
        int row = q >> 4, c = q & 15;
        *(float4*)&Bs[row * LSO + c * 8] =
            *(const float4*)(Wo + (size_t)row * 128 + c * 8);
    }
    #pragma unroll
    for (int t = 0; t < 4; ++t) {                 // token s0 -> As[0]
        int q = tid + t * 256;
        int h = q >> 7, rem = q & 127, l = rem >> 1, jj = rem & 1;
        *(short8*)&As[0][l * LSO + h * 16 + jj * 8] =
            *(const short8*)(O + (size_t)s0 * 8192 + (size_t)q * 8);
    }
    __syncthreads();

    float gch[8], bch[8], boch[8];
    #pragma unroll
    for (int nt = 0; nt < 8; ++nt) {
        int ch = nt * 16 + col;
        gch[nt] = ln_g[ch]; bch[nt] = ln_b[ch]; boch[nt] = b_out[ch];
    }
    const int mrow = wv * 16 + col;
    const int l0 = wv * 16 + quad * 4;
    const int nT = (SEQ - s0 < TOK) ? (SEQ - s0) : TOK;
    float accum[8][4] = {};

    for (int tt = 0; tt < nT; ++tt) {
        if (tt + 1 < nT) {                        // prefetch next token
            const size_t sn = s0 + tt + 1;
            #pragma unroll
            for (int t = 0; t < 4; ++t) {
                int q = tid + t * 256;
                int h = q >> 7, rem = q & 127, l = rem >> 1, jj = rem & 1;
                *(short8*)&As[(tt + 1) & 1][l * LSO + h * 16 + jj * 8] =
                    *(const short8*)(O + sn * 8192 + (size_t)q * 8);
            }
        }
        const unsigned short* Ac = As[tt & 1];
        f32x4 acc[8] = {};
        #pragma unroll
        for (int ks = 0; ks < 4; ++ks) {
            const int k0 = ks * 32 + quad * 8;
            short8 a = *(const short8*)&Ac[mrow * LSO + k0];
            #pragma unroll
            for (int nt = 0; nt < 8; ++nt) {
                short8 b = *(const short8*)&Bs[(nt * 16 + col) * LSO + k0];
                acc[nt] = __builtin_amdgcn_mfma_f32_16x16x32_bf16(a, b, acc[nt], 0, 0, 0);
            }
        }
        #pragma unroll
        for (int r = 0; r < 4; ++r) {
            float yv[8];
            float s1 = 0.0f, s2 = 0.0f;
            #pragma unroll
            for (int nt = 0; nt < 8; ++nt) {
                yv[nt] = acc[nt][r] + boch[nt];
                s1 += yv[nt]; s2 += yv[nt] * yv[nt];
            }
            #pragma unroll
            for (int off = 1; off < 16; off <<= 1) {
                s1 += __shfl_xor(s1, off);
                s2 += __shfl_xor(s2, off);
            }
            float mu = s1 * (1.0f / 128.0f);
            float var = s2 * (1.0f / 128.0f) - mu * mu;
            float rinv = rsqrtf(var + 1e-5f);
            #pragma unroll
            for (int nt = 0; nt < 8; ++nt)
                accum[nt][r] += (yv[nt] - mu) * rinv * gch[nt] + bch[nt];
        }
        __syncthreads();
    }

    #pragma unroll
    for (int nt = 0; nt < 8; ++nt)
        #pragma unroll
        for (int r = 0; r < 4; ++r)
            atomicAdd(&pooled[(l0 + r) * 128 + nt * 16 + col], accum[nt][r]);
}

// ---------------------------------------------------------------------------
// fp32 GEMM (precompute only, SB = A_pre @ w_in^T + b_in).
// ---------------------------------------------------------------------------
__global__ __launch_bounds__(256) void gemm64(
    const float* __restrict__ A, int lda, const float* __restrict__ B,
    const float* __restrict__ bias, float* __restrict__ C, int ldc) {
    __shared__ float As[64 * 68];
    __shared__ float Bs[64 * 68];
    const int bm = blockIdx.y * 64;
    const int bn = blockIdx.x * 64;
    const int tid = threadIdx.x;
    const int tx = tid & 15, ty = tid >> 4;

    float acc[4][4] = {};

    for (int kk = 0; kk < 128; kk += 64) {
        __syncthreads();
        #pragma unroll
        for (int t = 0; t < 4; ++t) {
            int q = tid + t * 256;
            int row = q & 63, c4 = (q >> 6) << 2;
            float4 va = *(const float4*)(A + (size_t)(bm + row) * lda + kk + c4);
            As[(c4 + 0) * 68 + row] = va.x;
            As[(c4 + 1) * 68 + row] = va.y;
            As[(c4 + 2) * 68 + row] = va.z;
            As[(c4 + 3) * 68 + row] = va.w;
            float4 vb = *(const float4*)(B + (size_t)(bn + row) * 128 + kk + c4);
            Bs[(c4 + 0) * 68 + row] = vb.x;
            Bs[(c4 + 1) * 68 + row] = vb.y;
            Bs[(c4 + 2) * 68 + row] = vb.z;
            Bs[(c4 + 3) * 68 + row] = vb.w;
        }
        __syncthreads();
        #pragma unroll 4
        for (int k = 0; k < 64; ++k) {
            float4 av = *(const float4*)&As[k * 68 + (ty << 2)];
            float4 bv = *(const float4*)&Bs[k * 68 + (tx << 2)];
            acc[0][0] += av.x*bv.x; acc[0][1] += av.x*bv.y; acc[0][2] += av.x*bv.z; acc[0][3] += av.x*bv.w;
            acc[1][0] += av.y*bv.x; acc[1][1] += av.y*bv.y; acc[1][2] += av.y*bv.z; acc[1][3] += av.y*bv.w;
            acc[2][0] += av.z*bv.x; acc[2][1] += av.z*bv.y; acc[2][2] += av.z*bv.z; acc[2][3] += av.z*bv.w;
            acc[3][0] += av.w*bv.x; acc[3][1] += av.w*bv.y; acc[3][2] += av.w*bv.z; acc[3][3] += av.w*bv.w;
        }
    }

    float4 bv = *(const float4*)(bias + bn + (tx << 2));
    #pragma unroll
    for (int i = 0; i < 4; ++i) {
        float4 r;
        r.x = acc[i][0] + bv.x; r.y = acc[i][1] + bv.y;
        r.z = acc[i][2] + bv.z; r.w = acc[i][3] + bv.w;
        *(float4*)(C + (size_t)(bm + (ty << 2) + i) * ldc + bn + (tx << 2)) = r;
    }
}

__global__ __launch_bounds__(128) void classify(
    const float* __restrict__ pooled, const float* __restrict__ out_w,
    const float* __restrict__ out_b, float* __restrict__ out) {
    const int l = blockIdx.x, e = threadIdx.x;
    __shared__ float sp[EMB];
    sp[e] = pooled[l * EMB + e] * (1.0f / (float)SEQ);
    __syncthreads();
    if (e < 3) {
        float acc = out_b[e];
        #pragma unroll 16
        for (int k = 0; k < EMB; ++k) acc += sp[k] * out_w[e * EMB + k];
        out[l * 3 + e] = acc;
    }
}

extern "C" void kernel_launch(void* const* d_in, const int* in_sizes, int n_in,
                              void* d_out, int out_size, void* d_ws, size_t ws_size,
                              hipStream_t stream) {
    const float* images = (const float*)d_in[0];
    const float* lm_w   = (const float*)d_in[1];
    const float* lm_b   = (const float*)d_in[2];
    const float* cls    = (const float*)d_in[3];
    const float* w_in   = (const float*)d_in[4];
    const float* b_in   = (const float*)d_in[5];
    const float* w_out  = (const float*)d_in[6];
    const float* b_out  = (const float*)d_in[7];
    const float* ln_g   = (const float*)d_in[8];
    const float* ln_b   = (const float*)d_in[9];
    const float* out_w  = (const float*)d_in[10];
    const float* out_b  = (const float*)d_in[11];
    float* out = (float*)d_out;

    // Workspace (~208 MB of 256 MiB), all regions 16B-aligned:
    float* SB     = (float*)d_ws;                         // [SPAD][384] f32
    float* A_pre  = SB + (size_t)SPAD * 384;              // [SPAD][128] f32
    float* pooled = A_pre + (size_t)SPAD * 128;           // [64][128] f32
    unsigned short* W2   = (unsigned short*)(pooled + 64 * 128); // [384][KQ]
    unsigned short* Wout = W2 + (size_t)384 * KQ;         // [128][128]
    unsigned short* Pb   = Wout + 128 * 128;              // [SEQ][64][KQ]
    unsigned short* Qh   = Pb + (size_t)SEQ * 64 * KQ;    // [SEQ][8][64][16]
    unsigned short* Kh   = Qh + (size_t)SEQ * 8192;       // [SEQ][8][64][16]
    unsigned short* Vh   = Kh + (size_t)SEQ * 8192;       // [SEQ][8][64][16]
    unsigned short* Obuf = Vh + (size_t)SEQ * 8192;       // [SEQ][8][64][16]

    build_A<<<dim3(SPAD), 128, 0, stream>>>(lm_b, cls, A_pre);
    gemm64<<<dim3(6, SPAD / 64), 256, 0, stream>>>(A_pre, 128, w_in, b_in, SB, 384);
    build_W2<<<dim3(384), 128, 0, stream>>>(w_in, lm_w, W2);
    build_Wout<<<dim3(128), 128, 0, stream>>>(w_out, Wout);
    zero_pooled<<<dim3(8), 1024, 0, stream>>>(pooled);
    zero_cls<<<dim3(3), 1024, 0, stream>>>((unsigned int*)Pb);

    patchify<<<dim3(51, 64), 256, 0, stream>>>(images, Pb);
    gemm_qkv_mfma<<<dim3(8 * 326 * 6), 256, 0, stream>>>(Pb, W2, SB, Qh, Kh, Vh);
    attention_mfma<<<dim3(SEQ * 8), 64, 0, stream>>>(Qh, Kh, Vh, Obuf);
    gemm_out_ln_pool<<<dim3((SEQ + TOK - 1) / TOK), 256, 0, stream>>>(
        Obuf, Wout, b_out, ln_g, ln_b, pooled);
    classify<<<dim3(NIMG), 128, 0, stream>>>(pooled, out_w, out_b, out);
}

// Round 11
// 247.843 us; speedup vs baseline: 6.0500x; 1.0055x over previous
//
#include <hip/hip_runtime.h>
#include <math.h>

#define NIMG 64
#define SEQ  2602
#define EMB  128
#define HD   16
#define SPAD 2624    // SEQ padded to multiple of 64
#define KQ   96      // patch K padded 75 -> 96 (multiple of 32)
#define LSO  136     // LDS row stride (bf16) for K=128 (272 B, 16B-multiple)
#define TOK  8       // tokens per gemm_out_ln_pool block

typedef float f32x4 __attribute__((ext_vector_type(4)));
typedef short short8 __attribute__((ext_vector_type(8)));

// round-half-up bf16 (2 VALU ops)
__device__ __forceinline__ unsigned short f2bf(float f) {
    union { float f; unsigned int u; } v; v.f = f;
    return (unsigned short)((v.u + 0x8000u) >> 16);
}

// ---------------------------------------------------------------------------
// A_pre[s][e]: s==0 -> cls + PE(0); 1<=s<SEQ -> lm_b + PE(s); else 0.
// ---------------------------------------------------------------------------
__global__ __launch_bounds__(128) void build_A(
    const float* __restrict__ lm_b, const float* __restrict__ cls,
    float* __restrict__ A) {
    const int s = blockIdx.x, e = threadIdx.x;
    const bool odd = e & 1;
    float v;
    if (s == 0) {
        v = cls[e] + (odd ? 1.0f : 0.0f);
    } else if (s < SEQ) {
        float pfac = powf(10000.0f, -(float)(e & ~1) / 128.0f);
        float ang = (float)s * pfac;
        v = lm_b[e] + (odd ? cosf(ang) : sinf(ang));
    } else {
        v = 0.0f;
    }
    A[(size_t)s * 128 + e] = v;
}

// ---------------------------------------------------------------------------
// W2[j][f] = sum_e w_in[j][e]*lm_w[e][f], f<75; zero-pad to KQ. bf16 out.
// ---------------------------------------------------------------------------
__global__ __launch_bounds__(128) void build_W2(
    const float* __restrict__ w_in, const float* __restrict__ lm_w,
    unsigned short* __restrict__ W2) {
    const int j = blockIdx.x, f = threadIdx.x;
    if (f >= KQ) return;
    float acc = 0.0f;
    if (f < 75) {
        for (int e = 0; e < 128; ++e)
            acc += w_in[j * 128 + e] * lm_w[e * 75 + f];
    }
    W2[j * KQ + f] = f2bf(acc);
}

__global__ __launch_bounds__(128) void build_Wout(
    const float* __restrict__ w_out, unsigned short* __restrict__ Wo) {
    const int j = blockIdx.x, e = threadIdx.x;
    Wo[j * 128 + e] = f2bf(w_out[j * 128 + e]);
}

__global__ __launch_bounds__(1024) void zero_pooled(float* __restrict__ p) {
    p[blockIdx.x * 1024 + threadIdx.x] = 0.0f;
}

// Pb token s=0 (cls row): 64 images x 96 halves = 3072 uints of zero.
__global__ __launch_bounds__(1024) void zero_cls(unsigned int* __restrict__ p) {
    p[blockIdx.x * 1024 + threadIdx.x] = 0u;
}

// ---------------------------------------------------------------------------
// Patchify, coalesced both ends. Grid (51 patch-rows, 64 images), 256 thr.
// ---------------------------------------------------------------------------
__global__ __launch_bounds__(256) void patchify(
    const float* __restrict__ images, unsigned short* __restrict__ Pb) {
    __shared__ unsigned short rows[15][256];
    const int i = blockIdx.x, l = blockIdx.y;
    const int tid = threadIdx.x;

    if (tid < 255) {
        #pragma unroll
        for (int seg = 0; seg < 15; ++seg) {
            int c = seg / 5, rr = seg % 5;
            float v = images[(((size_t)l * 3 + c) * 255 + (i * 5 + rr)) * 255 + tid];
            rows[seg][tid] = f2bf(v);
        }
    }
    __syncthreads();

    const int j = tid >> 2;          // token within this patch-row
    const int part = tid & 3;        // quarter of the 96-wide feature row
    if (j < 51) {
        const int f0 = part * 24;
        __align__(16) unsigned short buf[24];
        #pragma unroll
        for (int u = 0; u < 24; ++u) {
            int f = f0 + u;
            unsigned short v = 0;
            if (f < 75) {
                int c = f / 25, rem = f % 25, rr = rem / 5, cc = rem % 5;
                v = rows[c * 5 + rr][j * 5 + cc];
            }
            buf[u] = v;
        }
        const int s = i * 51 + j + 1;
        unsigned short* dst = Pb + ((size_t)s * 64 + l) * KQ + f0;
        #pragma unroll
        for (int t = 0; t < 3; ++t)
            *(short8*)(dst + t * 8) = *(const short8*)&buf[t * 8];
    }
}

// ---------------------------------------------------------------------------
// FUSED QKV-GEMM + attention. One block (4 waves) per token; wave w owns
// heads 2w, 2w+1 (channels [32w,32w+32) of each of Q/K/V). Q/K/V live only
// in wave-private LDS — never in HBM. ZERO barriers (no cross-wave data).
// Phase 1: 64x96 @ 96 sub-GEMM, A/B frags read directly from global (L2-hot).
// Epilogue scatters Q/K row-major (Q pre-scaled 0.125 for the dup-K trick)
// and V transposed. Phase 2 per head: S via dup-K MFMA, exp (no max),
// P -> swizzled LDS, PV + MFMA-ones row sums, O -> LDS assemble -> coalesced
// global store into Obuf[s][h][64][16].
// ---------------------------------------------------------------------------
__global__ __launch_bounds__(256) void qkv_attn(
    const unsigned short* __restrict__ Pb, const unsigned short* __restrict__ W2,
    const float* __restrict__ SB, unsigned short* __restrict__ Obuf) {
    __shared__ __align__(16) unsigned short Qw_[4][64 * 40];
    __shared__ __align__(16) unsigned short Kw_[4][64 * 40];
    __shared__ __align__(16) unsigned short Vw_[4][32 * 72];
    __shared__ __align__(16) unsigned short Pw_[4][64 * 80];
    __shared__ __align__(16) unsigned short Ow_[4][64 * 16];

    const int s = blockIdx.x;
    const int tid = threadIdx.x;
    const int w = tid >> 6, lane = tid & 63, quad = lane >> 4, col = lane & 15;
    unsigned short* Qw = Qw_[w];
    unsigned short* Kw = Kw_[w];
    unsigned short* Vw = Vw_[w];
    unsigned short* Pw = Pw_[w];
    unsigned short* Ow = Ow_[w];

    // ---- Phase 1: sub-GEMM for this wave's 96 channels (6 n-tiles of 16)
    // chan(nt) = (nt>>1)*128 + 32w + (nt&1)*16 + col
    f32x4 acc[6][4] = {};
    const unsigned short* arow0 = Pb + (size_t)s * 64 * KQ;
    #pragma unroll
    for (int ks = 0; ks < 3; ++ks) {
        const int k0 = ks * 32 + quad * 8;
        short8 b[6];
        #pragma unroll
        for (int nt = 0; nt < 6; ++nt) {
            int ch = (nt >> 1) * 128 + 32 * w + (nt & 1) * 16 + col;
            b[nt] = *(const short8*)(W2 + (size_t)ch * KQ + k0);
        }
        #pragma unroll
        for (int mt = 0; mt < 4; ++mt) {
            short8 a = *(const short8*)(arow0 + (size_t)(mt * 16 + col) * KQ + k0);
            #pragma unroll
            for (int nt = 0; nt < 6; ++nt)
                acc[nt][mt] = __builtin_amdgcn_mfma_f32_16x16x32_bf16(a, b[nt], acc[nt][mt], 0, 0, 0);
        }
    }

    // ---- Epilogue: bias + scatter to wave-private LDS
    const float* sbrow = SB + (size_t)s * 384;
    #pragma unroll
    for (int nt = 0; nt < 6; ++nt) {
        int ch = (nt >> 1) * 128 + 32 * w + (nt & 1) * 16 + col;
        float bv = sbrow[ch];
        int chl = (nt & 1) * 16 + col;           // 0..31 within this wave
        #pragma unroll
        for (int mt = 0; mt < 4; ++mt) {
            #pragma unroll
            for (int r = 0; r < 4; ++r) {
                int m = mt * 16 + quad * 4 + r;
                float v = acc[nt][mt][r] + bv;
                if (nt < 2)      Qw[m * 40 + chl] = f2bf(v * 0.125f);
                else if (nt < 4) Kw[m * 40 + chl] = f2bf(v);
                else             Vw[chl * 72 + m] = f2bf(v);
            }
        }
    }

    // ---- Phase 2: attention for this wave's two heads (no barriers needed:
    // all producer/consumer pairs are within this wave; HW orders via lgkmcnt)
    const int koff = (quad & 1) * 8;
    short8 ones8;
    #pragma unroll
    for (int i = 0; i < 8; ++i) ones8[i] = (short)0x3F80;   // bf16 1.0

    #pragma unroll
    for (int hl = 0; hl < 2; ++hl) {
        const int hoff = hl * 16;
        short8 bfr[4];
        #pragma unroll
        for (int nt = 0; nt < 4; ++nt)
            bfr[nt] = *(const short8*)&Kw[(nt * 16 + col) * 40 + hoff + koff];

        f32x4 sc[4][4] = {};
        #pragma unroll
        for (int mt = 0; mt < 4; ++mt) {
            short8 afr = *(const short8*)&Qw[(mt * 16 + col) * 40 + hoff + koff];
            #pragma unroll
            for (int nt = 0; nt < 4; ++nt)
                sc[mt][nt] = __builtin_amdgcn_mfma_f32_16x16x32_bf16(afr, bfr[nt], sc[mt][nt], 0, 0, 0);
        }

        // exp (no max) -> P (chunk-swizzled)
        #pragma unroll
        for (int mt = 0; mt < 4; ++mt) {
            #pragma unroll
            for (int r = 0; r < 4; ++r) {
                const int M = mt * 16 + quad * 4 + r;
                const int swz = (M >> 2) & 7;
                #pragma unroll
                for (int nt = 0; nt < 4; ++nt) {
                    int jc = (nt * 2 + (col >> 3)) ^ swz;
                    Pw[M * 80 + jc * 8 + (col & 7)] = f2bf(__expf(sc[mt][nt][r]));
                }
            }
        }

        short8 vfr[2];
        #pragma unroll
        for (int ks = 0; ks < 2; ++ks)
            vfr[ks] = *(const short8*)&Vw[(hoff + col) * 72 + ks * 32 + quad * 8];

        #pragma unroll
        for (int mt = 0; mt < 4; ++mt) {
            f32x4 o = {}, sm = {};
            const int m = mt * 16 + col;
            const int swz = (m >> 2) & 7;
            #pragma unroll
            for (int ks = 0; ks < 2; ++ks) {
                int kcs = (ks * 4 + quad) ^ swz;
                short8 pa = *(const short8*)&Pw[m * 80 + kcs * 8];
                o  = __builtin_amdgcn_mfma_f32_16x16x32_bf16(pa, vfr[ks], o, 0, 0, 0);
                sm = __builtin_amdgcn_mfma_f32_16x16x32_bf16(pa, ones8, sm, 0, 0, 0);
            }
            #pragma unroll
            for (int r = 0; r < 4; ++r) {
                float iv = __builtin_amdgcn_rcpf(sm[r]);
                int l = mt * 16 + quad * 4 + r;
                int cc = (l * 2 + (col >> 3)) ^ ((l >> 2) & 3);
                Ow[cc * 8 + (col & 7)] = f2bf(o[r] * iv);
            }
        }

        // coalesced O store: head h = 2w + hl, 2 KB contiguous
        unsigned short* od = Obuf + ((size_t)s * 8 + 2 * w + hl) * 1024;
        #pragma unroll
        for (int jj = 0; jj < 2; ++jj) {
            int cc = lane * 2 + jj;
            int cs = cc ^ ((lane >> 2) & 3);
            *(short8*)(od + cc * 8) = *(const short8*)&Ow[cs * 8];
        }
    }
}

// ---------------------------------------------------------------------------
// Fused out-proj + LayerNorm + mean-pool, TOK tokens per block.
// ---------------------------------------------------------------------------
__global__ __launch_bounds__(256) void gemm_out_ln_pool(
    const unsigned short* __restrict__ O, const unsigned short* __restrict__ Wo,
    const float* __restrict__ b_out, const float* __restrict__ ln_g,
    const float* __restrict__ ln_b, float* __restrict__ pooled) {
    __shared__ __align__(16) unsigned short As[2][64 * LSO];
    __shared__ __align__(16) unsigned short Bs[128 * LSO];
    const int tid = threadIdx.x;
    const int s0 = blockIdx.x * TOK;
    const int wv = tid >> 6, lane = tid & 63, quad = lane >> 4, col = lane & 15;

    #pragma unroll
    for (int t = 0; t < 8; ++t) {                 // Wo rows: 128 x 16 chunks
        int q = tid + t * 256;
        int row = q >> 4, c = q & 15;
        *(float4*)&Bs[row * LSO + c * 8] =
            *(const float4*)(Wo + (size_t)row * 128 + c * 8);
    }
    #pragma unroll
    for (int t = 0; t < 4; ++t) {                 // token s0 -> As[0]
        int q = tid + t * 256;
        int h = q >> 7, rem = q & 127, l = rem >> 1, jj = rem & 1;
        *(short8*)&As[0][l * LSO + h * 16 + jj * 8] =
            *(const short8*)(O + (size_t)s0 * 8192 + (size_t)q * 8);
    }
    __syncthreads();

    float gch[8], bch[8], boch[8];
    #pragma unroll
    for (int nt = 0; nt < 8; ++nt) {
        int ch = nt * 16 + col;
        gch[nt] = ln_g[ch]; bch[nt] = ln_b[ch]; boch[nt] = b_out[ch];
    }
    const int mrow = wv * 16 + col;
    const int l0 = wv * 16 + quad * 4;
    const int nT = (SEQ - s0 < TOK) ? (SEQ - s0) : TOK;
    float accum[8][4] = {};

    for (int tt = 0; tt < nT; ++tt) {
        if (tt + 1 < nT) {                        // prefetch next token
            const size_t sn = s0 + tt + 1;
            #pragma unroll
            for (int t = 0; t < 4; ++t) {
                int q = tid + t * 256;
                int h = q >> 7, rem = q & 127, l = rem >> 1, jj = rem & 1;
                *(short8*)&As[(tt + 1) & 1][l * LSO + h * 16 + jj * 8] =
                    *(const short8*)(O + sn * 8192 + (size_t)q * 8);
            }
        }
        const unsigned short* Ac = As[tt & 1];
        f32x4 acc[8] = {};
        #pragma unroll
        for (int ks = 0; ks < 4; ++ks) {
            const int k0 = ks * 32 + quad * 8;
            short8 a = *(const short8*)&Ac[mrow * LSO + k0];
            #pragma unroll
            for (int nt = 0; nt < 8; ++nt) {
                short8 b = *(const short8*)&Bs[(nt * 16 + col) * LSO + k0];
                acc[nt] = __builtin_amdgcn_mfma_f32_16x16x32_bf16(a, b, acc[nt], 0, 0, 0);
            }
        }
        #pragma unroll
        for (int r = 0; r < 4; ++r) {
            float yv[8];
            float s1 = 0.0f, s2 = 0.0f;
            #pragma unroll
            for (int nt = 0; nt < 8; ++nt) {
                yv[nt] = acc[nt][r] + boch[nt];
                s1 += yv[nt]; s2 += yv[nt] * yv[nt];
            }
            #pragma unroll
            for (int off = 1; off < 16; off <<= 1) {
                s1 += __shfl_xor(s1, off);
                s2 += __shfl_xor(s2, off);
            }
            float mu = s1 * (1.0f / 128.0f);
            float var = s2 * (1.0f / 128.0f) - mu * mu;
            float rinv = rsqrtf(var + 1e-5f);
            #pragma unroll
            for (int nt = 0; nt < 8; ++nt)
                accum[nt][r] += (yv[nt] - mu) * rinv * gch[nt] + bch[nt];
        }
        __syncthreads();
    }

    #pragma unroll
    for (int nt = 0; nt < 8; ++nt)
        #pragma unroll
        for (int r = 0; r < 4; ++r)
            atomicAdd(&pooled[(l0 + r) * 128 + nt * 16 + col], accum[nt][r]);
}

// ---------------------------------------------------------------------------
// fp32 GEMM (precompute only, SB = A_pre @ w_in^T + b_in).
// ---------------------------------------------------------------------------
__global__ __launch_bounds__(256) void gemm64(
    const float* __restrict__ A, int lda, const float* __restrict__ B,
    const float* __restrict__ bias, float* __restrict__ C, int ldc) {
    __shared__ float As[64 * 68];
    __shared__ float Bs[64 * 68];
    const int bm = blockIdx.y * 64;
    const int bn = blockIdx.x * 64;
    const int tid = threadIdx.x;
    const int tx = tid & 15, ty = tid >> 4;

    float acc[4][4] = {};

    for (int kk = 0; kk < 128; kk += 64) {
        __syncthreads();
        #pragma unroll
        for (int t = 0; t < 4; ++t) {
            int q = tid + t * 256;
            int row = q & 63, c4 = (q >> 6) << 2;
            float4 va = *(const float4*)(A + (size_t)(bm + row) * lda + kk + c4);
            As[(c4 + 0) * 68 + row] = va.x;
            As[(c4 + 1) * 68 + row] = va.y;
            As[(c4 + 2) * 68 + row] = va.z;
            As[(c4 + 3) * 68 + row] = va.w;
            float4 vb = *(const float4*)(B + (size_t)(bn + row) * 128 + kk + c4);
            Bs[(c4 + 0) * 68 + row] = vb.x;
            Bs[(c4 + 1) * 68 + row] = vb.y;
            Bs[(c4 + 2) * 68 + row] = vb.z;
            Bs[(c4 + 3) * 68 + row] = vb.w;
        }
        __syncthreads();
        #pragma unroll 4
        for (int k = 0; k < 64; ++k) {
            float4 av = *(const float4*)&As[k * 68 + (ty << 2)];
            float4 bv = *(const float4*)&Bs[k * 68 + (tx << 2)];
            acc[0][0] += av.x*bv.x; acc[0][1] += av.x*bv.y; acc[0][2] += av.x*bv.z; acc[0][3] += av.x*bv.w;
            acc[1][0] += av.y*bv.x; acc[1][1] += av.y*bv.y; acc[1][2] += av.y*bv.z; acc[1][3] += av.y*bv.w;
            acc[2][0] += av.z*bv.x; acc[2][1] += av.z*bv.y; acc[2][2] += av.z*bv.z; acc[2][3] += av.z*bv.w;
            acc[3][0] += av.w*bv.x; acc[3][1] += av.w*bv.y; acc[3][2] += av.w*bv.z; acc[3][3] += av.w*bv.w;
        }
    }

    float4 bv = *(const float4*)(bias + bn + (tx << 2));
    #pragma unroll
    for (int i = 0; i < 4; ++i) {
        float4 r;
        r.x = acc[i][0] + bv.x; r.y = acc[i][1] + bv.y;
        r.z = acc[i][2] + bv.z; r.w = acc[i][3] + bv.w;
        *(float4*)(C + (size_t)(bm + (ty << 2) + i) * ldc + bn + (tx << 2)) = r;
    }
}

__global__ __launch_bounds__(128) void classify(
    const float* __restrict__ pooled, const float* __restrict__ out_w,
    const float* __restrict__ out_b, float* __restrict__ out) {
    const int l = blockIdx.x, e = threadIdx.x;
    __shared__ float sp[EMB];
    sp[e] = pooled[l * EMB + e] * (1.0f / (float)SEQ);
    __syncthreads();
    if (e < 3) {
        float acc = out_b[e];
        #pragma unroll 16
        for (int k = 0; k < EMB; ++k) acc += sp[k] * out_w[e * EMB + k];
        out[l * 3 + e] = acc;
    }
}

extern "C" void kernel_launch(void* const* d_in, const int* in_sizes, int n_in,
                              void* d_out, int out_size, void* d_ws, size_t ws_size,
                              hipStream_t stream) {
    const float* images = (const float*)d_in[0];
    const float* lm_w   = (const float*)d_in[1];
    const float* lm_b   = (const float*)d_in[2];
    const float* cls    = (const float*)d_in[3];
    const float* w_in   = (const float*)d_in[4];
    const float* b_in   = (const float*)d_in[5];
    const float* w_out  = (const float*)d_in[6];
    const float* b_out  = (const float*)d_in[7];
    const float* ln_g   = (const float*)d_in[8];
    const float* ln_b   = (const float*)d_in[9];
    const float* out_w  = (const float*)d_in[10];
    const float* out_b  = (const float*)d_in[11];
    float* out = (float*)d_out;

    // Workspace (~80 MB of 256 MiB), all regions 16B-aligned:
    float* SB     = (float*)d_ws;                         // [SPAD][384] f32
    float* A_pre  = SB + (size_t)SPAD * 384;              // [SPAD][128] f32
    float* pooled = A_pre + (size_t)SPAD * 128;           // [64][128] f32
    unsigned short* W2   = (unsigned short*)(pooled + 64 * 128); // [384][KQ]
    unsigned short* Wout = W2 + (size_t)384 * KQ;         // [128][128]
    unsigned short* Pb   = Wout + 128 * 128;              // [SEQ][64][KQ]
    unsigned short* Obuf = Pb + (size_t)SEQ * 64 * KQ;    // [SEQ][8][64][16]

    build_A<<<dim3(SPAD), 128, 0, stream>>>(lm_b, cls, A_pre);
    gemm64<<<dim3(6, SPAD / 64), 256, 0, stream>>>(A_pre, 128, w_in, b_in, SB, 384);
    build_W2<<<dim3(384), 128, 0, stream>>>(w_in, lm_w, W2);
    build_Wout<<<dim3(128), 128, 0, stream>>>(w_out, Wout);
    zero_pooled<<<dim3(8), 1024, 0, stream>>>(pooled);
    zero_cls<<<dim3(3), 1024, 0, stream>>>((unsigned int*)Pb);

    patchify<<<dim3(51, 64), 256, 0, stream>>>(images, Pb);
    qkv_attn<<<dim3(SEQ), 256, 0, stream>>>(Pb, W2, SB, Obuf);
    gemm_out_ln_pool<<<dim3((SEQ + TOK - 1) / TOK), 256, 0, stream>>>(
        Obuf, Wout, b_out, ln_g, ln_b, pooled);
    classify<<<dim3(NIMG), 128, 0, stream>>>(pooled, out_w, out_b, out);
}

// Round 12
// 215.824 us; speedup vs baseline: 6.9476x; 1.1484x over previous
//
#include <hip/hip_runtime.h>
#include <math.h>

#define NIMG 64
#define SEQ  2602
#define EMB  128
#define HD   16
#define SPAD 2624    // SEQ padded to multiple of 64
#define KQ   96      // patch K padded 75 -> 96 (multiple of 32)
#define LSO  136     // LDS row stride (bf16) for K=128 (272 B, 16B-multiple)
#define TOK  8       // tokens per gemm_out_ln_pool block

typedef float f32x4 __attribute__((ext_vector_type(4)));
typedef short short8 __attribute__((ext_vector_type(8)));

// round-half-up bf16 (2 VALU ops)
__device__ __forceinline__ unsigned short f2bf(float f) {
    union { float f; unsigned int u; } v; v.f = f;
    return (unsigned short)((v.u + 0x8000u) >> 16);
}

// ---------------------------------------------------------------------------
// A_pre[s][e]: s==0 -> cls + PE(0); 1<=s<SEQ -> lm_b + PE(s); else 0.
// ---------------------------------------------------------------------------
__global__ __launch_bounds__(128) void build_A(
    const float* __restrict__ lm_b, const float* __restrict__ cls,
    float* __restrict__ A) {
    const int s = blockIdx.x, e = threadIdx.x;
    const bool odd = e & 1;
    float v;
    if (s == 0) {
        v = cls[e] + (odd ? 1.0f : 0.0f);
    } else if (s < SEQ) {
        float pfac = powf(10000.0f, -(float)(e & ~1) / 128.0f);
        float ang = (float)s * pfac;
        v = lm_b[e] + (odd ? cosf(ang) : sinf(ang));
    } else {
        v = 0.0f;
    }
    A[(size_t)s * 128 + e] = v;
}

// ---------------------------------------------------------------------------
// W2[j][f] = sum_e w_in[j][e]*lm_w[e][f], f<75; zero-pad to KQ. bf16 out.
// ---------------------------------------------------------------------------
__global__ __launch_bounds__(128) void build_W2(
    const float* __restrict__ w_in, const float* __restrict__ lm_w,
    unsigned short* __restrict__ W2) {
    const int j = blockIdx.x, f = threadIdx.x;
    if (f >= KQ) return;
    float acc = 0.0f;
    if (f < 75) {
        for (int e = 0; e < 128; ++e)
            acc += w_in[j * 128 + e] * lm_w[e * 75 + f];
    }
    W2[j * KQ + f] = f2bf(acc);
}

__global__ __launch_bounds__(128) void build_Wout(
    const float* __restrict__ w_out, unsigned short* __restrict__ Wo) {
    const int j = blockIdx.x, e = threadIdx.x;
    Wo[j * 128 + e] = f2bf(w_out[j * 128 + e]);
}

__global__ __launch_bounds__(1024) void zero_pooled(float* __restrict__ p) {
    p[blockIdx.x * 1024 + threadIdx.x] = 0.0f;
}

// Pb token s=0 (cls row): 64 images x 96 halves = 3072 uints of zero.
__global__ __launch_bounds__(1024) void zero_cls(unsigned int* __restrict__ p) {
    p[blockIdx.x * 1024 + threadIdx.x] = 0u;
}

// ---------------------------------------------------------------------------
// Patchify, coalesced both ends. Grid (51 patch-rows, 64 images), 256 thr.
// ---------------------------------------------------------------------------
__global__ __launch_bounds__(256) void patchify(
    const float* __restrict__ images, unsigned short* __restrict__ Pb) {
    __shared__ unsigned short rows[15][256];
    const int i = blockIdx.x, l = blockIdx.y;
    const int tid = threadIdx.x;

    if (tid < 255) {
        #pragma unroll
        for (int seg = 0; seg < 15; ++seg) {
            int c = seg / 5, rr = seg % 5;
            float v = images[(((size_t)l * 3 + c) * 255 + (i * 5 + rr)) * 255 + tid];
            rows[seg][tid] = f2bf(v);
        }
    }
    __syncthreads();

    const int j = tid >> 2;          // token within this patch-row
    const int part = tid & 3;        // quarter of the 96-wide feature row
    if (j < 51) {
        const int f0 = part * 24;
        __align__(16) unsigned short buf[24];
        #pragma unroll
        for (int u = 0; u < 24; ++u) {
            int f = f0 + u;
            unsigned short v = 0;
            if (f < 75) {
                int c = f / 25, rem = f % 25, rr = rem / 5, cc = rem % 5;
                v = rows[c * 5 + rr][j * 5 + cc];
            }
            buf[u] = v;
        }
        const int s = i * 51 + j + 1;
        unsigned short* dst = Pb + ((size_t)s * 64 + l) * KQ + f0;
        #pragma unroll
        for (int t = 0; t < 3; ++t)
            *(short8*)(dst + t * 8) = *(const short8*)&buf[t * 8];
    }
}

// ---------------------------------------------------------------------------
// FUSED QKV-GEMM + attention, occupancy-tuned: one block (4 waves) per token,
// wave w processes its two heads SEQUENTIALLY with per-head wave-private LDS
// (Q 3K, K 3K [reused for O], Vt 2.25K, half-P 5K = 13.25 KB/wave ->
// 53 KB/block -> 3 blocks/CU). ZERO barriers: all LDS is wave-private and
// per-wave LDS ops complete in order. XOR chunk swizzles (quad-aware) make
// every staged write/read <=2-way (free). P processed as two 64x32 halves
// (PV and ones-sum accumulate across halves). Arithmetic identical to R11.
// ---------------------------------------------------------------------------
__global__ __launch_bounds__(256, 3) void qkv_attn(
    const unsigned short* __restrict__ Pb, const unsigned short* __restrict__ W2,
    const float* __restrict__ SB, unsigned short* __restrict__ Obuf) {
    __shared__ __align__(16) unsigned short Qw_[4][64 * 24];
    __shared__ __align__(16) unsigned short Kw_[4][64 * 24];   // K, then O assembly
    __shared__ __align__(16) unsigned short Vw_[4][16 * 72];   // V transposed
    __shared__ __align__(16) unsigned short Pw_[4][64 * 40];   // half-P (64x32+pad)

    const int s = blockIdx.x;
    const int tid = threadIdx.x;
    const int w = tid >> 6, lane = tid & 63, quad = lane >> 4, col = lane & 15;
    unsigned short* Qw = Qw_[w];
    unsigned short* Kw = Kw_[w];
    unsigned short* Vw = Vw_[w];
    unsigned short* Pw = Pw_[w];

    const unsigned short* arow0 = Pb + (size_t)s * 64 * KQ;
    const float* sbrow = SB + (size_t)s * 384;
    const int koff = (quad & 1) * 8;             // dup-K k-offset (halves)
    short8 ones8;
    #pragma unroll
    for (int i = 0; i < 8; ++i) ones8[i] = (short)0x3F80;   // bf16 1.0

    #pragma unroll 1
    for (int hl = 0; hl < 2; ++hl) {
        const int h = 2 * w + hl;

        // ---- Phase 1: 48-channel sub-GEMM (Q/K/V 16-ch tiles for head h)
        f32x4 acc[3][4] = {};
        #pragma unroll
        for (int ks = 0; ks < 3; ++ks) {
            const int k0 = ks * 32 + quad * 8;
            short8 b[3];
            #pragma unroll
            for (int nt = 0; nt < 3; ++nt) {
                int ch = nt * 128 + h * 16 + col;
                b[nt] = *(const short8*)(W2 + (size_t)ch * KQ + k0);
            }
            #pragma unroll
            for (int mt = 0; mt < 4; ++mt) {
                short8 a = *(const short8*)(arow0 + (size_t)(mt * 16 + col) * KQ + k0);
                #pragma unroll
                for (int nt = 0; nt < 3; ++nt)
                    acc[nt][mt] = __builtin_amdgcn_mfma_f32_16x16x32_bf16(a, b[nt], acc[nt][mt], 0, 0, 0);
            }
        }

        // ---- Epilogue: bias + scatter to wave-private LDS
        // Q/K rows: 16 halves = 2 chunks; chunk pos = (col>>3) ^ ((m>>2)&1) = ^quad&1
        #pragma unroll
        for (int nt = 0; nt < 3; ++nt) {
            float bv = sbrow[nt * 128 + h * 16 + col];
            #pragma unroll
            for (int mt = 0; mt < 4; ++mt) {
                #pragma unroll
                for (int r = 0; r < 4; ++r) {
                    int m = mt * 16 + quad * 4 + r;
                    float v = acc[nt][mt][r] + bv;
                    if (nt == 0) {
                        int pos = (col >> 3) ^ (quad & 1);
                        Qw[m * 24 + pos * 8 + (col & 7)] = f2bf(v * 0.125f);
                    } else if (nt == 1) {
                        int pos = (col >> 3) ^ (quad & 1);
                        Kw[m * 24 + pos * 8 + (col & 7)] = f2bf(v);
                    } else {
                        Vw[col * 72 + m] = f2bf(v);
                    }
                }
            }
        }

        // ---- K as B-frags (dup-K: quads 2,3 re-read k0..15; x2 folded in Q)
        short8 bfr[4];
        #pragma unroll
        for (int nt = 0; nt < 4; ++nt) {
            int m_ = nt * 16 + col;
            int pos = (quad & 1) ^ ((col >> 2) & 1);
            bfr[nt] = *(const short8*)&Kw[m_ * 24 + pos * 8];
        }

        // ---- QK^T
        f32x4 sc[4][4] = {};
        #pragma unroll
        for (int mt = 0; mt < 4; ++mt) {
            int m_ = mt * 16 + col;
            int pos = (quad & 1) ^ ((col >> 2) & 1);
            short8 afr = *(const short8*)&Qw[m_ * 24 + pos * 8];
            #pragma unroll
            for (int nt = 0; nt < 4; ++nt)
                sc[mt][nt] = __builtin_amdgcn_mfma_f32_16x16x32_bf16(afr, bfr[nt], sc[mt][nt], 0, 0, 0);
        }

        // ---- V B-frags
        short8 vfr[2];
        #pragma unroll
        for (int ks = 0; ks < 2; ++ks)
            vfr[ks] = *(const short8*)&Vw[col * 72 + ks * 32 + quad * 8];

        // ---- softmax-PV in two n-halves through the half-P buffer
        f32x4 o[4] = {}, sm[4] = {};
        #pragma unroll
        for (int half = 0; half < 2; ++half) {
            // exp (no max) -> half-P, chunk-swizzled: pos = (2nt'+col>>3) ^ quad
            #pragma unroll
            for (int ntl = 0; ntl < 2; ++ntl) {
                int nt = half * 2 + ntl;
                #pragma unroll
                for (int mt = 0; mt < 4; ++mt) {
                    #pragma unroll
                    for (int r = 0; r < 4; ++r) {
                        int m = mt * 16 + quad * 4 + r;
                        int pos = (ntl * 2 + (col >> 3)) ^ quad;
                        Pw[m * 40 + pos * 8 + (col & 7)] = f2bf(__expf(sc[mt][nt][r]));
                    }
                }
            }
            // PV partial + ones-sum partial (reads: pos = quad ^ ((col>>2)&3))
            #pragma unroll
            for (int mt = 0; mt < 4; ++mt) {
                int m_ = mt * 16 + col;
                int pos = quad ^ ((col >> 2) & 3);
                short8 pa = *(const short8*)&Pw[m_ * 40 + pos * 8];
                o[mt]  = __builtin_amdgcn_mfma_f32_16x16x32_bf16(pa, vfr[half], o[mt], 0, 0, 0);
                sm[mt] = __builtin_amdgcn_mfma_f32_16x16x32_bf16(pa, ones8, sm[mt], 0, 0, 0);
            }
        }

        // ---- normalize, assemble O in Kw (K consumed), coalesced store
        #pragma unroll
        for (int mt = 0; mt < 4; ++mt) {
            #pragma unroll
            for (int r = 0; r < 4; ++r) {
                float iv = __builtin_amdgcn_rcpf(sm[mt][r]);
                int l = mt * 16 + quad * 4 + r;
                int cc = (l * 2 + (col >> 3)) ^ ((l >> 2) & 3);
                Kw[cc * 8 + (col & 7)] = f2bf(o[mt][r] * iv);
            }
        }
        unsigned short* od = Obuf + ((size_t)s * 8 + h) * 1024;
        #pragma unroll
        for (int jj = 0; jj < 2; ++jj) {
            int cc = lane * 2 + jj;
            int cs = cc ^ ((lane >> 2) & 3);
            *(short8*)(od + cc * 8) = *(const short8*)&Kw[cs * 8];
        }
        if (hl == 0) __builtin_amdgcn_s_waitcnt(0);   // drain O ds_reads before head-2 K scatter
    }
}

// ---------------------------------------------------------------------------
// Fused out-proj + LayerNorm + mean-pool, TOK tokens per block.
// ---------------------------------------------------------------------------
__global__ __launch_bounds__(256) void gemm_out_ln_pool(
    const unsigned short* __restrict__ O, const unsigned short* __restrict__ Wo,
    const float* __restrict__ b_out, const float* __restrict__ ln_g,
    const float* __restrict__ ln_b, float* __restrict__ pooled) {
    __shared__ __align__(16) unsigned short As[2][64 * LSO];
    __shared__ __align__(16) unsigned short Bs[128 * LSO];
    const int tid = threadIdx.x;
    const int s0 = blockIdx.x * TOK;
    const int wv = tid >> 6, lane = tid & 63, quad = lane >> 4, col = lane & 15;

    #pragma unroll
    for (int t = 0; t < 8; ++t) {                 // Wo rows: 128 x 16 chunks
        int q = tid + t * 256;
        int row = q >> 4, c = q & 15;
        *(float4*)&Bs[row * LSO + c * 8] =
            *(const float4*)(Wo + (size_t)row * 128 + c * 8);
    }
    #pragma unroll
    for (int t = 0; t < 4; ++t) {                 // token s0 -> As[0]
        int q = tid + t * 256;
        int h = q >> 7, rem = q & 127, l = rem >> 1, jj = rem & 1;
        *(short8*)&As[0][l * LSO + h * 16 + jj * 8] =
            *(const short8*)(O + (size_t)s0 * 8192 + (size_t)q * 8);
    }
    __syncthreads();

    float gch[8], bch[8], boch[8];
    #pragma unroll
    for (int nt = 0; nt < 8; ++nt) {
        int ch = nt * 16 + col;
        gch[nt] = ln_g[ch]; bch[nt] = ln_b[ch]; boch[nt] = b_out[ch];
    }
    const int mrow = wv * 16 + col;
    const int l0 = wv * 16 + quad * 4;
    const int nT = (SEQ - s0 < TOK) ? (SEQ - s0) : TOK;
    float accum[8][4] = {};

    for (int tt = 0; tt < nT; ++tt) {
        if (tt + 1 < nT) {                        // prefetch next token
            const size_t sn = s0 + tt + 1;
            #pragma unroll
            for (int t = 0; t < 4; ++t) {
                int q = tid + t * 256;
                int h = q >> 7, rem = q & 127, l = rem >> 1, jj = rem & 1;
                *(short8*)&As[(tt + 1) & 1][l * LSO + h * 16 + jj * 8] =
                    *(const short8*)(O + sn * 8192 + (size_t)q * 8);
            }
        }
        const unsigned short* Ac = As[tt & 1];
        f32x4 acc[8] = {};
        #pragma unroll
        for (int ks = 0; ks < 4; ++ks) {
            const int k0 = ks * 32 + quad * 8;
            short8 a = *(const short8*)&Ac[mrow * LSO + k0];
            #pragma unroll
            for (int nt = 0; nt < 8; ++nt) {
                short8 b = *(const short8*)&Bs[(nt * 16 + col) * LSO + k0];
                acc[nt] = __builtin_amdgcn_mfma_f32_16x16x32_bf16(a, b, acc[nt], 0, 0, 0);
            }
        }
        #pragma unroll
        for (int r = 0; r < 4; ++r) {
            float yv[8];
            float s1 = 0.0f, s2 = 0.0f;
            #pragma unroll
            for (int nt = 0; nt < 8; ++nt) {
                yv[nt] = acc[nt][r] + boch[nt];
                s1 += yv[nt]; s2 += yv[nt] * yv[nt];
            }
            #pragma unroll
            for (int off = 1; off < 16; off <<= 1) {
                s1 += __shfl_xor(s1, off);
                s2 += __shfl_xor(s2, off);
            }
            float mu = s1 * (1.0f / 128.0f);
            float var = s2 * (1.0f / 128.0f) - mu * mu;
            float rinv = rsqrtf(var + 1e-5f);
            #pragma unroll
            for (int nt = 0; nt < 8; ++nt)
                accum[nt][r] += (yv[nt] - mu) * rinv * gch[nt] + bch[nt];
        }
        __syncthreads();
    }

    #pragma unroll
    for (int nt = 0; nt < 8; ++nt)
        #pragma unroll
        for (int r = 0; r < 4; ++r)
            atomicAdd(&pooled[(l0 + r) * 128 + nt * 16 + col], accum[nt][r]);
}

// ---------------------------------------------------------------------------
// fp32 GEMM (precompute only, SB = A_pre @ w_in^T + b_in).
// ---------------------------------------------------------------------------
__global__ __launch_bounds__(256) void gemm64(
    const float* __restrict__ A, int lda, const float* __restrict__ B,
    const float* __restrict__ bias, float* __restrict__ C, int ldc) {
    __shared__ float As[64 * 68];
    __shared__ float Bs[64 * 68];
    const int bm = blockIdx.y * 64;
    const int bn = blockIdx.x * 64;
    const int tid = threadIdx.x;
    const int tx = tid & 15, ty = tid >> 4;

    float acc[4][4] = {};

    for (int kk = 0; kk < 128; kk += 64) {
        __syncthreads();
        #pragma unroll
        for (int t = 0; t < 4; ++t) {
            int q = tid + t * 256;
            int row = q & 63, c4 = (q >> 6) << 2;
            float4 va = *(const float4*)(A + (size_t)(bm + row) * lda + kk + c4);
            As[(c4 + 0) * 68 + row] = va.x;
            As[(c4 + 1) * 68 + row] = va.y;
            As[(c4 + 2) * 68 + row] = va.z;
            As[(c4 + 3) * 68 + row] = va.w;
            float4 vb = *(const float4*)(B + (size_t)(bn + row) * 128 + kk + c4);
            Bs[(c4 + 0) * 68 + row] = vb.x;
            Bs[(c4 + 1) * 68 + row] = vb.y;
            Bs[(c4 + 2) * 68 + row] = vb.z;
            Bs[(c4 + 3) * 68 + row] = vb.w;
        }
        __syncthreads();
        #pragma unroll 4
        for (int k = 0; k < 64; ++k) {
            float4 av = *(const float4*)&As[k * 68 + (ty << 2)];
            float4 bv = *(const float4*)&Bs[k * 68 + (tx << 2)];
            acc[0][0] += av.x*bv.x; acc[0][1] += av.x*bv.y; acc[0][2] += av.x*bv.z; acc[0][3] += av.x*bv.w;
            acc[1][0] += av.y*bv.x; acc[1][1] += av.y*bv.y; acc[1][2] += av.y*bv.z; acc[1][3] += av.y*bv.w;
            acc[2][0] += av.z*bv.x; acc[2][1] += av.z*bv.y; acc[2][2] += av.z*bv.z; acc[2][3] += av.z*bv.w;
            acc[3][0] += av.w*bv.x; acc[3][1] += av.w*bv.y; acc[3][2] += av.w*bv.z; acc[3][3] += av.w*bv.w;
        }
    }

    float4 bv = *(const float4*)(bias + bn + (tx << 2));
    #pragma unroll
    for (int i = 0; i < 4; ++i) {
        float4 r;
        r.x = acc[i][0] + bv.x; r.y = acc[i][1] + bv.y;
        r.z = acc[i][2] + bv.z; r.w = acc[i][3] + bv.w;
        *(float4*)(C + (size_t)(bm + (ty << 2) + i) * ldc + bn + (tx << 2)) = r;
    }
}

__global__ __launch_bounds__(128) void classify(
    const float* __restrict__ pooled, const float* __restrict__ out_w,
    const float* __restrict__ out_b, float* __restrict__ out) {
    const int l = blockIdx.x, e = threadIdx.x;
    __shared__ float sp[EMB];
    sp[e] = pooled[l * EMB + e] * (1.0f / (float)SEQ);
    __syncthreads();
    if (e < 3) {
        float acc = out_b[e];
        #pragma unroll 16
        for (int k = 0; k < EMB; ++k) acc += sp[k] * out_w[e * EMB + k];
        out[l * 3 + e] = acc;
    }
}

extern "C" void kernel_launch(void* const* d_in, const int* in_sizes, int n_in,
                              void* d_out, int out_size, void* d_ws, size_t ws_size,
                              hipStream_t stream) {
    const float* images = (const float*)d_in[0];
    const float* lm_w   = (const float*)d_in[1];
    const float* lm_b   = (const float*)d_in[2];
    const float* cls    = (const float*)d_in[3];
    const float* w_in   = (const float*)d_in[4];
    const float* b_in   = (const float*)d_in[5];
    const float* w_out  = (const float*)d_in[6];
    const float* b_out  = (const float*)d_in[7];
    const float* ln_g   = (const float*)d_in[8];
    const float* ln_b   = (const float*)d_in[9];
    const float* out_w  = (const float*)d_in[10];
    const float* out_b  = (const float*)d_in[11];
    float* out = (float*)d_out;

    // Workspace (~80 MB of 256 MiB), all regions 16B-aligned:
    float* SB     = (float*)d_ws;                         // [SPAD][384] f32
    float* A_pre  = SB + (size_t)SPAD * 384;              // [SPAD][128] f32
    float* pooled = A_pre + (size_t)SPAD * 128;           // [64][128] f32
    unsigned short* W2   = (unsigned short*)(pooled + 64 * 128); // [384][KQ]
    unsigned short* Wout = W2 + (size_t)384 * KQ;         // [128][128]
    unsigned short* Pb   = Wout + 128 * 128;              // [SEQ][64][KQ]
    unsigned short* Obuf = Pb + (size_t)SEQ * 64 * KQ;    // [SEQ][8][64][16]

    build_A<<<dim3(SPAD), 128, 0, stream>>>(lm_b, cls, A_pre);
    gemm64<<<dim3(6, SPAD / 64), 256, 0, stream>>>(A_pre, 128, w_in, b_in, SB, 384);
    build_W2<<<dim3(384), 128, 0, stream>>>(w_in, lm_w, W2);
    build_Wout<<<dim3(128), 128, 0, stream>>>(w_out, Wout);
    zero_pooled<<<dim3(8), 1024, 0, stream>>>(pooled);
    zero_cls<<<dim3(3), 1024, 0, stream>>>((unsigned int*)Pb);

    patchify<<<dim3(51, 64), 256, 0, stream>>>(images, Pb);
    qkv_attn<<<dim3(SEQ), 256, 0, stream>>>(Pb, W2, SB, Obuf);
    gemm_out_ln_pool<<<dim3((SEQ + TOK - 1) / TOK), 256, 0, stream>>>(
        Obuf, Wout, b_out, ln_g, ln_b, pooled);
    classify<<<dim3(NIMG), 128, 0, stream>>>(pooled, out_w, out_b, out);
}